// Round 9
// baseline (4211.032 us; speedup 1.0000x reference)
//
#include <hip/hip_runtime.h>
#include <cstdint>
#include <cstddef>
#include <cstdio>

typedef __bf16 bf16;
typedef __bf16 bf16x8 __attribute__((ext_vector_type(8)));
typedef __bf16 bf16x4 __attribute__((ext_vector_type(4)));
typedef float f32x4 __attribute__((ext_vector_type(4)));

#define DEVFN __device__ __forceinline__

DEVFN float geluf(float x) { return 0.5f * x * (1.0f + erff(x * 0.70710678118654752f)); }
DEVFN float sigmoidf(float x) { return 1.0f / (1.0f + expf(-x)); }

// ---------------------------------------------------------------------------
// Generic MFMA GEMM: C(M,N) = act(A(M,K) @ W(N,K)^T + bias) [+ residual]
// ---------------------------------------------------------------------------
template <int WGM, int WGN, int ACT, bool RES>
__launch_bounds__(WGM * WGN * 64)
__global__ void gemm_bt(const bf16* __restrict__ A, const bf16* __restrict__ W,
                        const float* __restrict__ bias, const bf16* __restrict__ Rsd,
                        bf16* __restrict__ C, int M, int N, int K) {
  constexpr int BM = WGM * 64, BN = WGN * 64, T = WGM * WGN * 64;
  constexpr int NA = BM * 4 / T, NB = BN * 4 / T;
  __shared__ __align__(16) char ldsA[BM * 64];
  __shared__ __align__(16) char ldsB[BN * 64];
  const int tid = threadIdx.x;
  const int lane = tid & 63, wave = tid >> 6;
  const int wm = wave % WGM, wn = wave / WGM;
  const int l16 = lane & 15, quad = lane >> 4;
  const int bm0 = blockIdx.x * BM, bn0 = blockIdx.y * BN;

  f32x4 acc[4][4] = {};
  for (int k0 = 0; k0 < K; k0 += 32) {
    bf16x8 ta[NA], tb[NB];
#pragma unroll
    for (int i = 0; i < NA; ++i) {
      int lin = i * T + tid;
      int row = lin >> 2, seg = lin & 3;
      ta[i] = *(const bf16x8*)(A + (size_t)(bm0 + row) * K + k0 + seg * 8);
    }
#pragma unroll
    for (int i = 0; i < NB; ++i) {
      int lin = i * T + tid;
      int row = lin >> 2, seg = lin & 3;
      tb[i] = *(const bf16x8*)(W + (size_t)(bn0 + row) * K + k0 + seg * 8);
    }
#pragma unroll
    for (int i = 0; i < NA; ++i) *(bf16x8*)(ldsA + (i * T + tid) * 16) = ta[i];
#pragma unroll
    for (int i = 0; i < NB; ++i) *(bf16x8*)(ldsB + (i * T + tid) * 16) = tb[i];
    __syncthreads();
    bf16x8 af[4], bfrag[4];
#pragma unroll
    for (int mi = 0; mi < 4; ++mi)
      af[mi] = *(const bf16x8*)(ldsA + (wm * 64 + mi * 16 + l16) * 64 + quad * 16);
#pragma unroll
    for (int ni = 0; ni < 4; ++ni)
      bfrag[ni] = *(const bf16x8*)(ldsB + (wn * 64 + ni * 16 + l16) * 64 + quad * 16);
#pragma unroll
    for (int mi = 0; mi < 4; ++mi)
#pragma unroll
      for (int ni = 0; ni < 4; ++ni)
        acc[mi][ni] = __builtin_amdgcn_mfma_f32_16x16x32_bf16(af[mi], bfrag[ni], acc[mi][ni], 0, 0, 0);
    __syncthreads();
  }
#pragma unroll
  for (int mi = 0; mi < 4; ++mi) {
#pragma unroll
    for (int ni = 0; ni < 4; ++ni) {
      int col = bn0 + wn * 64 + ni * 16 + l16;
      float bv = bias[col];
#pragma unroll
      for (int r = 0; r < 4; ++r) {
        int row = bm0 + wm * 64 + mi * 16 + quad * 4 + r;
        float x = acc[mi][ni][r] + bv;
        if (ACT == 1) x = tanhf(x);
        if (ACT == 2) x = geluf(x);
        size_t idx = (size_t)row * N + col;
        if (RES) x += (float)Rsd[idx];
        C[idx] = (bf16)x;
      }
    }
  }
}

// ---------------------------------------------------------------------------
// GEMM with A in LAYER-HC layout [t][128 slices][256 b][8 u] (stride 262144/t):
// A row r=(t*256+b) col u -> HC + t*262144 + (u>>3)*2048 + b*8 + (u&7).
// ---------------------------------------------------------------------------
template <int WGM, int WGN, int ACT>
__launch_bounds__(WGM * WGN * 64)
__global__ void gemm_hcA(const bf16* __restrict__ HC, int tbase, const bf16* __restrict__ W,
                         const float* __restrict__ bias, bf16* __restrict__ C,
                         int M, int N, int K) {
  constexpr int BM = WGM * 64, BN = WGN * 64, T = WGM * WGN * 64;
  constexpr int NA = BM * 4 / T, NB = BN * 4 / T;
  __shared__ __align__(16) char ldsA[BM * 64];
  __shared__ __align__(16) char ldsB[BN * 64];
  const int tid = threadIdx.x;
  const int lane = tid & 63, wave = tid >> 6;
  const int wm = wave % WGM, wn = wave / WGM;
  const int l16 = lane & 15, quad = lane >> 4;
  const int bm0 = blockIdx.x * BM, bn0 = blockIdx.y * BN;

  f32x4 acc[4][4] = {};
  for (int k0 = 0; k0 < K; k0 += 32) {
    bf16x8 ta[NA], tb[NB];
#pragma unroll
    for (int i = 0; i < NA; ++i) {
      int lin = i * T + tid;
      int row = bm0 + (lin >> 2), seg = lin & 3;
      int t = tbase + (row >> 8), b = row & 255;
      ta[i] = *(const bf16x8*)(HC + (size_t)t * 262144 + (size_t)((k0 >> 3) + seg) * 2048 + b * 8);
    }
#pragma unroll
    for (int i = 0; i < NB; ++i) {
      int lin = i * T + tid;
      int row = lin >> 2, seg = lin & 3;
      tb[i] = *(const bf16x8*)(W + (size_t)(bn0 + row) * K + k0 + seg * 8);
    }
#pragma unroll
    for (int i = 0; i < NA; ++i) *(bf16x8*)(ldsA + (i * T + tid) * 16) = ta[i];
#pragma unroll
    for (int i = 0; i < NB; ++i) *(bf16x8*)(ldsB + (i * T + tid) * 16) = tb[i];
    __syncthreads();
    bf16x8 af[4], bfrag[4];
#pragma unroll
    for (int mi = 0; mi < 4; ++mi)
      af[mi] = *(const bf16x8*)(ldsA + (wm * 64 + mi * 16 + l16) * 64 + quad * 16);
#pragma unroll
    for (int ni = 0; ni < 4; ++ni)
      bfrag[ni] = *(const bf16x8*)(ldsB + (wn * 64 + ni * 16 + l16) * 64 + quad * 16);
#pragma unroll
    for (int mi = 0; mi < 4; ++mi)
#pragma unroll
      for (int ni = 0; ni < 4; ++ni)
        acc[mi][ni] = __builtin_amdgcn_mfma_f32_16x16x32_bf16(af[mi], bfrag[ni], acc[mi][ni], 0, 0, 0);
    __syncthreads();
  }
#pragma unroll
  for (int mi = 0; mi < 4; ++mi) {
#pragma unroll
    for (int ni = 0; ni < 4; ++ni) {
      int col = bn0 + wn * 64 + ni * 16 + l16;
      float bv = bias[col];
#pragma unroll
      for (int r = 0; r < 4; ++r) {
        int row = bm0 + wm * 64 + mi * 16 + quad * 4 + r;
        float x = acc[mi][ni][r] + bv;
        if (ACT == 1) x = tanhf(x);
        if (ACT == 2) x = geluf(x);
        C[(size_t)row * N + col] = (bf16)x;
      }
    }
  }
}

// ---------------------------------------------------------------------------
// fc_out stage-1 GEMM reading A from decoder hc layout [t][64][256][8]
// (stride 131072/t). C(M,64) = gelu(A @ W(64,512)^T + bias).
// ---------------------------------------------------------------------------
__launch_bounds__(128)
__global__ void gemm_hc_fcout(const bf16* __restrict__ HC, const bf16* __restrict__ W,
                              const float* __restrict__ bias, bf16* __restrict__ C,
                              int M, int N, int K) {
  constexpr int WGM = 2, WGN = 1;
  constexpr int BM = WGM * 64, BN = WGN * 64, T = WGM * WGN * 64;
  constexpr int NA = BM * 4 / T, NB = BN * 4 / T;
  __shared__ __align__(16) char ldsA[BM * 64];
  __shared__ __align__(16) char ldsB[BN * 64];
  const int tid = threadIdx.x;
  const int lane = tid & 63, wave = tid >> 6;
  const int wm = wave % WGM, wn = wave / WGM;
  const int l16 = lane & 15, quad = lane >> 4;
  const int bm0 = blockIdx.x * BM, bn0 = blockIdx.y * BN;

  f32x4 acc[4][4] = {};
  for (int k0 = 0; k0 < K; k0 += 32) {
    bf16x8 ta[NA], tb[NB];
#pragma unroll
    for (int i = 0; i < NA; ++i) {
      int lin = i * T + tid;
      int row = bm0 + (lin >> 2), seg = lin & 3;
      int t = row >> 8, b = row & 255;
      ta[i] = *(const bf16x8*)(HC + (size_t)t * 131072 + (size_t)((k0 >> 3) + seg) * 2048 + b * 8);
    }
#pragma unroll
    for (int i = 0; i < NB; ++i) {
      int lin = i * T + tid;
      int row = lin >> 2, seg = lin & 3;
      tb[i] = *(const bf16x8*)(W + (size_t)(bn0 + row) * K + k0 + seg * 8);
    }
#pragma unroll
    for (int i = 0; i < NA; ++i) *(bf16x8*)(ldsA + (i * T + tid) * 16) = ta[i];
#pragma unroll
    for (int i = 0; i < NB; ++i) *(bf16x8*)(ldsB + (i * T + tid) * 16) = tb[i];
    __syncthreads();
    bf16x8 af[4], bfrag[4];
#pragma unroll
    for (int mi = 0; mi < 4; ++mi)
      af[mi] = *(const bf16x8*)(ldsA + (wm * 64 + mi * 16 + l16) * 64 + quad * 16);
#pragma unroll
    for (int ni = 0; ni < 4; ++ni)
      bfrag[ni] = *(const bf16x8*)(ldsB + (wn * 64 + ni * 16 + l16) * 64 + quad * 16);
#pragma unroll
    for (int mi = 0; mi < 4; ++mi)
#pragma unroll
      for (int ni = 0; ni < 4; ++ni)
        acc[mi][ni] = __builtin_amdgcn_mfma_f32_16x16x32_bf16(af[mi], bfrag[ni], acc[mi][ni], 0, 0, 0);
    __syncthreads();
  }
#pragma unroll
  for (int mi = 0; mi < 4; ++mi) {
#pragma unroll
    for (int ni = 0; ni < 4; ++ni) {
      int col = bn0 + wn * 64 + ni * 16 + l16;
      float bv = bias[col];
#pragma unroll
      for (int r = 0; r < 4; ++r) {
        int row = bm0 + wm * 64 + mi * 16 + quad * 4 + r;
        float x = geluf(acc[mi][ni][r] + bv);
        C[(size_t)row * N + col] = (bf16)x;
      }
    }
  }
}

// ---------------------------------------------------------------------------
// Device tile-GEMM for the fused rec+gemm kernel (512 threads, BM=128,
// BN=256). A row-major (HCMODE=0) or layer-hc (HCMODE=1). N fixed = 2048.
// ---------------------------------------------------------------------------
template <int HCMODE>
DEVFN void xg_tile(const bf16* __restrict__ A, int tbase, const bf16* __restrict__ W,
                   const float* __restrict__ bias, bf16* __restrict__ C,
                   int K, int bm0, int bn0, int tid, bf16* ldsA, bf16* ldsB) {
  const int lane = tid & 63, wave = tid >> 6;
  const int wm = wave & 1, wn = wave >> 1;  // WGM=2, WGN=4
  const int l16 = lane & 15, quad = lane >> 4;
  f32x4 acc[4][4] = {};
  for (int k0 = 0; k0 < K; k0 += 32) {
    bf16x8 ta, tb0, tb1;
    {
      int row = bm0 + (tid >> 2), seg = tid & 3;
      if (HCMODE) {
        int t = tbase + (row >> 8), b = row & 255;
        ta = *(const bf16x8*)(A + (size_t)t * 262144 + (size_t)((k0 >> 3) + seg) * 2048 + b * 8);
      } else {
        ta = *(const bf16x8*)(A + (size_t)row * K + k0 + seg * 8);
      }
    }
    { int row = tid >> 2, seg = tid & 3;
      tb0 = *(const bf16x8*)(W + (size_t)(bn0 + row) * K + k0 + seg * 8); }
    { int lin = 512 + tid; int row = lin >> 2, seg = lin & 3;
      tb1 = *(const bf16x8*)(W + (size_t)(bn0 + row) * K + k0 + seg * 8); }
    *(bf16x8*)(ldsA + tid * 8) = ta;
    *(bf16x8*)(ldsB + tid * 8) = tb0;
    *(bf16x8*)(ldsB + (512 + tid) * 8) = tb1;
    __syncthreads();
    bf16x8 af[4], bfr[4];
#pragma unroll
    for (int mi = 0; mi < 4; ++mi)
      af[mi] = *(const bf16x8*)(ldsA + (wm * 64 + mi * 16 + l16) * 32 + quad * 8);
#pragma unroll
    for (int ni = 0; ni < 4; ++ni)
      bfr[ni] = *(const bf16x8*)(ldsB + (wn * 64 + ni * 16 + l16) * 32 + quad * 8);
#pragma unroll
    for (int mi = 0; mi < 4; ++mi)
#pragma unroll
      for (int ni = 0; ni < 4; ++ni)
        acc[mi][ni] = __builtin_amdgcn_mfma_f32_16x16x32_bf16(af[mi], bfr[ni], acc[mi][ni], 0, 0, 0);
    __syncthreads();
  }
#pragma unroll
  for (int mi = 0; mi < 4; ++mi) {
#pragma unroll
    for (int ni = 0; ni < 4; ++ni) {
      int col = bn0 + wn * 64 + ni * 16 + l16;
      float bv = bias[col];
#pragma unroll
      for (int r = 0; r < 4; ++r) {
        int row = bm0 + wm * 64 + mi * 16 + quad * 4 + r;
        C[(size_t)row * 2048 + col] = (bf16)(acc[mi][ni][r] + bv);
      }
    }
  }
}

// ---------------------------------------------------------------------------
// Fused encoder dispatch, rebalanced: blocks 0-63 run the recurrence with
// FAT slices (32 blocks/dir x 64 gate-cols: halves h-broadcast volume and
// poll fan-in); blocks 64-255 (192) run the next-chunk xg tile-GEMM --
// layer-1 chunks were GEMM-bound at 128 blocks (155us > rec 104us), 192
// brings GEMM to ~105us. hc layout & publish discipline unchanged (each
// block owns 2 contiguous single-writer slices). Counter target 32/dir/step.
// ---------------------------------------------------------------------------
struct RDir {
  const bf16* whh_r;   // (2048,512) bf16, rows reordered 4j+g
  const bf16* xg;      // chunk: row lt*256+b, 2048 cols (bias included)
  bf16* hc;            // layer hc buffer [Tfull][128][256][8]
  int slcOff, rev;     // slice offset (0 fwd, 64 bwd), direction
  const bf16* h0;      // initial h (256x512 row-major) for global step 0
  float* cbuf;         // persistent c (256x512 fp32)
  bf16* hfin;          // final h (row-major) or nullptr
};

struct GJob {
  int mode;            // 0 none, 1 layer0 row-major A (K=128), 2 layer1 hcA (K=1024)
  const bf16* Af; const bf16* Ab;
  int tbF, tbB;        // hcA tbases (mode 2)
  const bf16* Wf; const bf16* Wb;
  const float* bsF; const float* bsB;
  bf16* outF; bf16* outB;   // next-chunk xg buffers (4096 rows x 2048)
};

__launch_bounds__(512, 1)
__global__ void lstm_rec_g(RDir da, RDir db, int t0, int tc, int Tfull,
                           int* __restrict__ cnts, GJob job) {
  __shared__ __align__(16) char smem[73728];  // rec: 64KB whh + 8KB hstg | gemm: 8KB A + 16KB B
  const int blk = blockIdx.x;
  const int tid = threadIdx.x;

  if (blk >= 64) {
    // ----------------- GEMM role: next-chunk xg (both dirs) -----------------
    if (job.mode == 0) return;
    bf16* ldsA = (bf16*)smem;
    bf16* ldsB = (bf16*)(smem + 8192);
    const int gb = blk - 64;
    const int K = (job.mode == 2) ? 1024 : 128;
    // tiles: 2 dirs x (4096/128=32 mtiles) x (2048/256=8 ntiles) = 512
    for (int tile = gb; tile < 512; tile += 192) {
      int dir = tile >> 8;
      int rem = tile & 255;
      int mi = rem >> 3, ni = rem & 7;
      const bf16* A = dir ? job.Ab : job.Af;
      int tb = dir ? job.tbB : job.tbF;
      const bf16* W = dir ? job.Wb : job.Wf;
      const float* bs = dir ? job.bsB : job.bsF;
      bf16* C = dir ? job.outB : job.outF;
      if (job.mode == 2)
        xg_tile<1>(A, tb, W, bs, C, K, mi * 128, ni * 256, tid, ldsA, ldsB);
      else
        xg_tile<0>(A, tb, W, bs, C, K, mi * 128, ni * 256, tid, ldsA, ldsB);
    }
    return;
  }

  // --------- REC role: 32 blocks/dir x 64 gate-cols (16 units) ---------
  bf16* whh_lds = (bf16*)smem;             // 64 cols x 512 k (64KB), permuted
  bf16* hstg = (bf16*)(smem + 65536);      // 256 b x 16 u (8KB)
  const RDir d = (blk >= 32) ? db : da;
  const int bslice = blk & 31;
  const int colBase = bslice * 64, unitBase = bslice * 16;
  const int w = tid >> 6, lane = tid & 63;
  const int l16 = lane & 15, quad = lane >> 4;

  // prologue: whh slice -> LDS, permuted ((k>>3)*512 + c*8 + (k&7))
  for (int e = tid * 8; e < 64 * 512; e += 512 * 8) {
    int c = e >> 9, k0 = e & 511;
    bf16x8 v = *(const bf16x8*)(d.whh_r + (size_t)(colBase + c) * 512 + k0);
    *(bf16x8*)(whh_lds + ((k0 >> 3) << 9) + (c << 3)) = v;
  }
  float cst[4][2];
#pragma unroll
  for (int m = 0; m < 4; ++m)
#pragma unroll
    for (int i = 0; i < 2; ++i) {
      int b = w * 32 + i * 16 + l16;
      cst[m][i] = d.cbuf[(size_t)b * 512 + unitBase + m * 4 + quad];
    }
  __syncthreads();

  int* cnt = cnts + ((blk & 32) << 1);   // 0 for dir A, 64 for dir B
  const int b0 = w * 32 + l16;
  const int b1 = b0 + 16;

  for (int s = 0; s < tc; ++s) {
    const int sg = t0 + s;
    const int t = d.rev ? (Tfull - 1 - sg) : sg;
    const int lt = d.rev ? (tc - 1 - s) : s;

    bf16x4 gxr[4][2];
#pragma unroll
    for (int m = 0; m < 4; ++m)
#pragma unroll
      for (int i = 0; i < 2; ++i) {
        int b = b0 + i * 16;
        gxr[m][i] = *(const bf16x4*)(d.xg + ((size_t)lt * 256 + b) * 2048 + colBase + m * 16 + quad * 4);
      }
    bf16x8 hr[16][2];
    if (sg == 0) {
      const bf16* hp0 = d.h0 + (size_t)b0 * 512 + quad * 8;
      const bf16* hp1 = d.h0 + (size_t)b1 * 512 + quad * 8;
#pragma unroll
      for (int kk = 0; kk < 16; ++kk) {
        hr[kk][0] = *(const bf16x8*)(hp0 + kk * 32);
        hr[kk][1] = *(const bf16x8*)(hp1 + kk * 32);
      }
    } else {
      const int tp = d.rev ? (t + 1) : (t - 1);
      const bf16* hc = d.hc + (size_t)tp * 262144 + (size_t)d.slcOff * 2048;
#pragma unroll
      for (int kk = 0; kk < 16; ++kk) {
        int u8 = kk * 4 + quad;
        hr[kk][0] = *(const bf16x8*)(hc + u8 * 2048 + (size_t)b0 * 8);
        hr[kk][1] = *(const bf16x8*)(hc + u8 * 2048 + (size_t)b1 * 8);
      }
    }
    __builtin_amdgcn_sched_barrier(0);

    f32x4 acc[4][2] = {};
#pragma unroll
    for (int kk = 0; kk < 16; ++kk) {
      bf16x8 a0 = *(const bf16x8*)(whh_lds + kk * 2048 + quad * 512 + l16 * 8);
      bf16x8 a1 = *(const bf16x8*)(whh_lds + kk * 2048 + quad * 512 + 128 + l16 * 8);
      bf16x8 a2 = *(const bf16x8*)(whh_lds + kk * 2048 + quad * 512 + 256 + l16 * 8);
      bf16x8 a3 = *(const bf16x8*)(whh_lds + kk * 2048 + quad * 512 + 384 + l16 * 8);
#pragma unroll
      for (int i = 0; i < 2; ++i) {
        acc[0][i] = __builtin_amdgcn_mfma_f32_16x16x32_bf16(a0, hr[kk][i], acc[0][i], 0, 0, 0);
        acc[1][i] = __builtin_amdgcn_mfma_f32_16x16x32_bf16(a1, hr[kk][i], acc[1][i], 0, 0, 0);
        acc[2][i] = __builtin_amdgcn_mfma_f32_16x16x32_bf16(a2, hr[kk][i], acc[2][i], 0, 0, 0);
        acc[3][i] = __builtin_amdgcn_mfma_f32_16x16x32_bf16(a3, hr[kk][i], acc[3][i], 0, 0, 0);
      }
    }
#pragma unroll
    for (int m = 0; m < 4; ++m)
#pragma unroll
      for (int i = 0; i < 2; ++i) {
        float gi = acc[m][i][0] + (float)gxr[m][i][0];
        float gf = acc[m][i][1] + (float)gxr[m][i][1];
        float gg = acc[m][i][2] + (float)gxr[m][i][2];
        float go = acc[m][i][3] + (float)gxr[m][i][3];
        float cn = sigmoidf(gf) * cst[m][i] + sigmoidf(gi) * tanhf(gg);
        float hv = sigmoidf(go) * tanhf(cn);
        cst[m][i] = cn;
        int b = b0 + i * 16;
        hstg[b * 16 + m * 4 + quad] = (bf16)hv;
      }
    __syncthreads();
    // publish 2 contiguous single-writer slices (2*bslice, 2*bslice+1): 8KB
    {
      int b = tid >> 1, uh = tid & 1;
#pragma unroll
      for (int hi = 0; hi < 2; ++hi) {
        unsigned long long v = *(const unsigned long long*)(hstg + b * 16 + hi * 8 + uh * 4);
        __hip_atomic_store((unsigned long long*)(d.hc + (size_t)t * 262144 +
                                                 (size_t)(d.slcOff + 2 * bslice + hi) * 2048 + tid * 4),
                           v, __ATOMIC_RELAXED, __HIP_MEMORY_SCOPE_AGENT);
      }
    }
    __syncthreads();  // drains vmcnt -> hc visible before signal
    if (s < tc - 1 && tid == 0)
      __hip_atomic_fetch_add(cnt, 1, __ATOMIC_RELAXED, __HIP_MEMORY_SCOPE_AGENT);
    if (sg == Tfull - 1 && d.hfin) {  // once per layer: final h (16 units/block)
      int b = tid >> 1, uh = tid & 1;
      const unsigned long long* p = (const unsigned long long*)(hstg + b * 16 + uh * 8);
      unsigned long long* r2 = (unsigned long long*)(d.hfin + (size_t)b * 512 + unitBase + uh * 8);
      r2[0] = p[0];
      *((unsigned long long*)(d.hfin + (size_t)b * 512 + unitBase + uh * 8) + 0) = p[0];
      // second 8B of this half
      unsigned long long v1 = *((const unsigned long long*)(hstg + b * 16 + uh * 8) + 0);
      (void)v1;
    }
    if (sg == Tfull - 1 && d.hfin) {
      int b = tid >> 1, uh = tid & 1;
      // copy full 8 units (16B) of this half
      const unsigned long long* p = (const unsigned long long*)(hstg + b * 16 + uh * 8);
      unsigned long long* r2 = (unsigned long long*)(d.hfin + (size_t)b * 512 + unitBase + uh * 8);
      r2[0] = p[0]; r2[1] = p[1];
    }
    if (s < tc - 1) {
      if (w == 0) {
        int target = 32 * (s + 1), guard = 0;
        while (__hip_atomic_load(cnt, __ATOMIC_RELAXED, __HIP_MEMORY_SCOPE_AGENT) < target) {
          __builtin_amdgcn_s_sleep(2);
          if (++guard > (1 << 22)) break;  // bail (wrong answer) instead of hang
        }
      }
      __syncthreads();
    }
  }
#pragma unroll
  for (int m = 0; m < 4; ++m)
#pragma unroll
    for (int i = 0; i < 2; ++i) {
      int b = w * 32 + i * 16 + l16;
      d.cbuf[(size_t)b * 512 + unitBase + m * 4 + quad] = cst[m][i];
    }
}

// ---------------------------------------------------------------------------
// Fused decoder (unchanged): d0 + d1 pipelined 1-step lag, both publishing
// single-writer 4KB hc regions; fc_out reads hc1 directly.
// ---------------------------------------------------------------------------
__launch_bounds__(512, 1)
__global__ void lstm_dec_fused(
    const bf16* __restrict__ whh0, const bf16* __restrict__ xg0,
    bf16* __restrict__ hc0, const bf16* __restrict__ h0d0, float* __restrict__ c0buf,
    const bf16* __restrict__ whh1, const bf16* __restrict__ wih1, const float* __restrict__ bias1,
    bf16* __restrict__ hc1, const bf16* __restrict__ h0d1,
    float* __restrict__ c1buf, int* __restrict__ cnts) {
  const int blk = blockIdx.x;
  const int tid = threadIdx.x;
  const int w = tid >> 6, lane = tid & 63;
  const int l16 = lane & 15, quad = lane >> 4;
  constexpr int TC = 64;

  __shared__ __align__(16) bf16 wldsA[32 * 512];
  __shared__ __align__(16) bf16 wldsB[32 * 512];
  __shared__ __align__(16) bf16 hstg[256 * 8];

  int* cnt0 = cnts;
  int* cnt1 = cnts + 64;
  const int b0 = (w * 2) * 16 + l16;
  const int b1 = b0 + 16;

  if (blk < 64) {
    const int slice = blk;
    const int colBase = slice * 32;
    for (int e = tid * 8; e < 32 * 512; e += 512 * 8) {
      int c = e >> 9, k0 = e & 511;
      bf16x8 v = *(const bf16x8*)(whh0 + (size_t)(colBase + c) * 512 + k0);
      *(bf16x8*)(wldsA + ((k0 >> 3) << 8) + (c << 3)) = v;
    }
    float cst[2][2];
#pragma unroll
    for (int m = 0; m < 2; ++m)
#pragma unroll
      for (int i = 0; i < 2; ++i) {
        int b = (w * 2 + i) * 16 + l16;
        cst[m][i] = c0buf[(size_t)b * 512 + slice * 8 + m * 4 + quad];
      }
    __syncthreads();

    for (int s = 0; s < TC; ++s) {
      bf16x4 gxr[2][2];
#pragma unroll
      for (int m = 0; m < 2; ++m)
#pragma unroll
        for (int i = 0; i < 2; ++i) {
          int b = b0 + i * 16;
          gxr[m][i] = *(const bf16x4*)(xg0 + ((size_t)s * 256 + b) * 2048 + colBase + m * 16 + quad * 4);
        }
      bf16x8 hr[16][2];
      if (s == 0) {
        const bf16* hp0 = h0d0 + (size_t)b0 * 512 + quad * 8;
        const bf16* hp1 = h0d0 + (size_t)b1 * 512 + quad * 8;
#pragma unroll
        for (int kk = 0; kk < 16; ++kk) {
          hr[kk][0] = *(const bf16x8*)(hp0 + kk * 32);
          hr[kk][1] = *(const bf16x8*)(hp1 + kk * 32);
        }
      } else {
        const bf16* hc = hc0 + (size_t)(s - 1) * 131072;
#pragma unroll
        for (int kk = 0; kk < 16; ++kk) {
          int u8 = kk * 4 + quad;
          hr[kk][0] = *(const bf16x8*)(hc + u8 * 2048 + (size_t)b0 * 8);
          hr[kk][1] = *(const bf16x8*)(hc + u8 * 2048 + (size_t)b1 * 8);
        }
      }
      __builtin_amdgcn_sched_barrier(0);
      f32x4 acc[2][2] = {};
#pragma unroll
      for (int kk = 0; kk < 16; ++kk) {
        bf16x8 a0 = *(const bf16x8*)(wldsA + kk * 1024 + quad * 256 + l16 * 8);
        bf16x8 a1 = *(const bf16x8*)(wldsA + kk * 1024 + quad * 256 + 128 + l16 * 8);
        acc[0][0] = __builtin_amdgcn_mfma_f32_16x16x32_bf16(a0, hr[kk][0], acc[0][0], 0, 0, 0);
        acc[1][0] = __builtin_amdgcn_mfma_f32_16x16x32_bf16(a1, hr[kk][0], acc[1][0], 0, 0, 0);
        acc[0][1] = __builtin_amdgcn_mfma_f32_16x16x32_bf16(a0, hr[kk][1], acc[0][1], 0, 0, 0);
        acc[1][1] = __builtin_amdgcn_mfma_f32_16x16x32_bf16(a1, hr[kk][1], acc[1][1], 0, 0, 0);
      }
#pragma unroll
      for (int m = 0; m < 2; ++m)
#pragma unroll
        for (int i = 0; i < 2; ++i) {
          float gi = acc[m][i][0] + (float)gxr[m][i][0];
          float gf = acc[m][i][1] + (float)gxr[m][i][1];
          float gg = acc[m][i][2] + (float)gxr[m][i][2];
          float go = acc[m][i][3] + (float)gxr[m][i][3];
          float cn = sigmoidf(gf) * cst[m][i] + sigmoidf(gi) * tanhf(gg);
          float hv = sigmoidf(go) * tanhf(cn);
          cst[m][i] = cn;
          int b = (w * 2 + i) * 16 + l16;
          hstg[b * 8 + m * 4 + quad] = (bf16)hv;
        }
      __syncthreads();
      {
        unsigned long long v = *(const unsigned long long*)(hstg + tid * 4);
        __hip_atomic_store((unsigned long long*)(hc0 + (size_t)s * 131072 + slice * 2048 + tid * 4),
                           v, __ATOMIC_RELAXED, __HIP_MEMORY_SCOPE_AGENT);
      }
      __syncthreads();
      if (tid == 0)
        __hip_atomic_fetch_add(cnt0, 1, __ATOMIC_RELAXED, __HIP_MEMORY_SCOPE_AGENT);
      if (s < TC - 1) {
        if (w == 0) {
          int target = 64 * (s + 1), guard = 0;
          while (__hip_atomic_load(cnt0, __ATOMIC_RELAXED, __HIP_MEMORY_SCOPE_AGENT) < target) {
            __builtin_amdgcn_s_sleep(2);
            if (++guard > (1 << 22)) break;
          }
        }
        __syncthreads();
      }
    }
#pragma unroll
    for (int m = 0; m < 2; ++m)
#pragma unroll
      for (int i = 0; i < 2; ++i) {
        int b = (w * 2 + i) * 16 + l16;
        c0buf[(size_t)b * 512 + slice * 8 + m * 4 + quad] = cst[m][i];
      }
  } else {
    const int slice = blk - 64;               // 0..63
    const int colBase = slice * 32;
    for (int e = tid * 8; e < 32 * 512; e += 512 * 8) {
      int c = e >> 9, k0 = e & 511;
      bf16x8 v = *(const bf16x8*)(whh1 + (size_t)(colBase + c) * 512 + k0);
      *(bf16x8*)(wldsA + ((k0 >> 3) << 8) + (c << 3)) = v;
      bf16x8 u = *(const bf16x8*)(wih1 + (size_t)(colBase + c) * 512 + k0);
      *(bf16x8*)(wldsB + ((k0 >> 3) << 8) + (c << 3)) = u;
    }
    float gbv[2][4];
#pragma unroll
    for (int m = 0; m < 2; ++m)
#pragma unroll
      for (int r = 0; r < 4; ++r) gbv[m][r] = bias1[colBase + m * 16 + quad * 4 + r];
    float cst[2][2];
#pragma unroll
    for (int m = 0; m < 2; ++m)
#pragma unroll
      for (int i = 0; i < 2; ++i) {
        int b = (w * 2 + i) * 16 + l16;
        cst[m][i] = c1buf[(size_t)b * 512 + slice * 8 + m * 4 + quad];
      }
    __syncthreads();
    if (w == 0) {
      int guard = 0;
      while (__hip_atomic_load(cnt0, __ATOMIC_RELAXED, __HIP_MEMORY_SCOPE_AGENT) < 64) {
        __builtin_amdgcn_s_sleep(2);
        if (++guard > (1 << 22)) break;
      }
    }
    __syncthreads();

    for (int s = 0; s < TC; ++s) {
      f32x4 acc[2][2] = {};
      {
        const bf16* xc = hc0 + (size_t)s * 131072;
        bf16x8 xr[16][2];
#pragma unroll
        for (int kk = 0; kk < 16; ++kk) {
          int u8 = kk * 4 + quad;
          xr[kk][0] = *(const bf16x8*)(xc + u8 * 2048 + (size_t)b0 * 8);
          xr[kk][1] = *(const bf16x8*)(xc + u8 * 2048 + (size_t)b1 * 8);
        }
        __builtin_amdgcn_sched_barrier(0);
#pragma unroll
        for (int kk = 0; kk < 16; ++kk) {
          bf16x8 aw0 = *(const bf16x8*)(wldsB + kk * 1024 + quad * 256 + l16 * 8);
          bf16x8 aw1 = *(const bf16x8*)(wldsB + kk * 1024 + quad * 256 + 128 + l16 * 8);
          acc[0][0] = __builtin_amdgcn_mfma_f32_16x16x32_bf16(aw0, xr[kk][0], acc[0][0], 0, 0, 0);
          acc[1][0] = __builtin_amdgcn_mfma_f32_16x16x32_bf16(aw1, xr[kk][0], acc[1][0], 0, 0, 0);
          acc[0][1] = __builtin_amdgcn_mfma_f32_16x16x32_bf16(aw0, xr[kk][1], acc[0][1], 0, 0, 0);
          acc[1][1] = __builtin_amdgcn_mfma_f32_16x16x32_bf16(aw1, xr[kk][1], acc[1][1], 0, 0, 0);
        }
      }
      {
        bf16x8 hr[16][2];
        if (s == 0) {
          const bf16* hp0 = h0d1 + (size_t)b0 * 512 + quad * 8;
          const bf16* hp1 = h0d1 + (size_t)b1 * 512 + quad * 8;
#pragma unroll
          for (int kk = 0; kk < 16; ++kk) {
            hr[kk][0] = *(const bf16x8*)(hp0 + kk * 32);
            hr[kk][1] = *(const bf16x8*)(hp1 + kk * 32);
          }
        } else {
          const bf16* hc = hc1 + (size_t)(s - 1) * 131072;
#pragma unroll
          for (int kk = 0; kk < 16; ++kk) {
            int u8 = kk * 4 + quad;
            hr[kk][0] = *(const bf16x8*)(hc + u8 * 2048 + (size_t)b0 * 8);
            hr[kk][1] = *(const bf16x8*)(hc + u8 * 2048 + (size_t)b1 * 8);
          }
        }
        __builtin_amdgcn_sched_barrier(0);
#pragma unroll
        for (int kk = 0; kk < 16; ++kk) {
          bf16x8 a0 = *(const bf16x8*)(wldsA + kk * 1024 + quad * 256 + l16 * 8);
          bf16x8 a1 = *(const bf16x8*)(wldsA + kk * 1024 + quad * 256 + 128 + l16 * 8);
          acc[0][0] = __builtin_amdgcn_mfma_f32_16x16x32_bf16(a0, hr[kk][0], acc[0][0], 0, 0, 0);
          acc[1][0] = __builtin_amdgcn_mfma_f32_16x16x32_bf16(a1, hr[kk][0], acc[1][0], 0, 0, 0);
          acc[0][1] = __builtin_amdgcn_mfma_f32_16x16x32_bf16(a0, hr[kk][1], acc[0][1], 0, 0, 0);
          acc[1][1] = __builtin_amdgcn_mfma_f32_16x16x32_bf16(a1, hr[kk][1], acc[1][1], 0, 0, 0);
        }
      }
#pragma unroll
      for (int m = 0; m < 2; ++m)
#pragma unroll
        for (int i = 0; i < 2; ++i) {
          float gi = acc[m][i][0] + gbv[m][0];
          float gf = acc[m][i][1] + gbv[m][1];
          float gg = acc[m][i][2] + gbv[m][2];
          float go = acc[m][i][3] + gbv[m][3];
          float cn = sigmoidf(gf) * cst[m][i] + sigmoidf(gi) * tanhf(gg);
          float hv = sigmoidf(go) * tanhf(cn);
          cst[m][i] = cn;
          int b = (w * 2 + i) * 16 + l16;
          hstg[b * 8 + m * 4 + quad] = (bf16)hv;
        }
      __syncthreads();
      {
        unsigned long long v = *(const unsigned long long*)(hstg + tid * 4);
        __hip_atomic_store((unsigned long long*)(hc1 + (size_t)s * 131072 + slice * 2048 + tid * 4),
                           v, __ATOMIC_RELAXED, __HIP_MEMORY_SCOPE_AGENT);
      }
      __syncthreads();
      if (s < TC - 1) {
        if (tid == 0)
          __hip_atomic_fetch_add(cnt1, 1, __ATOMIC_RELAXED, __HIP_MEMORY_SCOPE_AGENT);
        if (w == 0) {
          int t1 = 64 * (s + 1), t0n = 64 * (s + 2), guard = 0;
          while (true) {
            int v1 = __hip_atomic_load(cnt1, __ATOMIC_RELAXED, __HIP_MEMORY_SCOPE_AGENT);
            int v0 = __hip_atomic_load(cnt0, __ATOMIC_RELAXED, __HIP_MEMORY_SCOPE_AGENT);
            if (v1 >= t1 && v0 >= t0n) break;
            __builtin_amdgcn_s_sleep(2);
            if (++guard > (1 << 22)) break;
          }
        }
        __syncthreads();
      }
    }
#pragma unroll
    for (int m = 0; m < 2; ++m)
#pragma unroll
      for (int i = 0; i < 2; ++i) {
        int b = (w * 2 + i) * 16 + l16;
        c1buf[(size_t)b * 512 + slice * 8 + m * 4 + quad] = cst[m][i];
      }
  }
}

// ---------------------------------------------------------------------------
// fc_in MLP: 4 -> 32 -> 64 -> 128, exact GELU. One row per thread. fp32 in.
// ---------------------------------------------------------------------------
__launch_bounds__(256)
__global__ void fc_in_mlp(const float* __restrict__ x, bf16* __restrict__ y, int rows, int tmod,
                          const float* __restrict__ w1, const float* __restrict__ b1,
                          const float* __restrict__ w2, const float* __restrict__ b2,
                          const float* __restrict__ w3, const float* __restrict__ b3) {
  __shared__ float sm[10592];
  const int tid = threadIdx.x;
  for (int i = tid; i < 10592; i += 256) {
    float v;
    if (i < 128) v = w1[i];
    else if (i < 160) v = b1[i - 128];
    else if (i < 2208) v = w2[i - 160];
    else if (i < 2272) v = b2[i - 2208];
    else if (i < 10464) v = w3[i - 2272];
    else v = b3[i - 10464];
    sm[i] = v;
  }
  __syncthreads();
  int row = blockIdx.x * 256 + tid;
  if (row >= rows) return;
  int orow = tmod ? ((row % tmod) * 256 + row / tmod) : row;
  float xin[4];
#pragma unroll
  for (int k = 0; k < 4; ++k) xin[k] = x[(size_t)row * 4 + k];
  float h1[32];
#pragma unroll
  for (int j = 0; j < 32; ++j) {
    float a = sm[128 + j];
#pragma unroll
    for (int k = 0; k < 4; ++k) a += sm[j * 4 + k] * xin[k];
    h1[j] = geluf(a);
  }
  float h2[64];
#pragma unroll
  for (int j = 0; j < 64; ++j) {
    float a = sm[2208 + j];
#pragma unroll
    for (int k = 0; k < 32; ++k) a += sm[160 + j * 32 + k] * h1[k];
    h2[j] = geluf(a);
  }
  for (int c = 0; c < 8; ++c) {
    float accv[16];
#pragma unroll
    for (int j = 0; j < 16; ++j) accv[j] = sm[10464 + c * 16 + j];
#pragma unroll
    for (int j = 0; j < 16; ++j) {
#pragma unroll
      for (int k = 0; k < 64; ++k) accv[j] += sm[2272 + (c * 16 + j) * 64 + k] * h2[k];
    }
#pragma unroll
    for (int j = 0; j < 16; ++j) y[(size_t)orow * 128 + c * 16 + j] = (bf16)accv[j];
  }
}

// ---------------------------------------------------------------------------
// fc_out tail: h1in rows time-major (t*256+b); trg/out rows (b*64+t), fp32.
// ---------------------------------------------------------------------------
__launch_bounds__(256)
__global__ void fc_out_tail(const bf16* __restrict__ h1in, const float* __restrict__ trg,
                            float* __restrict__ out, int rows,
                            const float* __restrict__ w2, const float* __restrict__ b2,
                            const float* __restrict__ w3, const float* __restrict__ b3) {
  __shared__ float sm[2212];
  const int tid = threadIdx.x;
  for (int i = tid; i < 2212; i += 256) {
    float v;
    if (i < 2048) v = w2[i];
    else if (i < 2080) v = b2[i - 2048];
    else if (i < 2208) v = w3[i - 2080];
    else v = b3[i - 2208];
    sm[i] = v;
  }
  __syncthreads();
  int row = blockIdx.x * 256 + tid;
  if (row >= rows) return;
  int b = row >> 6, t = row & 63;
  const bf16* h1p = h1in + ((size_t)t * 256 + b) * 64;
  float h1[64];
#pragma unroll
  for (int k = 0; k < 64; ++k) h1[k] = (float)h1p[k];
  float h2[32];
#pragma unroll
  for (int j = 0; j < 32; ++j) {
    float a = sm[2048 + j];
#pragma unroll
    for (int k = 0; k < 64; ++k) a += sm[j * 64 + k] * h1[k];
    h2[j] = geluf(a);
  }
#pragma unroll
  for (int dd = 0; dd < 4; ++dd) {
    float a = sm[2208 + dd];
#pragma unroll
    for (int k = 0; k < 32; ++k) a += sm[2080 + dd * 32 + k] * h2[k];
    out[(size_t)row * 4 + dd] = trg[(size_t)row * 4 + dd] + a;
  }
}

// ---------------------------------------------------------------------------
// MHA core: one block per (batch, head). All tensors time-major (row s*256+b).
// ---------------------------------------------------------------------------
__launch_bounds__(128)
__global__ void attention_kernel(const bf16* __restrict__ Q, const bf16* __restrict__ K,
                                 const bf16* __restrict__ V, bf16* __restrict__ O) {
  __shared__ bf16 qs[64 * 32];
  __shared__ float ks[128 * 33];
  __shared__ bf16 vs[128 * 32];
  __shared__ float sc[64 * 132];
  const int b = blockIdx.x, h = blockIdx.y, tid = threadIdx.x;
  for (int i = tid; i < 64 * 32; i += 128) {
    int t = i >> 5, dd = i & 31;
    qs[i] = Q[((size_t)t * 256 + b) * 128 + h * 32 + dd];
  }
  for (int i = tid; i < 128 * 32; i += 128) {
    int s = i >> 5, dd = i & 31;
    size_t ridx = ((size_t)s * 256 + b) * 128 + h * 32 + dd;
    ks[s * 33 + dd] = (float)K[ridx];
    vs[i] = V[ridx];
  }
  __syncthreads();
  const float scale = 0.17677669529663687f;
  for (int i = tid; i < 64 * 128; i += 128) {
    int t = i >> 7, s = i & 127;
    float a = 0.f;
#pragma unroll
    for (int dd = 0; dd < 32; ++dd) a += (float)qs[t * 32 + dd] * ks[s * 33 + dd];
    sc[t * 132 + s] = a * scale;
  }
  __syncthreads();
  if (tid < 64) {
    float m = -1e30f;
    for (int s = 0; s < 128; ++s) m = fmaxf(m, sc[tid * 132 + s]);
    float sum = 0.f;
    for (int s = 0; s < 128; ++s) { float e = expf(sc[tid * 132 + s] - m); sc[tid * 132 + s] = e; sum += e; }
    float r = 1.0f / sum;
    for (int s = 0; s < 128; ++s) sc[tid * 132 + s] *= r;
  }
  __syncthreads();
  for (int i = tid; i < 64 * 32; i += 128) {
    int t = i >> 5, dd = i & 31;
    float a = 0.f;
    for (int s = 0; s < 128; ++s) a += sc[t * 132 + s] * (float)vs[s * 32 + dd];
    O[((size_t)t * 256 + b) * 128 + h * 32 + dd] = (bf16)a;
  }
}

// ---------------------------------------------------------------------------
// Prep kernels
// ---------------------------------------------------------------------------
__global__ void reorder_gate_rows(const float* __restrict__ in, bf16* __restrict__ out, int K) {
  int i = blockIdx.x * 256 + threadIdx.x;
  if (i >= 2048 * K) return;
  int r = i / K, k = i - r * K;
  int nr = 4 * (r & 511) + (r >> 9);
  out[(size_t)nr * K + k] = (bf16)in[i];
}

__global__ void combine_bias(const float* __restrict__ a, const float* __restrict__ b,
                             float* __restrict__ out) {
  int i = blockIdx.x * 256 + threadIdx.x;
  if (i >= 2048) return;
  out[4 * (i & 511) + (i >> 9)] = a[i] + b[i];
}

__global__ void f2b(const float* __restrict__ in, bf16* __restrict__ out, int n) {
  int i = blockIdx.x * 256 + threadIdx.x;
  if (i < n) out[i] = (bf16)in[i];
}

__global__ void zero_u32(uint32_t* __restrict__ p, int n) {
  int i = blockIdx.x * 256 + threadIdx.x;
  if (i < n) p[i] = 0u;
}

__global__ void dec_state_init(const bf16* __restrict__ hf, const bf16* __restrict__ hb,
                               const float* __restrict__ cf, const float* __restrict__ cb,
                               bf16* __restrict__ hout, float* __restrict__ cout) {
  int i = blockIdx.x * 256 + threadIdx.x;
  if (i >= 256 * 512) return;
  hout[i] = (bf16)((float)hf[i] + (float)hb[i]);
  cout[i] = cf[i] + cb[i];
}

// ---------------------------------------------------------------------------
// Host
// ---------------------------------------------------------------------------
extern "C" void kernel_launch(void* const* d_in, const int* in_sizes, int n_in,
                              void* d_out, int out_size, void* d_ws, size_t ws_size,
                              hipStream_t stream) {
  (void)in_sizes; (void)n_in; (void)out_size;
  const float* src = (const float*)d_in[0];
  const float* trg = (const float*)d_in[1];
  const float* fi_w1 = (const float*)d_in[2];
  const float* fi_b1 = (const float*)d_in[3];
  const float* fi_w2 = (const float*)d_in[4];
  const float* fi_b2 = (const float*)d_in[5];
  const float* fi_w3 = (const float*)d_in[6];
  const float* fi_b3 = (const float*)d_in[7];
  // LSTM param order: e0f, e0b, e1f, e1b, d0, d1
  const float* wih_in[6] = {(const float*)d_in[8],  (const float*)d_in[12], (const float*)d_in[16],
                            (const float*)d_in[20], (const float*)d_in[30], (const float*)d_in[34]};
  const float* whh_in[6] = {(const float*)d_in[9],  (const float*)d_in[13], (const float*)d_in[17],
                            (const float*)d_in[21], (const float*)d_in[31], (const float*)d_in[35]};
  const float* bih_in[6] = {(const float*)d_in[10], (const float*)d_in[14], (const float*)d_in[18],
                            (const float*)d_in[22], (const float*)d_in[32], (const float*)d_in[36]};
  const float* bhh_in[6] = {(const float*)d_in[11], (const float*)d_in[15], (const float*)d_in[19],
                            (const float*)d_in[23], (const float*)d_in[33], (const float*)d_in[37]};
  const int kin[6] = {128, 128, 1024, 1024, 128, 512};
  const float* attnfc_w = (const float*)d_in[24];
  const float* attnfc_b = (const float*)d_in[25];
  const float* inproj_w = (const float*)d_in[26];
  const float* inproj_b = (const float*)d_in[27];
  const float* outproj_w = (const float*)d_in[28];
  const float* outproj_b = (const float*)d_in[29];
  const float* fo_w1 = (const float*)d_in[38];
  const float* fo_b1 = (const float*)d_in[39];
  const float* fo_w2 = (const float*)d_in[40];
  const float* fo_b2 = (const float*)d_in[41];
  const float* fo_w3 = (const float*)d_in[42];
  const float* fo_b3 = (const float*)d_in[43];
  float* out = (float*)d_out;

  // ---- workspace carve ----
  char* base = (char*)d_ws;
  size_t o = 0;
  auto take = [&](size_t bytes) -> char* {
    char* p = base + o;
    o = (o + bytes + 255) & ~(size_t)255;
    return p;
  };
  bf16* wr_wih[6]; for (int i = 0; i < 6; ++i) wr_wih[i] = (bf16*)take((size_t)2048 * kin[i] * 2);
  bf16* wr_whh[6]; for (int i = 0; i < 6; ++i) wr_whh[i] = (bf16*)take((size_t)2048 * 512 * 2);
  float* bias_l[6]; for (int i = 0; i < 6; ++i) bias_l[i] = (float*)take(2048 * 4);
  bf16* attnfc_wb = (bf16*)take((size_t)128 * 1024 * 2);
  bf16* inproj_wb = (bf16*)take((size_t)384 * 128 * 2);
  bf16* outproj_wb = (bf16*)take((size_t)128 * 128 * 2);
  bf16* fo_w1b = (bf16*)take((size_t)64 * 512 * 2);
  bf16* h0_0 = (bf16*)take((size_t)6 * 256 * 512 * 2);   // initial h per dir
  bf16* hf_0 = (bf16*)take((size_t)6 * 256 * 512 * 2);   // final h
  float* c_0 = (float*)take((size_t)6 * 256 * 512 * 4);  // persistent c per dir
  int* flags = (int*)take(4096 * 4);
  bf16* h0_[6]; bf16* hf_[6]; float* c_[6];
  for (int i = 0; i < 6; ++i) {
    h0_[i] = h0_0 + (size_t)i * 256 * 512;
    hf_[i] = hf_0 + (size_t)i * 256 * 512;
    c_[i] = c_0 + (size_t)i * 256 * 512;
  }
  char* RA = take((size_t)64 << 20);  // x1_hc -> proj_enc/inp/qb/kb/vb/attnb/dec_in/fc1out
  char* RB = take((size_t)64 << 20);  // enc_hc -> hc0/hc1
  char* XG = take((size_t)64 << 20);  // 4 parity xg chunk buffers -> xg_dec
  bf16* embed = (bf16*)take((size_t)32768 * 128 * 2);
  size_t required = o;
  if (required > ws_size) {
    fprintf(stderr, "[kernel_launch] ws_size=%zu < required=%zu — aborting launch\n",
            ws_size, required);
    return;
  }

  bf16* x1_hc    = (bf16*)RA;                        // layer-0 out, hc layout (64MB)
  bf16* proj_enc = (bf16*)RA;                        // (128,256,128) time-major
  bf16* inp      = (bf16*)(RA + ((size_t)8 << 20));  // (64,256,128) time-major
  bf16* qb       = (bf16*)(RA + ((size_t)12 << 20));
  bf16* kb       = (bf16*)(RA + ((size_t)16 << 20));
  bf16* vb       = (bf16*)(RA + ((size_t)24 << 20));
  bf16* attnb    = (bf16*)(RA + ((size_t)32 << 20));
  bf16* dec_in   = (bf16*)(RA + ((size_t)36 << 20)); // (64,256,128) time-major
  bf16* fc1out   = (bf16*)(RA + ((size_t)40 << 20));
  bf16* enc_hc   = (bf16*)RB;                        // layer-1 out, hc layout (64MB)
  bf16* hc0      = (bf16*)RB;                        // decoder d0 hcomm (16MB)
  bf16* hc1      = (bf16*)(RB + ((size_t)20 << 20)); // decoder d1 hcomm (16MB)
  bf16* bufF[2]  = {(bf16*)XG, (bf16*)(XG + ((size_t)32 << 20))};             // fwd chunk xg (16MB each)
  bf16* bufB[2]  = {(bf16*)(XG + ((size_t)16 << 20)), (bf16*)(XG + ((size_t)48 << 20))};
  bf16* xg_dec   = (bf16*)XG;                        // (64,256,2048) decoder d0 (64MB)

  // ---- prep ----
  for (int i = 0; i < 6; ++i) {
    reorder_gate_rows<<<dim3((2048 * kin[i] + 255) / 256), 256, 0, stream>>>(wih_in[i], wr_wih[i], kin[i]);
    reorder_gate_rows<<<dim3(4096), 256, 0, stream>>>(whh_in[i], wr_whh[i], 512);
    combine_bias<<<dim3(8), 256, 0, stream>>>(bih_in[i], bhh_in[i], bias_l[i]);
  }
  f2b<<<dim3(512), 256, 0, stream>>>(attnfc_w, attnfc_wb, 128 * 1024);
  f2b<<<dim3(192), 256, 0, stream>>>(inproj_w, inproj_wb, 384 * 128);
  f2b<<<dim3(64), 256, 0, stream>>>(outproj_w, outproj_wb, 128 * 128);
  f2b<<<dim3(128), 256, 0, stream>>>(fo_w1, fo_w1b, 64 * 512);
  zero_u32<<<dim3(1024), 256, 0, stream>>>((uint32_t*)h0_0, 4 * 256 * 512 / 2);  // enc h0 = 0
  zero_u32<<<dim3(2048), 256, 0, stream>>>((uint32_t*)c_0, 4 * 256 * 512);       // enc c = 0
  zero_u32<<<dim3(16), 256, 0, stream>>>((uint32_t*)flags, 4096);

  // ---- fc_in on src (time-major) ----
  fc_in_mlp<<<dim3(128), 256, 0, stream>>>(src, embed, 32768, 128, fi_w1, fi_b1, fi_w2, fi_b2, fi_w3, fi_b3);

  constexpr int TCC = 16, NCH = 8;
  // ---- encoder layer 0: chunk-0 GEMM serial, then fused rec+next-GEMM ----
  gemm_bt<2, 2, 0, false><<<dim3(32, 16), 256, 0, stream>>>(
      embed, wr_wih[0], bias_l[0], nullptr, bufF[0], 4096, 2048, 128);
  gemm_bt<2, 2, 0, false><<<dim3(32, 16), 256, 0, stream>>>(
      embed + (size_t)(128 - TCC) * 256 * 128, wr_wih[1], bias_l[1], nullptr, bufB[0], 4096, 2048, 128);
  for (int c = 0; c < NCH; ++c) {
    GJob job{};
    if (c < NCH - 1) {
      int n = c + 1;
      job.mode = 1;
      job.Af = embed + (size_t)(TCC * n) * 256 * 128;
      job.Ab = embed + (size_t)(128 - TCC * n - TCC) * 256 * 128;
      job.Wf = wr_wih[0]; job.Wb = wr_wih[1];
      job.bsF = bias_l[0]; job.bsB = bias_l[1];
      job.outF = bufF[n & 1]; job.outB = bufB[n & 1];
    }
    RDir f{wr_whh[0], bufF[c & 1], x1_hc, 0, 0, h0_[0], c_[0], hf_[0]};
    RDir bk{wr_whh[1], bufB[c & 1], x1_hc, 64, 1, h0_[1], c_[1], hf_[1]};
    lstm_rec_g<<<dim3(256), 512, 0, stream>>>(f, bk, c * TCC, TCC, 128, flags + c * 128, job);
  }
  // ---- encoder layer 1: chunk-0 GEMM serial (needs full x1_hc), then fused ----
  gemm_hcA<2, 2, 0><<<dim3(32, 16), 256, 0, stream>>>(
      x1_hc, 0, wr_wih[2], bias_l[2], bufF[0], 4096, 2048, 1024);
  gemm_hcA<2, 2, 0><<<dim3(32, 16), 256, 0, stream>>>(
      x1_hc, 128 - TCC, wr_wih[3], bias_l[3], bufB[0], 4096, 2048, 1024);
  for (int c = 0; c < NCH; ++c) {
    GJob job{};
    if (c < NCH - 1) {
      int n = c + 1;
      job.mode = 2;
      job.Af = x1_hc; job.Ab = x1_hc;
      job.tbF = TCC * n; job.tbB = 128 - TCC * n - TCC;
      job.Wf = wr_wih[2]; job.Wb = wr_wih[3];
      job.bsF = bias_l[2]; job.bsB = bias_l[3];
      job.outF = bufF[n & 1]; job.outB = bufB[n & 1];
    }
    RDir f{wr_whh[2], bufF[c & 1], enc_hc, 0, 0, h0_[2], c_[2], hf_[2]};
    RDir bk{wr_whh[3], bufB[c & 1], enc_hc, 64, 1, h0_[3], c_[3], hf_[3]};
    lstm_rec_g<<<dim3(256), 512, 0, stream>>>(f, bk, c * TCC, TCC, 128, flags + 1024 + c * 128, job);
  }

  // ---- attnfc (tanh), reads enc_hc directly ----
  gemm_hcA<2, 2, 1><<<dim3(256, 1), 256, 0, stream>>>(
      enc_hc, 0, attnfc_wb, attnfc_b, proj_enc, 32768, 128, 1024);

  // ---- fc_in on trg (time-major) ----
  fc_in_mlp<<<dim3(64), 256, 0, stream>>>(trg, inp, 16384, 64, fi_w1, fi_b1, fi_w2, fi_b2, fi_w3, fi_b3);

  // ---- MHA (all time-major) ----
  gemm_bt<2, 2, 0, false><<<dim3(128, 1), 256, 0, stream>>>(inp, inproj_wb, inproj_b, nullptr, qb, 16384, 128, 128);
  gemm_bt<2, 2, 0, false><<<dim3(256, 1), 256, 0, stream>>>(proj_enc, inproj_wb + (size_t)128 * 128, inproj_b + 128, nullptr, kb, 32768, 128, 128);
  gemm_bt<2, 2, 0, false><<<dim3(256, 1), 256, 0, stream>>>(proj_enc, inproj_wb + (size_t)256 * 128, inproj_b + 256, nullptr, vb, 32768, 128, 128);
  attention_kernel<<<dim3(256, 4), 128, 0, stream>>>(qb, kb, vb, attnb);
  gemm_bt<2, 2, 0, true><<<dim3(128, 1), 256, 0, stream>>>(attnb, outproj_wb, outproj_b, inp, dec_in, 16384, 128, 128);

  // ---- decoder initial states (enc c_ hold final c after last chunk) ----
  dec_state_init<<<dim3(512), 256, 0, stream>>>(hf_[0], hf_[1], c_[0], c_[1], h0_[4], c_[4]);
  dec_state_init<<<dim3(512), 256, 0, stream>>>(hf_[2], hf_[3], c_[2], c_[3], h0_[5], c_[5]);

  // ---- decoder: d0 xg GEMM + fused d0/d1 pipelined recurrence ----
  gemm_bt<2, 2, 0, false><<<dim3(128, 16), 256, 0, stream>>>(dec_in, wr_wih[4], bias_l[4], nullptr, xg_dec, 16384, 2048, 128);
  lstm_dec_fused<<<dim3(128), 512, 0, stream>>>(
      wr_whh[4], xg_dec, hc0, h0_[4], c_[4],
      wr_whh[5], wr_wih[5], bias_l[5], hc1, h0_[5], c_[5],
      flags + 2048);

  // ---- fc_out (stage 1 reads hc1 hcomm layout directly) ----
  gemm_hc_fcout<<<dim3(128, 1), 128, 0, stream>>>(hc1, fo_w1b, fo_b1, fc1out, 16384, 64, 512);
  fc_out_tail<<<dim3(64), 256, 0, stream>>>(fc1out, trg, out, 16384, fo_w2, fo_b2, fo_w3, fo_b3);
}

// Round 10
// 3589.801 us; speedup vs baseline: 1.1731x; 1.1731x over previous
//
#include <hip/hip_runtime.h>
#include <cstdint>
#include <cstddef>
#include <cstdio>

typedef __bf16 bf16;
typedef __bf16 bf16x8 __attribute__((ext_vector_type(8)));
typedef __bf16 bf16x4 __attribute__((ext_vector_type(4)));
typedef float f32x4 __attribute__((ext_vector_type(4)));

#define DEVFN __device__ __forceinline__

DEVFN float geluf(float x) { return 0.5f * x * (1.0f + erff(x * 0.70710678118654752f)); }
DEVFN float sigmoidf(float x) { return 1.0f / (1.0f + expf(-x)); }

// ---------------------------------------------------------------------------
// Generic MFMA GEMM: C(M,N) = act(A(M,K) @ W(N,K)^T + bias) [+ residual]
// ---------------------------------------------------------------------------
template <int WGM, int WGN, int ACT, bool RES>
__launch_bounds__(WGM * WGN * 64)
__global__ void gemm_bt(const bf16* __restrict__ A, const bf16* __restrict__ W,
                        const float* __restrict__ bias, const bf16* __restrict__ Rsd,
                        bf16* __restrict__ C, int M, int N, int K) {
  constexpr int BM = WGM * 64, BN = WGN * 64, T = WGM * WGN * 64;
  constexpr int NA = BM * 4 / T, NB = BN * 4 / T;
  __shared__ __align__(16) char ldsA[BM * 64];
  __shared__ __align__(16) char ldsB[BN * 64];
  const int tid = threadIdx.x;
  const int lane = tid & 63, wave = tid >> 6;
  const int wm = wave % WGM, wn = wave / WGM;
  const int l16 = lane & 15, quad = lane >> 4;
  const int bm0 = blockIdx.x * BM, bn0 = blockIdx.y * BN;

  f32x4 acc[4][4] = {};
  for (int k0 = 0; k0 < K; k0 += 32) {
    bf16x8 ta[NA], tb[NB];
#pragma unroll
    for (int i = 0; i < NA; ++i) {
      int lin = i * T + tid;
      int row = lin >> 2, seg = lin & 3;
      ta[i] = *(const bf16x8*)(A + (size_t)(bm0 + row) * K + k0 + seg * 8);
    }
#pragma unroll
    for (int i = 0; i < NB; ++i) {
      int lin = i * T + tid;
      int row = lin >> 2, seg = lin & 3;
      tb[i] = *(const bf16x8*)(W + (size_t)(bn0 + row) * K + k0 + seg * 8);
    }
#pragma unroll
    for (int i = 0; i < NA; ++i) *(bf16x8*)(ldsA + (i * T + tid) * 16) = ta[i];
#pragma unroll
    for (int i = 0; i < NB; ++i) *(bf16x8*)(ldsB + (i * T + tid) * 16) = tb[i];
    __syncthreads();
    bf16x8 af[4], bfrag[4];
#pragma unroll
    for (int mi = 0; mi < 4; ++mi)
      af[mi] = *(const bf16x8*)(ldsA + (wm * 64 + mi * 16 + l16) * 64 + quad * 16);
#pragma unroll
    for (int ni = 0; ni < 4; ++ni)
      bfrag[ni] = *(const bf16x8*)(ldsB + (wn * 64 + ni * 16 + l16) * 64 + quad * 16);
#pragma unroll
    for (int mi = 0; mi < 4; ++mi)
#pragma unroll
      for (int ni = 0; ni < 4; ++ni)
        acc[mi][ni] = __builtin_amdgcn_mfma_f32_16x16x32_bf16(af[mi], bfrag[ni], acc[mi][ni], 0, 0, 0);
    __syncthreads();
  }
#pragma unroll
  for (int mi = 0; mi < 4; ++mi) {
#pragma unroll
    for (int ni = 0; ni < 4; ++ni) {
      int col = bn0 + wn * 64 + ni * 16 + l16;
      float bv = bias[col];
#pragma unroll
      for (int r = 0; r < 4; ++r) {
        int row = bm0 + wm * 64 + mi * 16 + quad * 4 + r;
        float x = acc[mi][ni][r] + bv;
        if (ACT == 1) x = tanhf(x);
        if (ACT == 2) x = geluf(x);
        size_t idx = (size_t)row * N + col;
        if (RES) x += (float)Rsd[idx];
        C[idx] = (bf16)x;
      }
    }
  }
}

// ---------------------------------------------------------------------------
// GEMM with A in LAYER-HC layout [t][128 slices][256 b][8 u] (stride 262144/t):
// A row r=(t*256+b) col u -> HC + t*262144 + (u>>3)*2048 + b*8 + (u&7).
// ---------------------------------------------------------------------------
template <int WGM, int WGN, int ACT>
__launch_bounds__(WGM * WGN * 64)
__global__ void gemm_hcA(const bf16* __restrict__ HC, int tbase, const bf16* __restrict__ W,
                         const float* __restrict__ bias, bf16* __restrict__ C,
                         int M, int N, int K) {
  constexpr int BM = WGM * 64, BN = WGN * 64, T = WGM * WGN * 64;
  constexpr int NA = BM * 4 / T, NB = BN * 4 / T;
  __shared__ __align__(16) char ldsA[BM * 64];
  __shared__ __align__(16) char ldsB[BN * 64];
  const int tid = threadIdx.x;
  const int lane = tid & 63, wave = tid >> 6;
  const int wm = wave % WGM, wn = wave / WGM;
  const int l16 = lane & 15, quad = lane >> 4;
  const int bm0 = blockIdx.x * BM, bn0 = blockIdx.y * BN;

  f32x4 acc[4][4] = {};
  for (int k0 = 0; k0 < K; k0 += 32) {
    bf16x8 ta[NA], tb[NB];
#pragma unroll
    for (int i = 0; i < NA; ++i) {
      int lin = i * T + tid;
      int row = bm0 + (lin >> 2), seg = lin & 3;
      int t = tbase + (row >> 8), b = row & 255;
      ta[i] = *(const bf16x8*)(HC + (size_t)t * 262144 + (size_t)((k0 >> 3) + seg) * 2048 + b * 8);
    }
#pragma unroll
    for (int i = 0; i < NB; ++i) {
      int lin = i * T + tid;
      int row = lin >> 2, seg = lin & 3;
      tb[i] = *(const bf16x8*)(W + (size_t)(bn0 + row) * K + k0 + seg * 8);
    }
#pragma unroll
    for (int i = 0; i < NA; ++i) *(bf16x8*)(ldsA + (i * T + tid) * 16) = ta[i];
#pragma unroll
    for (int i = 0; i < NB; ++i) *(bf16x8*)(ldsB + (i * T + tid) * 16) = tb[i];
    __syncthreads();
    bf16x8 af[4], bfrag[4];
#pragma unroll
    for (int mi = 0; mi < 4; ++mi)
      af[mi] = *(const bf16x8*)(ldsA + (wm * 64 + mi * 16 + l16) * 64 + quad * 16);
#pragma unroll
    for (int ni = 0; ni < 4; ++ni)
      bfrag[ni] = *(const bf16x8*)(ldsB + (wn * 64 + ni * 16 + l16) * 64 + quad * 16);
#pragma unroll
    for (int mi = 0; mi < 4; ++mi)
#pragma unroll
      for (int ni = 0; ni < 4; ++ni)
        acc[mi][ni] = __builtin_amdgcn_mfma_f32_16x16x32_bf16(af[mi], bfrag[ni], acc[mi][ni], 0, 0, 0);
    __syncthreads();
  }
#pragma unroll
  for (int mi = 0; mi < 4; ++mi) {
#pragma unroll
    for (int ni = 0; ni < 4; ++ni) {
      int col = bn0 + wn * 64 + ni * 16 + l16;
      float bv = bias[col];
#pragma unroll
      for (int r = 0; r < 4; ++r) {
        int row = bm0 + wm * 64 + mi * 16 + quad * 4 + r;
        float x = acc[mi][ni][r] + bv;
        if (ACT == 1) x = tanhf(x);
        if (ACT == 2) x = geluf(x);
        C[(size_t)row * N + col] = (bf16)x;
      }
    }
  }
}

// ---------------------------------------------------------------------------
// fc_out stage-1 GEMM reading A from decoder hc layout [t][64][256][8]
// (stride 131072/t). C(M,64) = gelu(A @ W(64,512)^T + bias).
// ---------------------------------------------------------------------------
__launch_bounds__(128)
__global__ void gemm_hc_fcout(const bf16* __restrict__ HC, const bf16* __restrict__ W,
                              const float* __restrict__ bias, bf16* __restrict__ C,
                              int M, int N, int K) {
  constexpr int WGM = 2, WGN = 1;
  constexpr int BM = WGM * 64, BN = WGN * 64, T = WGM * WGN * 64;
  constexpr int NA = BM * 4 / T, NB = BN * 4 / T;
  __shared__ __align__(16) char ldsA[BM * 64];
  __shared__ __align__(16) char ldsB[BN * 64];
  const int tid = threadIdx.x;
  const int lane = tid & 63, wave = tid >> 6;
  const int wm = wave % WGM, wn = wave / WGM;
  const int l16 = lane & 15, quad = lane >> 4;
  const int bm0 = blockIdx.x * BM, bn0 = blockIdx.y * BN;

  f32x4 acc[4][4] = {};
  for (int k0 = 0; k0 < K; k0 += 32) {
    bf16x8 ta[NA], tb[NB];
#pragma unroll
    for (int i = 0; i < NA; ++i) {
      int lin = i * T + tid;
      int row = bm0 + (lin >> 2), seg = lin & 3;
      int t = row >> 8, b = row & 255;
      ta[i] = *(const bf16x8*)(HC + (size_t)t * 131072 + (size_t)((k0 >> 3) + seg) * 2048 + b * 8);
    }
#pragma unroll
    for (int i = 0; i < NB; ++i) {
      int lin = i * T + tid;
      int row = lin >> 2, seg = lin & 3;
      tb[i] = *(const bf16x8*)(W + (size_t)(bn0 + row) * K + k0 + seg * 8);
    }
#pragma unroll
    for (int i = 0; i < NA; ++i) *(bf16x8*)(ldsA + (i * T + tid) * 16) = ta[i];
#pragma unroll
    for (int i = 0; i < NB; ++i) *(bf16x8*)(ldsB + (i * T + tid) * 16) = tb[i];
    __syncthreads();
    bf16x8 af[4], bfrag[4];
#pragma unroll
    for (int mi = 0; mi < 4; ++mi)
      af[mi] = *(const bf16x8*)(ldsA + (wm * 64 + mi * 16 + l16) * 64 + quad * 16);
#pragma unroll
    for (int ni = 0; ni < 4; ++ni)
      bfrag[ni] = *(const bf16x8*)(ldsB + (wn * 64 + ni * 16 + l16) * 64 + quad * 16);
#pragma unroll
    for (int mi = 0; mi < 4; ++mi)
#pragma unroll
      for (int ni = 0; ni < 4; ++ni)
        acc[mi][ni] = __builtin_amdgcn_mfma_f32_16x16x32_bf16(af[mi], bfrag[ni], acc[mi][ni], 0, 0, 0);
    __syncthreads();
  }
#pragma unroll
  for (int mi = 0; mi < 4; ++mi) {
#pragma unroll
    for (int ni = 0; ni < 4; ++ni) {
      int col = bn0 + wn * 64 + ni * 16 + l16;
      float bv = bias[col];
#pragma unroll
      for (int r = 0; r < 4; ++r) {
        int row = bm0 + wm * 64 + mi * 16 + quad * 4 + r;
        float x = geluf(acc[mi][ni][r] + bv);
        C[(size_t)row * N + col] = (bf16)x;
      }
    }
  }
}

// ---------------------------------------------------------------------------
// Device tile-GEMM for the fused rec+gemm kernel (512 threads, BM=128,
// BN=256). A row-major (HCMODE=0) or layer-hc (HCMODE=1). N fixed = 2048.
// ---------------------------------------------------------------------------
template <int HCMODE>
DEVFN void xg_tile(const bf16* __restrict__ A, int tbase, const bf16* __restrict__ W,
                   const float* __restrict__ bias, bf16* __restrict__ C,
                   int K, int bm0, int bn0, int tid, bf16* ldsA, bf16* ldsB) {
  const int lane = tid & 63, wave = tid >> 6;
  const int wm = wave & 1, wn = wave >> 1;  // WGM=2, WGN=4
  const int l16 = lane & 15, quad = lane >> 4;
  f32x4 acc[4][4] = {};
  for (int k0 = 0; k0 < K; k0 += 32) {
    bf16x8 ta, tb0, tb1;
    {
      int row = bm0 + (tid >> 2), seg = tid & 3;
      if (HCMODE) {
        int t = tbase + (row >> 8), b = row & 255;
        ta = *(const bf16x8*)(A + (size_t)t * 262144 + (size_t)((k0 >> 3) + seg) * 2048 + b * 8);
      } else {
        ta = *(const bf16x8*)(A + (size_t)row * K + k0 + seg * 8);
      }
    }
    { int row = tid >> 2, seg = tid & 3;
      tb0 = *(const bf16x8*)(W + (size_t)(bn0 + row) * K + k0 + seg * 8); }
    { int lin = 512 + tid; int row = lin >> 2, seg = lin & 3;
      tb1 = *(const bf16x8*)(W + (size_t)(bn0 + row) * K + k0 + seg * 8); }
    *(bf16x8*)(ldsA + tid * 8) = ta;
    *(bf16x8*)(ldsB + tid * 8) = tb0;
    *(bf16x8*)(ldsB + (512 + tid) * 8) = tb1;
    __syncthreads();
    bf16x8 af[4], bfr[4];
#pragma unroll
    for (int mi = 0; mi < 4; ++mi)
      af[mi] = *(const bf16x8*)(ldsA + (wm * 64 + mi * 16 + l16) * 32 + quad * 8);
#pragma unroll
    for (int ni = 0; ni < 4; ++ni)
      bfr[ni] = *(const bf16x8*)(ldsB + (wn * 64 + ni * 16 + l16) * 32 + quad * 8);
#pragma unroll
    for (int mi = 0; mi < 4; ++mi)
#pragma unroll
      for (int ni = 0; ni < 4; ++ni)
        acc[mi][ni] = __builtin_amdgcn_mfma_f32_16x16x32_bf16(af[mi], bfr[ni], acc[mi][ni], 0, 0, 0);
    __syncthreads();
  }
#pragma unroll
  for (int mi = 0; mi < 4; ++mi) {
#pragma unroll
    for (int ni = 0; ni < 4; ++ni) {
      int col = bn0 + wn * 64 + ni * 16 + l16;
      float bv = bias[col];
#pragma unroll
      for (int r = 0; r < 4; ++r) {
        int row = bm0 + wm * 64 + mi * 16 + quad * 4 + r;
        C[(size_t)row * 2048 + col] = (bf16)(acc[mi][ni][r] + bv);
      }
    }
  }
}

// ---------------------------------------------------------------------------
// Fused encoder dispatch (round-8 config restored): blocks 0-127 run the
// recurrence for chunk c (32 gate-cols/block -- the fat 64-col variant
// regressed: register demand exceeded budget, compiler re-split the h-load
// burst -> chained latency); blocks 128-255 run the next-chunk xg tile-GEMM.
// ---------------------------------------------------------------------------
struct RDir {
  const bf16* whh_r;   // (2048,512) bf16, rows reordered 4j+g
  const bf16* xg;      // chunk: row lt*256+b, 2048 cols (bias included)
  bf16* hc;            // layer hc buffer [Tfull][128][256][8]
  int slcOff, rev;     // slice offset (0 fwd, 64 bwd), direction
  const bf16* h0;      // initial h (256x512 row-major) for global step 0
  float* cbuf;         // persistent c (256x512 fp32)
  bf16* hfin;          // final h (row-major) or nullptr
};

struct GJob {
  int mode;            // 0 none, 1 layer0 row-major A (K=128), 2 layer1 hcA (K=1024)
  const bf16* Af; const bf16* Ab;
  int tbF, tbB;        // hcA tbases (mode 2)
  const bf16* Wf; const bf16* Wb;
  const float* bsF; const float* bsB;
  bf16* outF; bf16* outB;   // next-chunk xg buffers (4096 rows x 2048)
};

__launch_bounds__(512, 1)
__global__ void lstm_rec_g(RDir da, RDir db, int t0, int tc, int Tfull,
                           int* __restrict__ cnts, GJob job) {
  __shared__ __align__(16) char smem[36864];  // rec: 32KB whh + 4KB hstg | gemm: 8KB A + 16KB B
  const int blk = blockIdx.x;
  const int tid = threadIdx.x;

  if (blk >= 128) {
    // ----------------- GEMM role: next-chunk xg (both dirs) -----------------
    if (job.mode == 0) return;
    bf16* ldsA = (bf16*)smem;
    bf16* ldsB = (bf16*)(smem + 8192);
    const int gb = blk - 128;
    const int K = (job.mode == 2) ? 1024 : 128;
    // tiles: 2 dirs x (4096/128=32 mtiles) x (2048/256=8 ntiles) = 512
    for (int tile = gb; tile < 512; tile += 128) {
      int dir = tile >> 8;
      int rem = tile & 255;
      int mi = rem >> 3, ni = rem & 7;
      const bf16* A = dir ? job.Ab : job.Af;
      int tb = dir ? job.tbB : job.tbF;
      const bf16* W = dir ? job.Wb : job.Wf;
      const float* bs = dir ? job.bsB : job.bsF;
      bf16* C = dir ? job.outB : job.outF;
      if (job.mode == 2)
        xg_tile<1>(A, tb, W, bs, C, K, mi * 128, ni * 256, tid, ldsA, ldsB);
      else
        xg_tile<0>(A, tb, W, bs, C, K, mi * 128, ni * 256, tid, ldsA, ldsB);
    }
    return;
  }

  // ----------------- REC role: 64 blocks/dir x 32 gate-cols -----------------
  bf16* whh_lds = (bf16*)smem;
  bf16* hstg = (bf16*)(smem + 32768);
  const RDir d = (blk >= 64) ? db : da;
  const int slice = blk & 63;
  const int colBase = slice * 32, unitBase = slice * 8;
  const int w = tid >> 6, lane = tid & 63;
  const int l16 = lane & 15, quad = lane >> 4;

  for (int e = tid * 8; e < 32 * 512; e += 512 * 8) {
    int c = e >> 9, k0 = e & 511;
    bf16x8 v = *(const bf16x8*)(d.whh_r + (size_t)(colBase + c) * 512 + k0);
    *(bf16x8*)(whh_lds + ((k0 >> 3) << 8) + (c << 3)) = v;
  }
  float cst[2][2];
#pragma unroll
  for (int m = 0; m < 2; ++m)
#pragma unroll
    for (int i = 0; i < 2; ++i) {
      int b = (w * 2 + i) * 16 + l16;
      cst[m][i] = d.cbuf[(size_t)b * 512 + unitBase + m * 4 + quad];
    }
  __syncthreads();

  int* cnt = cnts + (blk & 64);
  const int b0 = (w * 2) * 16 + l16;
  const int b1 = b0 + 16;

  for (int s = 0; s < tc; ++s) {
    const int sg = t0 + s;
    const int t = d.rev ? (Tfull - 1 - sg) : sg;
    const int lt = d.rev ? (tc - 1 - s) : s;

    bf16x4 gxr[2][2];
#pragma unroll
    for (int m = 0; m < 2; ++m)
#pragma unroll
      for (int i = 0; i < 2; ++i) {
        int b = b0 + i * 16;
        gxr[m][i] = *(const bf16x4*)(d.xg + ((size_t)lt * 256 + b) * 2048 + colBase + m * 16 + quad * 4);
      }
    bf16x8 hr[16][2];
    if (sg == 0) {
      const bf16* hp0 = d.h0 + (size_t)b0 * 512 + quad * 8;
      const bf16* hp1 = d.h0 + (size_t)b1 * 512 + quad * 8;
#pragma unroll
      for (int kk = 0; kk < 16; ++kk) {
        hr[kk][0] = *(const bf16x8*)(hp0 + kk * 32);
        hr[kk][1] = *(const bf16x8*)(hp1 + kk * 32);
      }
    } else {
      const int tp = d.rev ? (t + 1) : (t - 1);
      const bf16* hc = d.hc + (size_t)tp * 262144 + (size_t)d.slcOff * 2048;
#pragma unroll
      for (int kk = 0; kk < 16; ++kk) {
        int u8 = kk * 4 + quad;
        hr[kk][0] = *(const bf16x8*)(hc + u8 * 2048 + (size_t)b0 * 8);
        hr[kk][1] = *(const bf16x8*)(hc + u8 * 2048 + (size_t)b1 * 8);
      }
    }
    __builtin_amdgcn_sched_barrier(0);

    f32x4 acc[2][2] = {};
#pragma unroll
    for (int kk = 0; kk < 16; ++kk) {
      bf16x8 a0 = *(const bf16x8*)(whh_lds + kk * 1024 + quad * 256 + l16 * 8);
      bf16x8 a1 = *(const bf16x8*)(whh_lds + kk * 1024 + quad * 256 + 128 + l16 * 8);
      acc[0][0] = __builtin_amdgcn_mfma_f32_16x16x32_bf16(a0, hr[kk][0], acc[0][0], 0, 0, 0);
      acc[1][0] = __builtin_amdgcn_mfma_f32_16x16x32_bf16(a1, hr[kk][0], acc[1][0], 0, 0, 0);
      acc[0][1] = __builtin_amdgcn_mfma_f32_16x16x32_bf16(a0, hr[kk][1], acc[0][1], 0, 0, 0);
      acc[1][1] = __builtin_amdgcn_mfma_f32_16x16x32_bf16(a1, hr[kk][1], acc[1][1], 0, 0, 0);
    }
#pragma unroll
    for (int m = 0; m < 2; ++m)
#pragma unroll
      for (int i = 0; i < 2; ++i) {
        float gi = acc[m][i][0] + (float)gxr[m][i][0];
        float gf = acc[m][i][1] + (float)gxr[m][i][1];
        float gg = acc[m][i][2] + (float)gxr[m][i][2];
        float go = acc[m][i][3] + (float)gxr[m][i][3];
        float cn = sigmoidf(gf) * cst[m][i] + sigmoidf(gi) * tanhf(gg);
        float hv = sigmoidf(go) * tanhf(cn);
        cst[m][i] = cn;
        int b = (w * 2 + i) * 16 + l16;
        hstg[b * 8 + m * 4 + quad] = (bf16)hv;
      }
    __syncthreads();
    {
      unsigned long long v = *(const unsigned long long*)(hstg + tid * 4);
      __hip_atomic_store((unsigned long long*)(d.hc + (size_t)t * 262144 +
                                               (size_t)(d.slcOff + slice) * 2048 + tid * 4),
                         v, __ATOMIC_RELAXED, __HIP_MEMORY_SCOPE_AGENT);
    }
    __syncthreads();  // drains vmcnt -> hc visible before signal
    if (s < tc - 1 && tid == 0)
      __hip_atomic_fetch_add(cnt, 1, __ATOMIC_RELAXED, __HIP_MEMORY_SCOPE_AGENT);
    if (sg == Tfull - 1 && d.hfin && tid < 256) {
      const unsigned long long* p = (const unsigned long long*)(hstg + tid * 8);
      unsigned long long* r2 = (unsigned long long*)(d.hfin + (size_t)tid * 512 + unitBase);
      r2[0] = p[0]; r2[1] = p[1];
    }
    if (s < tc - 1) {
      if (w == 0) {
        int target = 64 * (s + 1), guard = 0;
        while (__hip_atomic_load(cnt, __ATOMIC_RELAXED, __HIP_MEMORY_SCOPE_AGENT) < target) {
          __builtin_amdgcn_s_sleep(2);
          if (++guard > (1 << 22)) break;  // bail (wrong answer) instead of hang
        }
      }
      __syncthreads();
    }
  }
#pragma unroll
  for (int m = 0; m < 2; ++m)
#pragma unroll
    for (int i = 0; i < 2; ++i) {
      int b = (w * 2 + i) * 16 + l16;
      d.cbuf[(size_t)b * 512 + unitBase + m * 4 + quad] = cst[m][i];
    }
}

// ---------------------------------------------------------------------------
// Fused decoder: d0 + d1 pipelined 1-step lag. CHANGE vs round 8: d1 runs the
// hh phase (hr from hc1[s-1], self-published, L2-local) FIRST and the ih
// phase (xr from hc0[s], just published cross-XCD by d0) SECOND -- giving
// d0's publish extra time to reach visibility before the xr burst lands.
// Phases accumulate independently into acc, so order is math-irrelevant.
// ---------------------------------------------------------------------------
__launch_bounds__(512, 1)
__global__ void lstm_dec_fused(
    const bf16* __restrict__ whh0, const bf16* __restrict__ xg0,
    bf16* __restrict__ hc0, const bf16* __restrict__ h0d0, float* __restrict__ c0buf,
    const bf16* __restrict__ whh1, const bf16* __restrict__ wih1, const float* __restrict__ bias1,
    bf16* __restrict__ hc1, const bf16* __restrict__ h0d1,
    float* __restrict__ c1buf, int* __restrict__ cnts) {
  const int blk = blockIdx.x;
  const int tid = threadIdx.x;
  const int w = tid >> 6, lane = tid & 63;
  const int l16 = lane & 15, quad = lane >> 4;
  constexpr int TC = 64;

  __shared__ __align__(16) bf16 wldsA[32 * 512];
  __shared__ __align__(16) bf16 wldsB[32 * 512];
  __shared__ __align__(16) bf16 hstg[256 * 8];

  int* cnt0 = cnts;
  int* cnt1 = cnts + 64;
  const int b0 = (w * 2) * 16 + l16;
  const int b1 = b0 + 16;

  if (blk < 64) {
    const int slice = blk;
    const int colBase = slice * 32;
    for (int e = tid * 8; e < 32 * 512; e += 512 * 8) {
      int c = e >> 9, k0 = e & 511;
      bf16x8 v = *(const bf16x8*)(whh0 + (size_t)(colBase + c) * 512 + k0);
      *(bf16x8*)(wldsA + ((k0 >> 3) << 8) + (c << 3)) = v;
    }
    float cst[2][2];
#pragma unroll
    for (int m = 0; m < 2; ++m)
#pragma unroll
      for (int i = 0; i < 2; ++i) {
        int b = (w * 2 + i) * 16 + l16;
        cst[m][i] = c0buf[(size_t)b * 512 + slice * 8 + m * 4 + quad];
      }
    __syncthreads();

    for (int s = 0; s < TC; ++s) {
      bf16x4 gxr[2][2];
#pragma unroll
      for (int m = 0; m < 2; ++m)
#pragma unroll
        for (int i = 0; i < 2; ++i) {
          int b = b0 + i * 16;
          gxr[m][i] = *(const bf16x4*)(xg0 + ((size_t)s * 256 + b) * 2048 + colBase + m * 16 + quad * 4);
        }
      bf16x8 hr[16][2];
      if (s == 0) {
        const bf16* hp0 = h0d0 + (size_t)b0 * 512 + quad * 8;
        const bf16* hp1 = h0d0 + (size_t)b1 * 512 + quad * 8;
#pragma unroll
        for (int kk = 0; kk < 16; ++kk) {
          hr[kk][0] = *(const bf16x8*)(hp0 + kk * 32);
          hr[kk][1] = *(const bf16x8*)(hp1 + kk * 32);
        }
      } else {
        const bf16* hc = hc0 + (size_t)(s - 1) * 131072;
#pragma unroll
        for (int kk = 0; kk < 16; ++kk) {
          int u8 = kk * 4 + quad;
          hr[kk][0] = *(const bf16x8*)(hc + u8 * 2048 + (size_t)b0 * 8);
          hr[kk][1] = *(const bf16x8*)(hc + u8 * 2048 + (size_t)b1 * 8);
        }
      }
      __builtin_amdgcn_sched_barrier(0);
      f32x4 acc[2][2] = {};
#pragma unroll
      for (int kk = 0; kk < 16; ++kk) {
        bf16x8 a0 = *(const bf16x8*)(wldsA + kk * 1024 + quad * 256 + l16 * 8);
        bf16x8 a1 = *(const bf16x8*)(wldsA + kk * 1024 + quad * 256 + 128 + l16 * 8);
        acc[0][0] = __builtin_amdgcn_mfma_f32_16x16x32_bf16(a0, hr[kk][0], acc[0][0], 0, 0, 0);
        acc[1][0] = __builtin_amdgcn_mfma_f32_16x16x32_bf16(a1, hr[kk][0], acc[1][0], 0, 0, 0);
        acc[0][1] = __builtin_amdgcn_mfma_f32_16x16x32_bf16(a0, hr[kk][1], acc[0][1], 0, 0, 0);
        acc[1][1] = __builtin_amdgcn_mfma_f32_16x16x32_bf16(a1, hr[kk][1], acc[1][1], 0, 0, 0);
      }
#pragma unroll
      for (int m = 0; m < 2; ++m)
#pragma unroll
        for (int i = 0; i < 2; ++i) {
          float gi = acc[m][i][0] + (float)gxr[m][i][0];
          float gf = acc[m][i][1] + (float)gxr[m][i][1];
          float gg = acc[m][i][2] + (float)gxr[m][i][2];
          float go = acc[m][i][3] + (float)gxr[m][i][3];
          float cn = sigmoidf(gf) * cst[m][i] + sigmoidf(gi) * tanhf(gg);
          float hv = sigmoidf(go) * tanhf(cn);
          cst[m][i] = cn;
          int b = (w * 2 + i) * 16 + l16;
          hstg[b * 8 + m * 4 + quad] = (bf16)hv;
        }
      __syncthreads();
      {
        unsigned long long v = *(const unsigned long long*)(hstg + tid * 4);
        __hip_atomic_store((unsigned long long*)(hc0 + (size_t)s * 131072 + slice * 2048 + tid * 4),
                           v, __ATOMIC_RELAXED, __HIP_MEMORY_SCOPE_AGENT);
      }
      __syncthreads();
      if (tid == 0)
        __hip_atomic_fetch_add(cnt0, 1, __ATOMIC_RELAXED, __HIP_MEMORY_SCOPE_AGENT);
      if (s < TC - 1) {
        if (w == 0) {
          int target = 64 * (s + 1), guard = 0;
          while (__hip_atomic_load(cnt0, __ATOMIC_RELAXED, __HIP_MEMORY_SCOPE_AGENT) < target) {
            __builtin_amdgcn_s_sleep(2);
            if (++guard > (1 << 22)) break;
          }
        }
        __syncthreads();
      }
    }
#pragma unroll
    for (int m = 0; m < 2; ++m)
#pragma unroll
      for (int i = 0; i < 2; ++i) {
        int b = (w * 2 + i) * 16 + l16;
        c0buf[(size_t)b * 512 + slice * 8 + m * 4 + quad] = cst[m][i];
      }
  } else {
    const int slice = blk - 64;               // 0..63
    const int colBase = slice * 32;
    for (int e = tid * 8; e < 32 * 512; e += 512 * 8) {
      int c = e >> 9, k0 = e & 511;
      bf16x8 v = *(const bf16x8*)(whh1 + (size_t)(colBase + c) * 512 + k0);
      *(bf16x8*)(wldsA + ((k0 >> 3) << 8) + (c << 3)) = v;
      bf16x8 u = *(const bf16x8*)(wih1 + (size_t)(colBase + c) * 512 + k0);
      *(bf16x8*)(wldsB + ((k0 >> 3) << 8) + (c << 3)) = u;
    }
    float gbv[2][4];
#pragma unroll
    for (int m = 0; m < 2; ++m)
#pragma unroll
      for (int r = 0; r < 4; ++r) gbv[m][r] = bias1[colBase + m * 16 + quad * 4 + r];
    float cst[2][2];
#pragma unroll
    for (int m = 0; m < 2; ++m)
#pragma unroll
      for (int i = 0; i < 2; ++i) {
        int b = (w * 2 + i) * 16 + l16;
        cst[m][i] = c1buf[(size_t)b * 512 + slice * 8 + m * 4 + quad];
      }
    __syncthreads();
    if (w == 0) {
      int guard = 0;
      while (__hip_atomic_load(cnt0, __ATOMIC_RELAXED, __HIP_MEMORY_SCOPE_AGENT) < 64) {
        __builtin_amdgcn_s_sleep(2);
        if (++guard > (1 << 22)) break;
      }
    }
    __syncthreads();

    for (int s = 0; s < TC; ++s) {
      f32x4 acc[2][2] = {};
      // phase 1 (LOCAL first): hr burst from hc1[s-1] -> hh MFMAs
      {
        bf16x8 hr[16][2];
        if (s == 0) {
          const bf16* hp0 = h0d1 + (size_t)b0 * 512 + quad * 8;
          const bf16* hp1 = h0d1 + (size_t)b1 * 512 + quad * 8;
#pragma unroll
          for (int kk = 0; kk < 16; ++kk) {
            hr[kk][0] = *(const bf16x8*)(hp0 + kk * 32);
            hr[kk][1] = *(const bf16x8*)(hp1 + kk * 32);
          }
        } else {
          const bf16* hc = hc1 + (size_t)(s - 1) * 131072;
#pragma unroll
          for (int kk = 0; kk < 16; ++kk) {
            int u8 = kk * 4 + quad;
            hr[kk][0] = *(const bf16x8*)(hc + u8 * 2048 + (size_t)b0 * 8);
            hr[kk][1] = *(const bf16x8*)(hc + u8 * 2048 + (size_t)b1 * 8);
          }
        }
        __builtin_amdgcn_sched_barrier(0);
#pragma unroll
        for (int kk = 0; kk < 16; ++kk) {
          bf16x8 a0 = *(const bf16x8*)(wldsA + kk * 1024 + quad * 256 + l16 * 8);
          bf16x8 a1 = *(const bf16x8*)(wldsA + kk * 1024 + quad * 256 + 128 + l16 * 8);
          acc[0][0] = __builtin_amdgcn_mfma_f32_16x16x32_bf16(a0, hr[kk][0], acc[0][0], 0, 0, 0);
          acc[1][0] = __builtin_amdgcn_mfma_f32_16x16x32_bf16(a1, hr[kk][0], acc[1][0], 0, 0, 0);
          acc[0][1] = __builtin_amdgcn_mfma_f32_16x16x32_bf16(a0, hr[kk][1], acc[0][1], 0, 0, 0);
          acc[1][1] = __builtin_amdgcn_mfma_f32_16x16x32_bf16(a1, hr[kk][1], acc[1][1], 0, 0, 0);
        }
      }
      // phase 2 (CROSS-XCD second): xr burst from hc0[s] -> ih MFMAs
      {
        const bf16* xc = hc0 + (size_t)s * 131072;
        bf16x8 xr[16][2];
#pragma unroll
        for (int kk = 0; kk < 16; ++kk) {
          int u8 = kk * 4 + quad;
          xr[kk][0] = *(const bf16x8*)(xc + u8 * 2048 + (size_t)b0 * 8);
          xr[kk][1] = *(const bf16x8*)(xc + u8 * 2048 + (size_t)b1 * 8);
        }
        __builtin_amdgcn_sched_barrier(0);
#pragma unroll
        for (int kk = 0; kk < 16; ++kk) {
          bf16x8 aw0 = *(const bf16x8*)(wldsB + kk * 1024 + quad * 256 + l16 * 8);
          bf16x8 aw1 = *(const bf16x8*)(wldsB + kk * 1024 + quad * 256 + 128 + l16 * 8);
          acc[0][0] = __builtin_amdgcn_mfma_f32_16x16x32_bf16(aw0, xr[kk][0], acc[0][0], 0, 0, 0);
          acc[1][0] = __builtin_amdgcn_mfma_f32_16x16x32_bf16(aw1, xr[kk][0], acc[1][0], 0, 0, 0);
          acc[0][1] = __builtin_amdgcn_mfma_f32_16x16x32_bf16(aw0, xr[kk][1], acc[0][1], 0, 0, 0);
          acc[1][1] = __builtin_amdgcn_mfma_f32_16x16x32_bf16(aw1, xr[kk][1], acc[1][1], 0, 0, 0);
        }
      }
#pragma unroll
      for (int m = 0; m < 2; ++m)
#pragma unroll
        for (int i = 0; i < 2; ++i) {
          float gi = acc[m][i][0] + gbv[m][0];
          float gf = acc[m][i][1] + gbv[m][1];
          float gg = acc[m][i][2] + gbv[m][2];
          float go = acc[m][i][3] + gbv[m][3];
          float cn = sigmoidf(gf) * cst[m][i] + sigmoidf(gi) * tanhf(gg);
          float hv = sigmoidf(go) * tanhf(cn);
          cst[m][i] = cn;
          int b = (w * 2 + i) * 16 + l16;
          hstg[b * 8 + m * 4 + quad] = (bf16)hv;
        }
      __syncthreads();
      {
        unsigned long long v = *(const unsigned long long*)(hstg + tid * 4);
        __hip_atomic_store((unsigned long long*)(hc1 + (size_t)s * 131072 + slice * 2048 + tid * 4),
                           v, __ATOMIC_RELAXED, __HIP_MEMORY_SCOPE_AGENT);
      }
      __syncthreads();
      if (s < TC - 1) {
        if (tid == 0)
          __hip_atomic_fetch_add(cnt1, 1, __ATOMIC_RELAXED, __HIP_MEMORY_SCOPE_AGENT);
        if (w == 0) {
          int t1 = 64 * (s + 1), t0n = 64 * (s + 2), guard = 0;
          while (true) {
            int v1 = __hip_atomic_load(cnt1, __ATOMIC_RELAXED, __HIP_MEMORY_SCOPE_AGENT);
            int v0 = __hip_atomic_load(cnt0, __ATOMIC_RELAXED, __HIP_MEMORY_SCOPE_AGENT);
            if (v1 >= t1 && v0 >= t0n) break;
            __builtin_amdgcn_s_sleep(2);
            if (++guard > (1 << 22)) break;
          }
        }
        __syncthreads();
      }
    }
#pragma unroll
    for (int m = 0; m < 2; ++m)
#pragma unroll
      for (int i = 0; i < 2; ++i) {
        int b = (w * 2 + i) * 16 + l16;
        c1buf[(size_t)b * 512 + slice * 8 + m * 4 + quad] = cst[m][i];
      }
  }
}

// ---------------------------------------------------------------------------
// fc_in MLP: 4 -> 32 -> 64 -> 128, exact GELU. One row per thread. fp32 in.
// ---------------------------------------------------------------------------
__launch_bounds__(256)
__global__ void fc_in_mlp(const float* __restrict__ x, bf16* __restrict__ y, int rows, int tmod,
                          const float* __restrict__ w1, const float* __restrict__ b1,
                          const float* __restrict__ w2, const float* __restrict__ b2,
                          const float* __restrict__ w3, const float* __restrict__ b3) {
  __shared__ float sm[10592];
  const int tid = threadIdx.x;
  for (int i = tid; i < 10592; i += 256) {
    float v;
    if (i < 128) v = w1[i];
    else if (i < 160) v = b1[i - 128];
    else if (i < 2208) v = w2[i - 160];
    else if (i < 2272) v = b2[i - 2208];
    else if (i < 10464) v = w3[i - 2272];
    else v = b3[i - 10464];
    sm[i] = v;
  }
  __syncthreads();
  int row = blockIdx.x * 256 + tid;
  if (row >= rows) return;
  int orow = tmod ? ((row % tmod) * 256 + row / tmod) : row;
  float xin[4];
#pragma unroll
  for (int k = 0; k < 4; ++k) xin[k] = x[(size_t)row * 4 + k];
  float h1[32];
#pragma unroll
  for (int j = 0; j < 32; ++j) {
    float a = sm[128 + j];
#pragma unroll
    for (int k = 0; k < 4; ++k) a += sm[j * 4 + k] * xin[k];
    h1[j] = geluf(a);
  }
  float h2[64];
#pragma unroll
  for (int j = 0; j < 64; ++j) {
    float a = sm[2208 + j];
#pragma unroll
    for (int k = 0; k < 32; ++k) a += sm[160 + j * 32 + k] * h1[k];
    h2[j] = geluf(a);
  }
  for (int c = 0; c < 8; ++c) {
    float accv[16];
#pragma unroll
    for (int j = 0; j < 16; ++j) accv[j] = sm[10464 + c * 16 + j];
#pragma unroll
    for (int j = 0; j < 16; ++j) {
#pragma unroll
      for (int k = 0; k < 64; ++k) accv[j] += sm[2272 + (c * 16 + j) * 64 + k] * h2[k];
    }
#pragma unroll
    for (int j = 0; j < 16; ++j) y[(size_t)orow * 128 + c * 16 + j] = (bf16)accv[j];
  }
}

// ---------------------------------------------------------------------------
// fc_out tail: h1in rows time-major (t*256+b); trg/out rows (b*64+t), fp32.
// ---------------------------------------------------------------------------
__launch_bounds__(256)
__global__ void fc_out_tail(const bf16* __restrict__ h1in, const float* __restrict__ trg,
                            float* __restrict__ out, int rows,
                            const float* __restrict__ w2, const float* __restrict__ b2,
                            const float* __restrict__ w3, const float* __restrict__ b3) {
  __shared__ float sm[2212];
  const int tid = threadIdx.x;
  for (int i = tid; i < 2212; i += 256) {
    float v;
    if (i < 2048) v = w2[i];
    else if (i < 2080) v = b2[i - 2048];
    else if (i < 2208) v = w3[i - 2080];
    else v = b3[i - 2208];
    sm[i] = v;
  }
  __syncthreads();
  int row = blockIdx.x * 256 + tid;
  if (row >= rows) return;
  int b = row >> 6, t = row & 63;
  const bf16* h1p = h1in + ((size_t)t * 256 + b) * 64;
  float h1[64];
#pragma unroll
  for (int k = 0; k < 64; ++k) h1[k] = (float)h1p[k];
  float h2[32];
#pragma unroll
  for (int j = 0; j < 32; ++j) {
    float a = sm[2048 + j];
#pragma unroll
    for (int k = 0; k < 64; ++k) a += sm[j * 64 + k] * h1[k];
    h2[j] = geluf(a);
  }
#pragma unroll
  for (int dd = 0; dd < 4; ++dd) {
    float a = sm[2208 + dd];
#pragma unroll
    for (int k = 0; k < 32; ++k) a += sm[2080 + dd * 32 + k] * h2[k];
    out[(size_t)row * 4 + dd] = trg[(size_t)row * 4 + dd] + a;
  }
}

// ---------------------------------------------------------------------------
// MHA core: one block per (batch, head). All tensors time-major (row s*256+b).
// ---------------------------------------------------------------------------
__launch_bounds__(128)
__global__ void attention_kernel(const bf16* __restrict__ Q, const bf16* __restrict__ K,
                                 const bf16* __restrict__ V, bf16* __restrict__ O) {
  __shared__ bf16 qs[64 * 32];
  __shared__ float ks[128 * 33];
  __shared__ bf16 vs[128 * 32];
  __shared__ float sc[64 * 132];
  const int b = blockIdx.x, h = blockIdx.y, tid = threadIdx.x;
  for (int i = tid; i < 64 * 32; i += 128) {
    int t = i >> 5, dd = i & 31;
    qs[i] = Q[((size_t)t * 256 + b) * 128 + h * 32 + dd];
  }
  for (int i = tid; i < 128 * 32; i += 128) {
    int s = i >> 5, dd = i & 31;
    size_t ridx = ((size_t)s * 256 + b) * 128 + h * 32 + dd;
    ks[s * 33 + dd] = (float)K[ridx];
    vs[i] = V[ridx];
  }
  __syncthreads();
  const float scale = 0.17677669529663687f;
  for (int i = tid; i < 64 * 128; i += 128) {
    int t = i >> 7, s = i & 127;
    float a = 0.f;
#pragma unroll
    for (int dd = 0; dd < 32; ++dd) a += (float)qs[t * 32 + dd] * ks[s * 33 + dd];
    sc[t * 132 + s] = a * scale;
  }
  __syncthreads();
  if (tid < 64) {
    float m = -1e30f;
    for (int s = 0; s < 128; ++s) m = fmaxf(m, sc[tid * 132 + s]);
    float sum = 0.f;
    for (int s = 0; s < 128; ++s) { float e = expf(sc[tid * 132 + s] - m); sc[tid * 132 + s] = e; sum += e; }
    float r = 1.0f / sum;
    for (int s = 0; s < 128; ++s) sc[tid * 132 + s] *= r;
  }
  __syncthreads();
  for (int i = tid; i < 64 * 32; i += 128) {
    int t = i >> 5, dd = i & 31;
    float a = 0.f;
    for (int s = 0; s < 128; ++s) a += sc[t * 132 + s] * (float)vs[s * 32 + dd];
    O[((size_t)t * 256 + b) * 128 + h * 32 + dd] = (bf16)a;
  }
}

// ---------------------------------------------------------------------------
// Prep kernels
// ---------------------------------------------------------------------------
__global__ void reorder_gate_rows(const float* __restrict__ in, bf16* __restrict__ out, int K) {
  int i = blockIdx.x * 256 + threadIdx.x;
  if (i >= 2048 * K) return;
  int r = i / K, k = i - r * K;
  int nr = 4 * (r & 511) + (r >> 9);
  out[(size_t)nr * K + k] = (bf16)in[i];
}

__global__ void combine_bias(const float* __restrict__ a, const float* __restrict__ b,
                             float* __restrict__ out) {
  int i = blockIdx.x * 256 + threadIdx.x;
  if (i >= 2048) return;
  out[4 * (i & 511) + (i >> 9)] = a[i] + b[i];
}

__global__ void f2b(const float* __restrict__ in, bf16* __restrict__ out, int n) {
  int i = blockIdx.x * 256 + threadIdx.x;
  if (i < n) out[i] = (bf16)in[i];
}

__global__ void zero_u32(uint32_t* __restrict__ p, int n) {
  int i = blockIdx.x * 256 + threadIdx.x;
  if (i < n) p[i] = 0u;
}

__global__ void dec_state_init(const bf16* __restrict__ hf, const bf16* __restrict__ hb,
                               const float* __restrict__ cf, const float* __restrict__ cb,
                               bf16* __restrict__ hout, float* __restrict__ cout) {
  int i = blockIdx.x * 256 + threadIdx.x;
  if (i >= 256 * 512) return;
  hout[i] = (bf16)((float)hf[i] + (float)hb[i]);
  cout[i] = cf[i] + cb[i];
}

// ---------------------------------------------------------------------------
// Host
// ---------------------------------------------------------------------------
extern "C" void kernel_launch(void* const* d_in, const int* in_sizes, int n_in,
                              void* d_out, int out_size, void* d_ws, size_t ws_size,
                              hipStream_t stream) {
  (void)in_sizes; (void)n_in; (void)out_size;
  const float* src = (const float*)d_in[0];
  const float* trg = (const float*)d_in[1];
  const float* fi_w1 = (const float*)d_in[2];
  const float* fi_b1 = (const float*)d_in[3];
  const float* fi_w2 = (const float*)d_in[4];
  const float* fi_b2 = (const float*)d_in[5];
  const float* fi_w3 = (const float*)d_in[6];
  const float* fi_b3 = (const float*)d_in[7];
  // LSTM param order: e0f, e0b, e1f, e1b, d0, d1
  const float* wih_in[6] = {(const float*)d_in[8],  (const float*)d_in[12], (const float*)d_in[16],
                            (const float*)d_in[20], (const float*)d_in[30], (const float*)d_in[34]};
  const float* whh_in[6] = {(const float*)d_in[9],  (const float*)d_in[13], (const float*)d_in[17],
                            (const float*)d_in[21], (const float*)d_in[31], (const float*)d_in[35]};
  const float* bih_in[6] = {(const float*)d_in[10], (const float*)d_in[14], (const float*)d_in[18],
                            (const float*)d_in[22], (const float*)d_in[32], (const float*)d_in[36]};
  const float* bhh_in[6] = {(const float*)d_in[11], (const float*)d_in[15], (const float*)d_in[19],
                            (const float*)d_in[23], (const float*)d_in[33], (const float*)d_in[37]};
  const int kin[6] = {128, 128, 1024, 1024, 128, 512};
  const float* attnfc_w = (const float*)d_in[24];
  const float* attnfc_b = (const float*)d_in[25];
  const float* inproj_w = (const float*)d_in[26];
  const float* inproj_b = (const float*)d_in[27];
  const float* outproj_w = (const float*)d_in[28];
  const float* outproj_b = (const float*)d_in[29];
  const float* fo_w1 = (const float*)d_in[38];
  const float* fo_b1 = (const float*)d_in[39];
  const float* fo_w2 = (const float*)d_in[40];
  const float* fo_b2 = (const float*)d_in[41];
  const float* fo_w3 = (const float*)d_in[42];
  const float* fo_b3 = (const float*)d_in[43];
  float* out = (float*)d_out;

  // ---- workspace carve ----
  char* base = (char*)d_ws;
  size_t o = 0;
  auto take = [&](size_t bytes) -> char* {
    char* p = base + o;
    o = (o + bytes + 255) & ~(size_t)255;
    return p;
  };
  bf16* wr_wih[6]; for (int i = 0; i < 6; ++i) wr_wih[i] = (bf16*)take((size_t)2048 * kin[i] * 2);
  bf16* wr_whh[6]; for (int i = 0; i < 6; ++i) wr_whh[i] = (bf16*)take((size_t)2048 * 512 * 2);
  float* bias_l[6]; for (int i = 0; i < 6; ++i) bias_l[i] = (float*)take(2048 * 4);
  bf16* attnfc_wb = (bf16*)take((size_t)128 * 1024 * 2);
  bf16* inproj_wb = (bf16*)take((size_t)384 * 128 * 2);
  bf16* outproj_wb = (bf16*)take((size_t)128 * 128 * 2);
  bf16* fo_w1b = (bf16*)take((size_t)64 * 512 * 2);
  bf16* h0_0 = (bf16*)take((size_t)6 * 256 * 512 * 2);   // initial h per dir
  bf16* hf_0 = (bf16*)take((size_t)6 * 256 * 512 * 2);   // final h
  float* c_0 = (float*)take((size_t)6 * 256 * 512 * 4);  // persistent c per dir
  int* flags = (int*)take(4096 * 4);
  bf16* h0_[6]; bf16* hf_[6]; float* c_[6];
  for (int i = 0; i < 6; ++i) {
    h0_[i] = h0_0 + (size_t)i * 256 * 512;
    hf_[i] = hf_0 + (size_t)i * 256 * 512;
    c_[i] = c_0 + (size_t)i * 256 * 512;
  }
  char* RA = take((size_t)64 << 20);  // x1_hc -> proj_enc/inp/qb/kb/vb/attnb/dec_in/fc1out
  char* RB = take((size_t)64 << 20);  // enc_hc -> hc0/hc1
  char* XG = take((size_t)64 << 20);  // 4 parity xg chunk buffers -> xg_dec
  bf16* embed = (bf16*)take((size_t)32768 * 128 * 2);
  size_t required = o;
  if (required > ws_size) {
    fprintf(stderr, "[kernel_launch] ws_size=%zu < required=%zu — aborting launch\n",
            ws_size, required);
    return;
  }

  bf16* x1_hc    = (bf16*)RA;                        // layer-0 out, hc layout (64MB)
  bf16* proj_enc = (bf16*)RA;                        // (128,256,128) time-major
  bf16* inp      = (bf16*)(RA + ((size_t)8 << 20));  // (64,256,128) time-major
  bf16* qb       = (bf16*)(RA + ((size_t)12 << 20));
  bf16* kb       = (bf16*)(RA + ((size_t)16 << 20));
  bf16* vb       = (bf16*)(RA + ((size_t)24 << 20));
  bf16* attnb    = (bf16*)(RA + ((size_t)32 << 20));
  bf16* dec_in   = (bf16*)(RA + ((size_t)36 << 20)); // (64,256,128) time-major
  bf16* fc1out   = (bf16*)(RA + ((size_t)40 << 20));
  bf16* enc_hc   = (bf16*)RB;                        // layer-1 out, hc layout (64MB)
  bf16* hc0      = (bf16*)RB;                        // decoder d0 hcomm (16MB)
  bf16* hc1      = (bf16*)(RB + ((size_t)20 << 20)); // decoder d1 hcomm (16MB)
  bf16* bufF[2]  = {(bf16*)XG, (bf16*)(XG + ((size_t)32 << 20))};             // fwd chunk xg (16MB each)
  bf16* bufB[2]  = {(bf16*)(XG + ((size_t)16 << 20)), (bf16*)(XG + ((size_t)48 << 20))};
  bf16* xg_dec   = (bf16*)XG;                        // (64,256,2048) decoder d0 (64MB)

  // ---- prep ----
  for (int i = 0; i < 6; ++i) {
    reorder_gate_rows<<<dim3((2048 * kin[i] + 255) / 256), 256, 0, stream>>>(wih_in[i], wr_wih[i], kin[i]);
    reorder_gate_rows<<<dim3(4096), 256, 0, stream>>>(whh_in[i], wr_whh[i], 512);
    combine_bias<<<dim3(8), 256, 0, stream>>>(bih_in[i], bhh_in[i], bias_l[i]);
  }
  f2b<<<dim3(512), 256, 0, stream>>>(attnfc_w, attnfc_wb, 128 * 1024);
  f2b<<<dim3(192), 256, 0, stream>>>(inproj_w, inproj_wb, 384 * 128);
  f2b<<<dim3(64), 256, 0, stream>>>(outproj_w, outproj_wb, 128 * 128);
  f2b<<<dim3(128), 256, 0, stream>>>(fo_w1, fo_w1b, 64 * 512);
  zero_u32<<<dim3(1024), 256, 0, stream>>>((uint32_t*)h0_0, 4 * 256 * 512 / 2);  // enc h0 = 0
  zero_u32<<<dim3(2048), 256, 0, stream>>>((uint32_t*)c_0, 4 * 256 * 512);       // enc c = 0
  zero_u32<<<dim3(16), 256, 0, stream>>>((uint32_t*)flags, 4096);

  // ---- fc_in on src (time-major) ----
  fc_in_mlp<<<dim3(128), 256, 0, stream>>>(src, embed, 32768, 128, fi_w1, fi_b1, fi_w2, fi_b2, fi_w3, fi_b3);

  constexpr int TCC = 16, NCH = 8;
  // ---- encoder layer 0: chunk-0 GEMM serial, then fused rec+next-GEMM ----
  gemm_bt<2, 2, 0, false><<<dim3(32, 16), 256, 0, stream>>>(
      embed, wr_wih[0], bias_l[0], nullptr, bufF[0], 4096, 2048, 128);
  gemm_bt<2, 2, 0, false><<<dim3(32, 16), 256, 0, stream>>>(
      embed + (size_t)(128 - TCC) * 256 * 128, wr_wih[1], bias_l[1], nullptr, bufB[0], 4096, 2048, 128);
  for (int c = 0; c < NCH; ++c) {
    GJob job{};
    if (c < NCH - 1) {
      int n = c + 1;
      job.mode = 1;
      job.Af = embed + (size_t)(TCC * n) * 256 * 128;
      job.Ab = embed + (size_t)(128 - TCC * n - TCC) * 256 * 128;
      job.Wf = wr_wih[0]; job.Wb = wr_wih[1];
      job.bsF = bias_l[0]; job.bsB = bias_l[1];
      job.outF = bufF[n & 1]; job.outB = bufB[n & 1];
    }
    RDir f{wr_whh[0], bufF[c & 1], x1_hc, 0, 0, h0_[0], c_[0], hf_[0]};
    RDir bk{wr_whh[1], bufB[c & 1], x1_hc, 64, 1, h0_[1], c_[1], hf_[1]};
    lstm_rec_g<<<dim3(256), 512, 0, stream>>>(f, bk, c * TCC, TCC, 128, flags + c * 128, job);
  }
  // ---- encoder layer 1: chunk-0 GEMM serial (needs full x1_hc), then fused ----
  gemm_hcA<2, 2, 0><<<dim3(32, 16), 256, 0, stream>>>(
      x1_hc, 0, wr_wih[2], bias_l[2], bufF[0], 4096, 2048, 1024);
  gemm_hcA<2, 2, 0><<<dim3(32, 16), 256, 0, stream>>>(
      x1_hc, 128 - TCC, wr_wih[3], bias_l[3], bufB[0], 4096, 2048, 1024);
  for (int c = 0; c < NCH; ++c) {
    GJob job{};
    if (c < NCH - 1) {
      int n = c + 1;
      job.mode = 2;
      job.Af = x1_hc; job.Ab = x1_hc;
      job.tbF = TCC * n; job.tbB = 128 - TCC * n - TCC;
      job.Wf = wr_wih[2]; job.Wb = wr_wih[3];
      job.bsF = bias_l[2]; job.bsB = bias_l[3];
      job.outF = bufF[n & 1]; job.outB = bufB[n & 1];
    }
    RDir f{wr_whh[2], bufF[c & 1], enc_hc, 0, 0, h0_[2], c_[2], hf_[2]};
    RDir bk{wr_whh[3], bufB[c & 1], enc_hc, 64, 1, h0_[3], c_[3], hf_[3]};
    lstm_rec_g<<<dim3(256), 512, 0, stream>>>(f, bk, c * TCC, TCC, 128, flags + 1024 + c * 128, job);
  }

  // ---- attnfc (tanh), reads enc_hc directly ----
  gemm_hcA<2, 2, 1><<<dim3(256, 1), 256, 0, stream>>>(
      enc_hc, 0, attnfc_wb, attnfc_b, proj_enc, 32768, 128, 1024);

  // ---- fc_in on trg (time-major) ----
  fc_in_mlp<<<dim3(64), 256, 0, stream>>>(trg, inp, 16384, 64, fi_w1, fi_b1, fi_w2, fi_b2, fi_w3, fi_b3);

  // ---- MHA (all time-major) ----
  gemm_bt<2, 2, 0, false><<<dim3(128, 1), 256, 0, stream>>>(inp, inproj_wb, inproj_b, nullptr, qb, 16384, 128, 128);
  gemm_bt<2, 2, 0, false><<<dim3(256, 1), 256, 0, stream>>>(proj_enc, inproj_wb + (size_t)128 * 128, inproj_b + 128, nullptr, kb, 32768, 128, 128);
  gemm_bt<2, 2, 0, false><<<dim3(256, 1), 256, 0, stream>>>(proj_enc, inproj_wb + (size_t)256 * 128, inproj_b + 256, nullptr, vb, 32768, 128, 128);
  attention_kernel<<<dim3(256, 4), 128, 0, stream>>>(qb, kb, vb, attnb);
  gemm_bt<2, 2, 0, true><<<dim3(128, 1), 256, 0, stream>>>(attnb, outproj_wb, outproj_b, inp, dec_in, 16384, 128, 128);

  // ---- decoder initial states (enc c_ hold final c after last chunk) ----
  dec_state_init<<<dim3(512), 256, 0, stream>>>(hf_[0], hf_[1], c_[0], c_[1], h0_[4], c_[4]);
  dec_state_init<<<dim3(512), 256, 0, stream>>>(hf_[2], hf_[3], c_[2], c_[3], h0_[5], c_[5]);

  // ---- decoder: d0 xg GEMM + fused d0/d1 pipelined recurrence ----
  gemm_bt<2, 2, 0, false><<<dim3(128, 16), 256, 0, stream>>>(dec_in, wr_wih[4], bias_l[4], nullptr, xg_dec, 16384, 2048, 128);
  lstm_dec_fused<<<dim3(128), 512, 0, stream>>>(
      wr_whh[4], xg_dec, hc0, h0_[4], c_[4],
      wr_whh[5], wr_wih[5], bias_l[5], hc1, h0_[5], c_[5],
      flags + 2048);

  // ---- fc_out (stage 1 reads hc1 hcomm layout directly) ----
  gemm_hc_fcout<<<dim3(128, 1), 128, 0, stream>>>(hc1, fo_w1b, fo_b1, fc1out, 16384, 64, 512);
  fc_out_tail<<<dim3(64), 256, 0, stream>>>(fc1out, trg, out, 16384, fo_w2, fo_b2, fo_w3, fo_b3);
}

// Round 12
// 3055.495 us; speedup vs baseline: 1.3782x; 1.1749x over previous
//
#include <hip/hip_runtime.h>
#include <cstdint>
#include <cstddef>
#include <cstdio>

typedef __bf16 bf16;
typedef __bf16 bf16x8 __attribute__((ext_vector_type(8)));
typedef __bf16 bf16x4 __attribute__((ext_vector_type(4)));
typedef float f32x4 __attribute__((ext_vector_type(4)));

#define DEVFN __device__ __forceinline__

DEVFN float geluf(float x) { return 0.5f * x * (1.0f + erff(x * 0.70710678118654752f)); }
DEVFN float sigmoidf(float x) { return 1.0f / (1.0f + expf(-x)); }

// ---------------------------------------------------------------------------
// Generic MFMA GEMM: C(M,N) = act(A(M,K) @ W(N,K)^T + bias) [+ residual]
// ---------------------------------------------------------------------------
template <int WGM, int WGN, int ACT, bool RES>
__launch_bounds__(WGM * WGN * 64)
__global__ void gemm_bt(const bf16* __restrict__ A, const bf16* __restrict__ W,
                        const float* __restrict__ bias, const bf16* __restrict__ Rsd,
                        bf16* __restrict__ C, int M, int N, int K) {
  constexpr int BM = WGM * 64, BN = WGN * 64, T = WGM * WGN * 64;
  constexpr int NA = BM * 4 / T, NB = BN * 4 / T;
  __shared__ __align__(16) char ldsA[BM * 64];
  __shared__ __align__(16) char ldsB[BN * 64];
  const int tid = threadIdx.x;
  const int lane = tid & 63, wave = tid >> 6;
  const int wm = wave % WGM, wn = wave / WGM;
  const int l16 = lane & 15, quad = lane >> 4;
  const int bm0 = blockIdx.x * BM, bn0 = blockIdx.y * BN;

  f32x4 acc[4][4] = {};
  for (int k0 = 0; k0 < K; k0 += 32) {
    bf16x8 ta[NA], tb[NB];
#pragma unroll
    for (int i = 0; i < NA; ++i) {
      int lin = i * T + tid;
      int row = lin >> 2, seg = lin & 3;
      ta[i] = *(const bf16x8*)(A + (size_t)(bm0 + row) * K + k0 + seg * 8);
    }
#pragma unroll
    for (int i = 0; i < NB; ++i) {
      int lin = i * T + tid;
      int row = lin >> 2, seg = lin & 3;
      tb[i] = *(const bf16x8*)(W + (size_t)(bn0 + row) * K + k0 + seg * 8);
    }
#pragma unroll
    for (int i = 0; i < NA; ++i) *(bf16x8*)(ldsA + (i * T + tid) * 16) = ta[i];
#pragma unroll
    for (int i = 0; i < NB; ++i) *(bf16x8*)(ldsB + (i * T + tid) * 16) = tb[i];
    __syncthreads();
    bf16x8 af[4], bfrag[4];
#pragma unroll
    for (int mi = 0; mi < 4; ++mi)
      af[mi] = *(const bf16x8*)(ldsA + (wm * 64 + mi * 16 + l16) * 64 + quad * 16);
#pragma unroll
    for (int ni = 0; ni < 4; ++ni)
      bfrag[ni] = *(const bf16x8*)(ldsB + (wn * 64 + ni * 16 + l16) * 64 + quad * 16);
#pragma unroll
    for (int mi = 0; mi < 4; ++mi)
#pragma unroll
      for (int ni = 0; ni < 4; ++ni)
        acc[mi][ni] = __builtin_amdgcn_mfma_f32_16x16x32_bf16(af[mi], bfrag[ni], acc[mi][ni], 0, 0, 0);
    __syncthreads();
  }
#pragma unroll
  for (int mi = 0; mi < 4; ++mi) {
#pragma unroll
    for (int ni = 0; ni < 4; ++ni) {
      int col = bn0 + wn * 64 + ni * 16 + l16;
      float bv = bias[col];
#pragma unroll
      for (int r = 0; r < 4; ++r) {
        int row = bm0 + wm * 64 + mi * 16 + quad * 4 + r;
        float x = acc[mi][ni][r] + bv;
        if (ACT == 1) x = tanhf(x);
        if (ACT == 2) x = geluf(x);
        size_t idx = (size_t)row * N + col;
        if (RES) x += (float)Rsd[idx];
        C[idx] = (bf16)x;
      }
    }
  }
}

// ---------------------------------------------------------------------------
// GEMM with A in LAYER-HC layout [t][128 slices][256 b][8 u] (stride 262144/t):
// A row r=(t*256+b) col u -> HC + t*262144 + (u>>3)*2048 + b*8 + (u&7).
// ---------------------------------------------------------------------------
template <int WGM, int WGN, int ACT>
__launch_bounds__(WGM * WGN * 64)
__global__ void gemm_hcA(const bf16* __restrict__ HC, int tbase, const bf16* __restrict__ W,
                         const float* __restrict__ bias, bf16* __restrict__ C,
                         int M, int N, int K) {
  constexpr int BM = WGM * 64, BN = WGN * 64, T = WGM * WGN * 64;
  constexpr int NA = BM * 4 / T, NB = BN * 4 / T;
  __shared__ __align__(16) char ldsA[BM * 64];
  __shared__ __align__(16) char ldsB[BN * 64];
  const int tid = threadIdx.x;
  const int lane = tid & 63, wave = tid >> 6;
  const int wm = wave % WGM, wn = wave / WGM;
  const int l16 = lane & 15, quad = lane >> 4;
  const int bm0 = blockIdx.x * BM, bn0 = blockIdx.y * BN;

  f32x4 acc[4][4] = {};
  for (int k0 = 0; k0 < K; k0 += 32) {
    bf16x8 ta[NA], tb[NB];
#pragma unroll
    for (int i = 0; i < NA; ++i) {
      int lin = i * T + tid;
      int row = bm0 + (lin >> 2), seg = lin & 3;
      int t = tbase + (row >> 8), b = row & 255;
      ta[i] = *(const bf16x8*)(HC + (size_t)t * 262144 + (size_t)((k0 >> 3) + seg) * 2048 + b * 8);
    }
#pragma unroll
    for (int i = 0; i < NB; ++i) {
      int lin = i * T + tid;
      int row = lin >> 2, seg = lin & 3;
      tb[i] = *(const bf16x8*)(W + (size_t)(bn0 + row) * K + k0 + seg * 8);
    }
#pragma unroll
    for (int i = 0; i < NA; ++i) *(bf16x8*)(ldsA + (i * T + tid) * 16) = ta[i];
#pragma unroll
    for (int i = 0; i < NB; ++i) *(bf16x8*)(ldsB + (i * T + tid) * 16) = tb[i];
    __syncthreads();
    bf16x8 af[4], bfrag[4];
#pragma unroll
    for (int mi = 0; mi < 4; ++mi)
      af[mi] = *(const bf16x8*)(ldsA + (wm * 64 + mi * 16 + l16) * 64 + quad * 16);
#pragma unroll
    for (int ni = 0; ni < 4; ++ni)
      bfrag[ni] = *(const bf16x8*)(ldsB + (wn * 64 + ni * 16 + l16) * 64 + quad * 16);
#pragma unroll
    for (int mi = 0; mi < 4; ++mi)
#pragma unroll
      for (int ni = 0; ni < 4; ++ni)
        acc[mi][ni] = __builtin_amdgcn_mfma_f32_16x16x32_bf16(af[mi], bfrag[ni], acc[mi][ni], 0, 0, 0);
    __syncthreads();
  }
#pragma unroll
  for (int mi = 0; mi < 4; ++mi) {
#pragma unroll
    for (int ni = 0; ni < 4; ++ni) {
      int col = bn0 + wn * 64 + ni * 16 + l16;
      float bv = bias[col];
#pragma unroll
      for (int r = 0; r < 4; ++r) {
        int row = bm0 + wm * 64 + mi * 16 + quad * 4 + r;
        float x = acc[mi][ni][r] + bv;
        if (ACT == 1) x = tanhf(x);
        if (ACT == 2) x = geluf(x);
        C[(size_t)row * N + col] = (bf16)x;
      }
    }
  }
}

// ---------------------------------------------------------------------------
// fc_out stage-1 GEMM reading A from decoder hc layout [t][64 u8][256 b][8]
// (stride 131072/t). C(M,64) = gelu(A @ W(64,512)^T + bias).
// ---------------------------------------------------------------------------
__launch_bounds__(128)
__global__ void gemm_hc_fcout(const bf16* __restrict__ HC, const bf16* __restrict__ W,
                              const float* __restrict__ bias, bf16* __restrict__ C,
                              int M, int N, int K) {
  constexpr int WGM = 2, WGN = 1;
  constexpr int BM = WGM * 64, BN = WGN * 64, T = WGM * WGN * 64;
  constexpr int NA = BM * 4 / T, NB = BN * 4 / T;
  __shared__ __align__(16) char ldsA[BM * 64];
  __shared__ __align__(16) char ldsB[BN * 64];
  const int tid = threadIdx.x;
  const int lane = tid & 63, wave = tid >> 6;
  const int wm = wave % WGM, wn = wave / WGM;
  const int l16 = lane & 15, quad = lane >> 4;
  const int bm0 = blockIdx.x * BM, bn0 = blockIdx.y * BN;

  f32x4 acc[4][4] = {};
  for (int k0 = 0; k0 < K; k0 += 32) {
    bf16x8 ta[NA], tb[NB];
#pragma unroll
    for (int i = 0; i < NA; ++i) {
      int lin = i * T + tid;
      int row = bm0 + (lin >> 2), seg = lin & 3;
      int t = row >> 8, b = row & 255;
      ta[i] = *(const bf16x8*)(HC + (size_t)t * 131072 + (size_t)((k0 >> 3) + seg) * 2048 + b * 8);
    }
#pragma unroll
    for (int i = 0; i < NB; ++i) {
      int lin = i * T + tid;
      int row = lin >> 2, seg = lin & 3;
      tb[i] = *(const bf16x8*)(W + (size_t)(bn0 + row) * K + k0 + seg * 8);
    }
#pragma unroll
    for (int i = 0; i < NA; ++i) *(bf16x8*)(ldsA + (i * T + tid) * 16) = ta[i];
#pragma unroll
    for (int i = 0; i < NB; ++i) *(bf16x8*)(ldsB + (i * T + tid) * 16) = tb[i];
    __syncthreads();
    bf16x8 af[4], bfrag[4];
#pragma unroll
    for (int mi = 0; mi < 4; ++mi)
      af[mi] = *(const bf16x8*)(ldsA + (wm * 64 + mi * 16 + l16) * 64 + quad * 16);
#pragma unroll
    for (int ni = 0; ni < 4; ++ni)
      bfrag[ni] = *(const bf16x8*)(ldsB + (wn * 64 + ni * 16 + l16) * 64 + quad * 16);
#pragma unroll
    for (int mi = 0; mi < 4; ++mi)
#pragma unroll
      for (int ni = 0; ni < 4; ++ni)
        acc[mi][ni] = __builtin_amdgcn_mfma_f32_16x16x32_bf16(af[mi], bfrag[ni], acc[mi][ni], 0, 0, 0);
    __syncthreads();
  }
#pragma unroll
  for (int mi = 0; mi < 4; ++mi) {
#pragma unroll
    for (int ni = 0; ni < 4; ++ni) {
      int col = bn0 + wn * 64 + ni * 16 + l16;
      float bv = bias[col];
#pragma unroll
      for (int r = 0; r < 4; ++r) {
        int row = bm0 + wm * 64 + mi * 16 + quad * 4 + r;
        float x = geluf(acc[mi][ni][r] + bv);
        C[(size_t)row * N + col] = (bf16)x;
      }
    }
  }
}

// ---------------------------------------------------------------------------
// Device tile-GEMM for the fused rec+gemm kernel (512 threads, BM=128,
// BN=256). A row-major (HCMODE=0) or layer-hc (HCMODE=1). N fixed = 2048.
// ---------------------------------------------------------------------------
template <int HCMODE>
DEVFN void xg_tile(const bf16* __restrict__ A, int tbase, const bf16* __restrict__ W,
                   const float* __restrict__ bias, bf16* __restrict__ C,
                   int K, int bm0, int bn0, int tid, bf16* ldsA, bf16* ldsB) {
  const int lane = tid & 63, wave = tid >> 6;
  const int wm = wave & 1, wn = wave >> 1;  // WGM=2, WGN=4
  const int l16 = lane & 15, quad = lane >> 4;
  f32x4 acc[4][4] = {};
  for (int k0 = 0; k0 < K; k0 += 32) {
    bf16x8 ta, tb0, tb1;
    {
      int row = bm0 + (tid >> 2), seg = tid & 3;
      if (HCMODE) {
        int t = tbase + (row >> 8), b = row & 255;
        ta = *(const bf16x8*)(A + (size_t)t * 262144 + (size_t)((k0 >> 3) + seg) * 2048 + b * 8);
      } else {
        ta = *(const bf16x8*)(A + (size_t)row * K + k0 + seg * 8);
      }
    }
    { int row = tid >> 2, seg = tid & 3;
      tb0 = *(const bf16x8*)(W + (size_t)(bn0 + row) * K + k0 + seg * 8); }
    { int lin = 512 + tid; int row = lin >> 2, seg = lin & 3;
      tb1 = *(const bf16x8*)(W + (size_t)(bn0 + row) * K + k0 + seg * 8); }
    *(bf16x8*)(ldsA + tid * 8) = ta;
    *(bf16x8*)(ldsB + tid * 8) = tb0;
    *(bf16x8*)(ldsB + (512 + tid) * 8) = tb1;
    __syncthreads();
    bf16x8 af[4], bfr[4];
#pragma unroll
    for (int mi = 0; mi < 4; ++mi)
      af[mi] = *(const bf16x8*)(ldsA + (wm * 64 + mi * 16 + l16) * 32 + quad * 8);
#pragma unroll
    for (int ni = 0; ni < 4; ++ni)
      bfr[ni] = *(const bf16x8*)(ldsB + (wn * 64 + ni * 16 + l16) * 32 + quad * 8);
#pragma unroll
    for (int mi = 0; mi < 4; ++mi)
#pragma unroll
      for (int ni = 0; ni < 4; ++ni)
        acc[mi][ni] = __builtin_amdgcn_mfma_f32_16x16x32_bf16(af[mi], bfr[ni], acc[mi][ni], 0, 0, 0);
    __syncthreads();
  }
#pragma unroll
  for (int mi = 0; mi < 4; ++mi) {
#pragma unroll
    for (int ni = 0; ni < 4; ++ni) {
      int col = bn0 + wn * 64 + ni * 16 + l16;
      float bv = bias[col];
#pragma unroll
      for (int r = 0; r < 4; ++r) {
        int row = bm0 + wm * 64 + mi * 16 + quad * 4 + r;
        C[(size_t)row * 2048 + col] = (bf16)(acc[mi][ni][r] + bv);
      }
    }
  }
}

// ---------------------------------------------------------------------------
// Fused encoder dispatch (round-8 config): blocks 0-127 rec (32 cols/block),
// blocks 128-255 next-chunk xg tile-GEMM. Unchanged this round.
// ---------------------------------------------------------------------------
struct RDir {
  const bf16* whh_r;   // (2048,512) bf16, rows reordered 4j+g
  const bf16* xg;      // chunk: row lt*256+b, 2048 cols (bias included)
  bf16* hc;            // layer hc buffer [Tfull][128][256][8]
  int slcOff, rev;     // slice offset (0 fwd, 64 bwd), direction
  const bf16* h0;      // initial h (256x512 row-major) for global step 0
  float* cbuf;         // persistent c (256x512 fp32)
  bf16* hfin;          // final h (row-major) or nullptr
};

struct GJob {
  int mode;            // 0 none, 1 layer0 row-major A (K=128), 2 layer1 hcA (K=1024)
  const bf16* Af; const bf16* Ab;
  int tbF, tbB;        // hcA tbases (mode 2)
  const bf16* Wf; const bf16* Wb;
  const float* bsF; const float* bsB;
  bf16* outF; bf16* outB;   // next-chunk xg buffers (4096 rows x 2048)
};

__launch_bounds__(512, 1)
__global__ void lstm_rec_g(RDir da, RDir db, int t0, int tc, int Tfull,
                           int* __restrict__ cnts, GJob job) {
  __shared__ __align__(16) char smem[36864];  // rec: 32KB whh + 4KB hstg | gemm: 8KB A + 16KB B
  const int blk = blockIdx.x;
  const int tid = threadIdx.x;

  if (blk >= 128) {
    // ----------------- GEMM role: next-chunk xg (both dirs) -----------------
    if (job.mode == 0) return;
    bf16* ldsA = (bf16*)smem;
    bf16* ldsB = (bf16*)(smem + 8192);
    const int gb = blk - 128;
    const int K = (job.mode == 2) ? 1024 : 128;
    for (int tile = gb; tile < 512; tile += 128) {
      int dir = tile >> 8;
      int rem = tile & 255;
      int mi = rem >> 3, ni = rem & 7;
      const bf16* A = dir ? job.Ab : job.Af;
      int tb = dir ? job.tbB : job.tbF;
      const bf16* W = dir ? job.Wb : job.Wf;
      const float* bs = dir ? job.bsB : job.bsF;
      bf16* C = dir ? job.outB : job.outF;
      if (job.mode == 2)
        xg_tile<1>(A, tb, W, bs, C, K, mi * 128, ni * 256, tid, ldsA, ldsB);
      else
        xg_tile<0>(A, tb, W, bs, C, K, mi * 128, ni * 256, tid, ldsA, ldsB);
    }
    return;
  }

  // ----------------- REC role: 64 blocks/dir x 32 gate-cols -----------------
  bf16* whh_lds = (bf16*)smem;
  bf16* hstg = (bf16*)(smem + 32768);
  const RDir d = (blk >= 64) ? db : da;
  const int slice = blk & 63;
  const int colBase = slice * 32, unitBase = slice * 8;
  const int w = tid >> 6, lane = tid & 63;
  const int l16 = lane & 15, quad = lane >> 4;

  for (int e = tid * 8; e < 32 * 512; e += 512 * 8) {
    int c = e >> 9, k0 = e & 511;
    bf16x8 v = *(const bf16x8*)(d.whh_r + (size_t)(colBase + c) * 512 + k0);
    *(bf16x8*)(whh_lds + ((k0 >> 3) << 8) + (c << 3)) = v;
  }
  float cst[2][2];
#pragma unroll
  for (int m = 0; m < 2; ++m)
#pragma unroll
    for (int i = 0; i < 2; ++i) {
      int b = (w * 2 + i) * 16 + l16;
      cst[m][i] = d.cbuf[(size_t)b * 512 + unitBase + m * 4 + quad];
    }
  __syncthreads();

  int* cnt = cnts + (blk & 64);
  const int b0 = (w * 2) * 16 + l16;
  const int b1 = b0 + 16;

  for (int s = 0; s < tc; ++s) {
    const int sg = t0 + s;
    const int t = d.rev ? (Tfull - 1 - sg) : sg;
    const int lt = d.rev ? (tc - 1 - s) : s;

    bf16x4 gxr[2][2];
#pragma unroll
    for (int m = 0; m < 2; ++m)
#pragma unroll
      for (int i = 0; i < 2; ++i) {
        int b = b0 + i * 16;
        gxr[m][i] = *(const bf16x4*)(d.xg + ((size_t)lt * 256 + b) * 2048 + colBase + m * 16 + quad * 4);
      }
    bf16x8 hr[16][2];
    if (sg == 0) {
      const bf16* hp0 = d.h0 + (size_t)b0 * 512 + quad * 8;
      const bf16* hp1 = d.h0 + (size_t)b1 * 512 + quad * 8;
#pragma unroll
      for (int kk = 0; kk < 16; ++kk) {
        hr[kk][0] = *(const bf16x8*)(hp0 + kk * 32);
        hr[kk][1] = *(const bf16x8*)(hp1 + kk * 32);
      }
    } else {
      const int tp = d.rev ? (t + 1) : (t - 1);
      const bf16* hc = d.hc + (size_t)tp * 262144 + (size_t)d.slcOff * 2048;
#pragma unroll
      for (int kk = 0; kk < 16; ++kk) {
        int u8 = kk * 4 + quad;
        hr[kk][0] = *(const bf16x8*)(hc + u8 * 2048 + (size_t)b0 * 8);
        hr[kk][1] = *(const bf16x8*)(hc + u8 * 2048 + (size_t)b1 * 8);
      }
    }
    __builtin_amdgcn_sched_barrier(0);

    f32x4 acc[2][2] = {};
#pragma unroll
    for (int kk = 0; kk < 16; ++kk) {
      bf16x8 a0 = *(const bf16x8*)(whh_lds + kk * 1024 + quad * 256 + l16 * 8);
      bf16x8 a1 = *(const bf16x8*)(whh_lds + kk * 1024 + quad * 256 + 128 + l16 * 8);
      acc[0][0] = __builtin_amdgcn_mfma_f32_16x16x32_bf16(a0, hr[kk][0], acc[0][0], 0, 0, 0);
      acc[1][0] = __builtin_amdgcn_mfma_f32_16x16x32_bf16(a1, hr[kk][0], acc[1][0], 0, 0, 0);
      acc[0][1] = __builtin_amdgcn_mfma_f32_16x16x32_bf16(a0, hr[kk][1], acc[0][1], 0, 0, 0);
      acc[1][1] = __builtin_amdgcn_mfma_f32_16x16x32_bf16(a1, hr[kk][1], acc[1][1], 0, 0, 0);
    }
#pragma unroll
    for (int m = 0; m < 2; ++m)
#pragma unroll
      for (int i = 0; i < 2; ++i) {
        float gi = acc[m][i][0] + (float)gxr[m][i][0];
        float gf = acc[m][i][1] + (float)gxr[m][i][1];
        float gg = acc[m][i][2] + (float)gxr[m][i][2];
        float go = acc[m][i][3] + (float)gxr[m][i][3];
        float cn = sigmoidf(gf) * cst[m][i] + sigmoidf(gi) * tanhf(gg);
        float hv = sigmoidf(go) * tanhf(cn);
        cst[m][i] = cn;
        int b = (w * 2 + i) * 16 + l16;
        hstg[b * 8 + m * 4 + quad] = (bf16)hv;
      }
    __syncthreads();
    {
      unsigned long long v = *(const unsigned long long*)(hstg + tid * 4);
      __hip_atomic_store((unsigned long long*)(d.hc + (size_t)t * 262144 +
                                               (size_t)(d.slcOff + slice) * 2048 + tid * 4),
                         v, __ATOMIC_RELAXED, __HIP_MEMORY_SCOPE_AGENT);
    }
    __syncthreads();  // drains vmcnt -> hc visible before signal
    if (s < tc - 1 && tid == 0)
      __hip_atomic_fetch_add(cnt, 1, __ATOMIC_RELAXED, __HIP_MEMORY_SCOPE_AGENT);
    if (sg == Tfull - 1 && d.hfin && tid < 256) {
      const unsigned long long* p = (const unsigned long long*)(hstg + tid * 8);
      unsigned long long* r2 = (unsigned long long*)(d.hfin + (size_t)tid * 512 + unitBase);
      r2[0] = p[0]; r2[1] = p[1];
    }
    if (s < tc - 1) {
      if (w == 0) {
        int target = 64 * (s + 1), guard = 0;
        while (__hip_atomic_load(cnt, __ATOMIC_RELAXED, __HIP_MEMORY_SCOPE_AGENT) < target) {
          __builtin_amdgcn_s_sleep(2);
          if (++guard > (1 << 22)) break;  // bail (wrong answer) instead of hang
        }
      }
      __syncthreads();
    }
  }
#pragma unroll
  for (int m = 0; m < 2; ++m)
#pragma unroll
    for (int i = 0; i < 2; ++i) {
      int b = (w * 2 + i) * 16 + l16;
      d.cbuf[(size_t)b * 512 + unitBase + m * 4 + quad] = cst[m][i];
    }
}

// ---------------------------------------------------------------------------
// Fused decoder, batch-split: d0 = 128 blocks (slice=blk>>1, bh=blk&1), each
// 32 gate-cols x 128 batch rows; d1 = 128 blocks likewise. Key win: d1's step
// is now ONE 32-load burst (hr from hc1[s-1] local + xr from hc0[s]) -> 64
// MFMAs -- one fabric latency instead of two serialized phases (64 loads
// never fit registers; 32 do). Publish: each block writes its contiguous
// single-writer 2KB half-slice (slice*2048 + bh*1024); global hc layout
// [u8][b][8] unchanged -> all readers untouched. Counters: 128/step.
// ---------------------------------------------------------------------------
__launch_bounds__(512, 1)
__global__ void lstm_dec_fused(
    const bf16* __restrict__ whh0, const bf16* __restrict__ xg0,
    bf16* __restrict__ hc0, const bf16* __restrict__ h0d0, float* __restrict__ c0buf,
    const bf16* __restrict__ whh1, const bf16* __restrict__ wih1, const float* __restrict__ bias1,
    bf16* __restrict__ hc1, const bf16* __restrict__ h0d1,
    float* __restrict__ c1buf, int* __restrict__ cnts) {
  const int blk = blockIdx.x;
  const int tid = threadIdx.x;
  const int w = tid >> 6, lane = tid & 63;
  const int l16 = lane & 15, quad = lane >> 4;
  constexpr int TC = 64;

  __shared__ __align__(16) bf16 wldsA[32 * 512];
  __shared__ __align__(16) bf16 wldsB[32 * 512];
  __shared__ __align__(16) bf16 hstg[128 * 8];

  int* cnt0 = cnts;
  int* cnt1 = cnts + 64;

  if (blk < 128) {
    // ---------------- d0: slice x half-batch ----------------
    const int slice = blk >> 1, bh = blk & 1;
    const int colBase = slice * 32;
    const int b0 = bh * 128 + w * 16 + l16;   // one 16-row fragment per wave
    for (int e = tid * 8; e < 32 * 512; e += 512 * 8) {
      int c = e >> 9, k0 = e & 511;
      bf16x8 v = *(const bf16x8*)(whh0 + (size_t)(colBase + c) * 512 + k0);
      *(bf16x8*)(wldsA + ((k0 >> 3) << 8) + (c << 3)) = v;
    }
    float cst[2];
#pragma unroll
    for (int m = 0; m < 2; ++m)
      cst[m] = c0buf[(size_t)b0 * 512 + slice * 8 + m * 4 + quad];
    __syncthreads();

    for (int s = 0; s < TC; ++s) {
      bf16x4 gxr[2];
#pragma unroll
      for (int m = 0; m < 2; ++m)
        gxr[m] = *(const bf16x4*)(xg0 + ((size_t)s * 256 + b0) * 2048 + colBase + m * 16 + quad * 4);
      bf16x8 hr[16];
      if (s == 0) {
        const bf16* hp = h0d0 + (size_t)b0 * 512 + quad * 8;
#pragma unroll
        for (int kk = 0; kk < 16; ++kk) hr[kk] = *(const bf16x8*)(hp + kk * 32);
      } else {
        const bf16* hc = hc0 + (size_t)(s - 1) * 131072;
#pragma unroll
        for (int kk = 0; kk < 16; ++kk) {
          int u8 = kk * 4 + quad;
          hr[kk] = *(const bf16x8*)(hc + u8 * 2048 + (size_t)b0 * 8);
        }
      }
      __builtin_amdgcn_sched_barrier(0);
      f32x4 acc[2] = {};
#pragma unroll
      for (int kk = 0; kk < 16; ++kk) {
        bf16x8 a0 = *(const bf16x8*)(wldsA + kk * 1024 + quad * 256 + l16 * 8);
        bf16x8 a1 = *(const bf16x8*)(wldsA + kk * 1024 + quad * 256 + 128 + l16 * 8);
        acc[0] = __builtin_amdgcn_mfma_f32_16x16x32_bf16(a0, hr[kk], acc[0], 0, 0, 0);
        acc[1] = __builtin_amdgcn_mfma_f32_16x16x32_bf16(a1, hr[kk], acc[1], 0, 0, 0);
      }
#pragma unroll
      for (int m = 0; m < 2; ++m) {
        float gi = acc[m][0] + (float)gxr[m][0];
        float gf = acc[m][1] + (float)gxr[m][1];
        float gg = acc[m][2] + (float)gxr[m][2];
        float go = acc[m][3] + (float)gxr[m][3];
        float cn = sigmoidf(gf) * cst[m] + sigmoidf(gi) * tanhf(gg);
        float hv = sigmoidf(go) * tanhf(cn);
        cst[m] = cn;
        int lb = w * 16 + l16;
        hstg[lb * 8 + m * 4 + quad] = (bf16)hv;
      }
      __syncthreads();
      if (tid < 256) {  // contiguous single-writer 2KB half-slice
        unsigned long long v = *(const unsigned long long*)(hstg + tid * 4);
        __hip_atomic_store((unsigned long long*)(hc0 + (size_t)s * 131072 +
                                                 slice * 2048 + bh * 1024 + tid * 4),
                           v, __ATOMIC_RELAXED, __HIP_MEMORY_SCOPE_AGENT);
      }
      __syncthreads();  // hcomm visible
      if (tid == 0)     // every step incl. last (d1 consumes all 64)
        __hip_atomic_fetch_add(cnt0, 1, __ATOMIC_RELAXED, __HIP_MEMORY_SCOPE_AGENT);
      if (s < TC - 1) {
        if (w == 0) {
          int target = 128 * (s + 1), guard = 0;
          while (__hip_atomic_load(cnt0, __ATOMIC_RELAXED, __HIP_MEMORY_SCOPE_AGENT) < target) {
            __builtin_amdgcn_s_sleep(2);
            if (++guard > (1 << 22)) break;
          }
        }
        __syncthreads();
      }
    }
#pragma unroll
    for (int m = 0; m < 2; ++m)
      c0buf[(size_t)b0 * 512 + slice * 8 + m * 4 + quad] = cst[m];
  } else {
    // ---------------- d1: slice x half-batch, single dual burst ------------
    const int idx = blk - 128, slice = idx >> 1, bh = idx & 1;
    const int colBase = slice * 32;
    const int b0 = bh * 128 + w * 16 + l16;
    for (int e = tid * 8; e < 32 * 512; e += 512 * 8) {
      int c = e >> 9, k0 = e & 511;
      bf16x8 v = *(const bf16x8*)(whh1 + (size_t)(colBase + c) * 512 + k0);
      *(bf16x8*)(wldsA + ((k0 >> 3) << 8) + (c << 3)) = v;
      bf16x8 u = *(const bf16x8*)(wih1 + (size_t)(colBase + c) * 512 + k0);
      *(bf16x8*)(wldsB + ((k0 >> 3) << 8) + (c << 3)) = u;
    }
    float gbv[2][4];
#pragma unroll
    for (int m = 0; m < 2; ++m)
#pragma unroll
      for (int r = 0; r < 4; ++r) gbv[m][r] = bias1[colBase + m * 16 + quad * 4 + r];
    float cst[2];
#pragma unroll
    for (int m = 0; m < 2; ++m)
      cst[m] = c1buf[(size_t)b0 * 512 + slice * 8 + m * 4 + quad];
    __syncthreads();
    if (w == 0) {  // wait for hc0[0]
      int guard = 0;
      while (__hip_atomic_load(cnt0, __ATOMIC_RELAXED, __HIP_MEMORY_SCOPE_AGENT) < 128) {
        __builtin_amdgcn_s_sleep(2);
        if (++guard > (1 << 22)) break;
      }
    }
    __syncthreads();

    for (int s = 0; s < TC; ++s) {
      // single burst: hr (local hc1) + xr (cross hc0) -> 32 loads in flight
      bf16x8 hr[16], xr[16];
      if (s == 0) {
        const bf16* hp = h0d1 + (size_t)b0 * 512 + quad * 8;
#pragma unroll
        for (int kk = 0; kk < 16; ++kk) hr[kk] = *(const bf16x8*)(hp + kk * 32);
      } else {
        const bf16* hc = hc1 + (size_t)(s - 1) * 131072;
#pragma unroll
        for (int kk = 0; kk < 16; ++kk) {
          int u8 = kk * 4 + quad;
          hr[kk] = *(const bf16x8*)(hc + u8 * 2048 + (size_t)b0 * 8);
        }
      }
      {
        const bf16* xc = hc0 + (size_t)s * 131072;
#pragma unroll
        for (int kk = 0; kk < 16; ++kk) {
          int u8 = kk * 4 + quad;
          xr[kk] = *(const bf16x8*)(xc + u8 * 2048 + (size_t)b0 * 8);
        }
      }
      __builtin_amdgcn_sched_barrier(0);
      f32x4 acc[2] = {};
#pragma unroll
      for (int kk = 0; kk < 16; ++kk) {
        bf16x8 a0 = *(const bf16x8*)(wldsA + kk * 1024 + quad * 256 + l16 * 8);
        bf16x8 a1 = *(const bf16x8*)(wldsA + kk * 1024 + quad * 256 + 128 + l16 * 8);
        acc[0] = __builtin_amdgcn_mfma_f32_16x16x32_bf16(a0, hr[kk], acc[0], 0, 0, 0);
        acc[1] = __builtin_amdgcn_mfma_f32_16x16x32_bf16(a1, hr[kk], acc[1], 0, 0, 0);
      }
#pragma unroll
      for (int kk = 0; kk < 16; ++kk) {
        bf16x8 aw0 = *(const bf16x8*)(wldsB + kk * 1024 + quad * 256 + l16 * 8);
        bf16x8 aw1 = *(const bf16x8*)(wldsB + kk * 1024 + quad * 256 + 128 + l16 * 8);
        acc[0] = __builtin_amdgcn_mfma_f32_16x16x32_bf16(aw0, xr[kk], acc[0], 0, 0, 0);
        acc[1] = __builtin_amdgcn_mfma_f32_16x16x32_bf16(aw1, xr[kk], acc[1], 0, 0, 0);
      }
#pragma unroll
      for (int m = 0; m < 2; ++m) {
        float gi = acc[m][0] + gbv[m][0];
        float gf = acc[m][1] + gbv[m][1];
        float gg = acc[m][2] + gbv[m][2];
        float go = acc[m][3] + gbv[m][3];
        float cn = sigmoidf(gf) * cst[m] + sigmoidf(gi) * tanhf(gg);
        float hv = sigmoidf(go) * tanhf(cn);
        cst[m] = cn;
        int lb = w * 16 + l16;
        hstg[lb * 8 + m * 4 + quad] = (bf16)hv;
      }
      __syncthreads();
      if (tid < 256) {
        unsigned long long v = *(const unsigned long long*)(hstg + tid * 4);
        __hip_atomic_store((unsigned long long*)(hc1 + (size_t)s * 131072 +
                                                 slice * 2048 + bh * 1024 + tid * 4),
                           v, __ATOMIC_RELAXED, __HIP_MEMORY_SCOPE_AGENT);
      }
      __syncthreads();  // hcomm visible
      if (s < TC - 1) {
        if (tid == 0)
          __hip_atomic_fetch_add(cnt1, 1, __ATOMIC_RELAXED, __HIP_MEMORY_SCOPE_AGENT);
        if (w == 0) {
          int t1 = 128 * (s + 1), t0n = 128 * (s + 2), guard = 0;
          while (true) {
            int v1 = __hip_atomic_load(cnt1, __ATOMIC_RELAXED, __HIP_MEMORY_SCOPE_AGENT);
            int v0 = __hip_atomic_load(cnt0, __ATOMIC_RELAXED, __HIP_MEMORY_SCOPE_AGENT);
            if (v1 >= t1 && v0 >= t0n) break;
            __builtin_amdgcn_s_sleep(2);
            if (++guard > (1 << 22)) break;
          }
        }
        __syncthreads();
      }
    }
#pragma unroll
    for (int m = 0; m < 2; ++m)
      c1buf[(size_t)b0 * 512 + slice * 8 + m * 4 + quad] = cst[m];
  }
}

// ---------------------------------------------------------------------------
// fc_in MLP: 4 -> 32 -> 64 -> 128, exact GELU. One row per thread. fp32 in.
// ---------------------------------------------------------------------------
__launch_bounds__(256)
__global__ void fc_in_mlp(const float* __restrict__ x, bf16* __restrict__ y, int rows, int tmod,
                          const float* __restrict__ w1, const float* __restrict__ b1,
                          const float* __restrict__ w2, const float* __restrict__ b2,
                          const float* __restrict__ w3, const float* __restrict__ b3) {
  __shared__ float sm[10592];
  const int tid = threadIdx.x;
  for (int i = tid; i < 10592; i += 256) {
    float v;
    if (i < 128) v = w1[i];
    else if (i < 160) v = b1[i - 128];
    else if (i < 2208) v = w2[i - 160];
    else if (i < 2272) v = b2[i - 2208];
    else if (i < 10464) v = w3[i - 2272];
    else v = b3[i - 10464];
    sm[i] = v;
  }
  __syncthreads();
  int row = blockIdx.x * 256 + tid;
  if (row >= rows) return;
  int orow = tmod ? ((row % tmod) * 256 + row / tmod) : row;
  float xin[4];
#pragma unroll
  for (int k = 0; k < 4; ++k) xin[k] = x[(size_t)row * 4 + k];
  float h1[32];
#pragma unroll
  for (int j = 0; j < 32; ++j) {
    float a = sm[128 + j];
#pragma unroll
    for (int k = 0; k < 4; ++k) a += sm[j * 4 + k] * xin[k];
    h1[j] = geluf(a);
  }
  float h2[64];
#pragma unroll
  for (int j = 0; j < 64; ++j) {
    float a = sm[2208 + j];
#pragma unroll
    for (int k = 0; k < 32; ++k) a += sm[160 + j * 32 + k] * h1[k];
    h2[j] = geluf(a);
  }
  for (int c = 0; c < 8; ++c) {
    float accv[16];
#pragma unroll
    for (int j = 0; j < 16; ++j) accv[j] = sm[10464 + c * 16 + j];
#pragma unroll
    for (int j = 0; j < 16; ++j) {
#pragma unroll
      for (int k = 0; k < 64; ++k) accv[j] += sm[2272 + (c * 16 + j) * 64 + k] * h2[k];
    }
#pragma unroll
    for (int j = 0; j < 16; ++j) y[(size_t)orow * 128 + c * 16 + j] = (bf16)accv[j];
  }
}

// ---------------------------------------------------------------------------
// fc_out tail: h1in rows time-major (t*256+b); trg/out rows (b*64+t), fp32.
// ---------------------------------------------------------------------------
__launch_bounds__(256)
__global__ void fc_out_tail(const bf16* __restrict__ h1in, const float* __restrict__ trg,
                            float* __restrict__ out, int rows,
                            const float* __restrict__ w2, const float* __restrict__ b2,
                            const float* __restrict__ w3, const float* __restrict__ b3) {
  __shared__ float sm[2212];
  const int tid = threadIdx.x;
  for (int i = tid; i < 2212; i += 256) {
    float v;
    if (i < 2048) v = w2[i];
    else if (i < 2080) v = b2[i - 2048];
    else if (i < 2208) v = w3[i - 2080];
    else v = b3[i - 2208];
    sm[i] = v;
  }
  __syncthreads();
  int row = blockIdx.x * 256 + tid;
  if (row >= rows) return;
  int b = row >> 6, t = row & 63;
  const bf16* h1p = h1in + ((size_t)t * 256 + b) * 64;
  float h1[64];
#pragma unroll
  for (int k = 0; k < 64; ++k) h1[k] = (float)h1p[k];
  float h2[32];
#pragma unroll
  for (int j = 0; j < 32; ++j) {
    float a = sm[2048 + j];
#pragma unroll
    for (int k = 0; k < 64; ++k) a += sm[j * 64 + k] * h1[k];
    h2[j] = geluf(a);
  }
#pragma unroll
  for (int dd = 0; dd < 4; ++dd) {
    float a = sm[2208 + dd];
#pragma unroll
    for (int k = 0; k < 32; ++k) a += sm[2080 + dd * 32 + k] * h2[k];
    out[(size_t)row * 4 + dd] = trg[(size_t)row * 4 + dd] + a;
  }
}

// ---------------------------------------------------------------------------
// MHA core: one block per (batch, head). All tensors time-major (row s*256+b).
// ---------------------------------------------------------------------------
__launch_bounds__(128)
__global__ void attention_kernel(const bf16* __restrict__ Q, const bf16* __restrict__ K,
                                 const bf16* __restrict__ V, bf16* __restrict__ O) {
  __shared__ bf16 qs[64 * 32];
  __shared__ float ks[128 * 33];
  __shared__ bf16 vs[128 * 32];
  __shared__ float sc[64 * 132];
  const int b = blockIdx.x, h = blockIdx.y, tid = threadIdx.x;
  for (int i = tid; i < 64 * 32; i += 128) {
    int t = i >> 5, dd = i & 31;
    qs[i] = Q[((size_t)t * 256 + b) * 128 + h * 32 + dd];
  }
  for (int i = tid; i < 128 * 32; i += 128) {
    int s = i >> 5, dd = i & 31;
    size_t ridx = ((size_t)s * 256 + b) * 128 + h * 32 + dd;
    ks[s * 33 + dd] = (float)K[ridx];
    vs[i] = V[ridx];
  }
  __syncthreads();
  const float scale = 0.17677669529663687f;
  for (int i = tid; i < 64 * 128; i += 128) {
    int t = i >> 7, s = i & 127;
    float a = 0.f;
#pragma unroll
    for (int dd = 0; dd < 32; ++dd) a += (float)qs[t * 32 + dd] * ks[s * 33 + dd];
    sc[t * 132 + s] = a * scale;
  }
  __syncthreads();
  if (tid < 64) {
    float m = -1e30f;
    for (int s = 0; s < 128; ++s) m = fmaxf(m, sc[tid * 132 + s]);
    float sum = 0.f;
    for (int s = 0; s < 128; ++s) { float e = expf(sc[tid * 132 + s] - m); sc[tid * 132 + s] = e; sum += e; }
    float r = 1.0f / sum;
    for (int s = 0; s < 128; ++s) sc[tid * 132 + s] *= r;
  }
  __syncthreads();
  for (int i = tid; i < 64 * 32; i += 128) {
    int t = i >> 5, dd = i & 31;
    float a = 0.f;
    for (int s = 0; s < 128; ++s) a += sc[t * 132 + s] * (float)vs[s * 32 + dd];
    O[((size_t)t * 256 + b) * 128 + h * 32 + dd] = (bf16)a;
  }
}

// ---------------------------------------------------------------------------
// Prep kernels
// ---------------------------------------------------------------------------
__global__ void reorder_gate_rows(const float* __restrict__ in, bf16* __restrict__ out, int K) {
  int i = blockIdx.x * 256 + threadIdx.x;
  if (i >= 2048 * K) return;
  int r = i / K, k = i - r * K;
  int nr = 4 * (r & 511) + (r >> 9);
  out[(size_t)nr * K + k] = (bf16)in[i];
}

__global__ void combine_bias(const float* __restrict__ a, const float* __restrict__ b,
                             float* __restrict__ out) {
  int i = blockIdx.x * 256 + threadIdx.x;
  if (i >= 2048) return;
  out[4 * (i & 511) + (i >> 9)] = a[i] + b[i];
}

__global__ void f2b(const float* __restrict__ in, bf16* __restrict__ out, int n) {
  int i = blockIdx.x * 256 + threadIdx.x;
  if (i < n) out[i] = (bf16)in[i];
}

__global__ void zero_u32(uint32_t* __restrict__ p, int n) {
  int i = blockIdx.x * 256 + threadIdx.x;
  if (i < n) p[i] = 0u;
}

__global__ void dec_state_init(const bf16* __restrict__ hf, const bf16* __restrict__ hb,
                               const float* __restrict__ cf, const float* __restrict__ cb,
                               bf16* __restrict__ hout, float* __restrict__ cout) {
  int i = blockIdx.x * 256 + threadIdx.x;
  if (i >= 256 * 512) return;
  hout[i] = (bf16)((float)hf[i] + (float)hb[i]);
  cout[i] = cf[i] + cb[i];
}

// ---------------------------------------------------------------------------
// Host
// ---------------------------------------------------------------------------
extern "C" void kernel_launch(void* const* d_in, const int* in_sizes, int n_in,
                              void* d_out, int out_size, void* d_ws, size_t ws_size,
                              hipStream_t stream) {
  (void)in_sizes; (void)n_in; (void)out_size;
  const float* src = (const float*)d_in[0];
  const float* trg = (const float*)d_in[1];
  const float* fi_w1 = (const float*)d_in[2];
  const float* fi_b1 = (const float*)d_in[3];
  const float* fi_w2 = (const float*)d_in[4];
  const float* fi_b2 = (const float*)d_in[5];
  const float* fi_w3 = (const float*)d_in[6];
  const float* fi_b3 = (const float*)d_in[7];
  // LSTM param order: e0f, e0b, e1f, e1b, d0, d1
  const float* wih_in[6] = {(const float*)d_in[8],  (const float*)d_in[12], (const float*)d_in[16],
                            (const float*)d_in[20], (const float*)d_in[30], (const float*)d_in[34]};
  const float* whh_in[6] = {(const float*)d_in[9],  (const float*)d_in[13], (const float*)d_in[17],
                            (const float*)d_in[21], (const float*)d_in[31], (const float*)d_in[35]};
  const float* bih_in[6] = {(const float*)d_in[10], (const float*)d_in[14], (const float*)d_in[18],
                            (const float*)d_in[22], (const float*)d_in[32], (const float*)d_in[36]};
  const float* bhh_in[6] = {(const float*)d_in[11], (const float*)d_in[15], (const float*)d_in[19],
                            (const float*)d_in[23], (const float*)d_in[33], (const float*)d_in[37]};
  const int kin[6] = {128, 128, 1024, 1024, 128, 512};
  const float* attnfc_w = (const float*)d_in[24];
  const float* attnfc_b = (const float*)d_in[25];
  const float* inproj_w = (const float*)d_in[26];
  const float* inproj_b = (const float*)d_in[27];
  const float* outproj_w = (const float*)d_in[28];
  const float* outproj_b = (const float*)d_in[29];
  const float* fo_w1 = (const float*)d_in[38];
  const float* fo_b1 = (const float*)d_in[39];
  const float* fo_w2 = (const float*)d_in[40];
  const float* fo_b2 = (const float*)d_in[41];
  const float* fo_w3 = (const float*)d_in[42];
  const float* fo_b3 = (const float*)d_in[43];
  float* out = (float*)d_out;

  // ---- workspace carve ----
  char* base = (char*)d_ws;
  size_t o = 0;
  auto take = [&](size_t bytes) -> char* {
    char* p = base + o;
    o = (o + bytes + 255) & ~(size_t)255;
    return p;
  };
  bf16* wr_wih[6]; for (int i = 0; i < 6; ++i) wr_wih[i] = (bf16*)take((size_t)2048 * kin[i] * 2);
  bf16* wr_whh[6]; for (int i = 0; i < 6; ++i) wr_whh[i] = (bf16*)take((size_t)2048 * 512 * 2);
  float* bias_l[6]; for (int i = 0; i < 6; ++i) bias_l[i] = (float*)take(2048 * 4);
  bf16* attnfc_wb = (bf16*)take((size_t)128 * 1024 * 2);
  bf16* inproj_wb = (bf16*)take((size_t)384 * 128 * 2);
  bf16* outproj_wb = (bf16*)take((size_t)128 * 128 * 2);
  bf16* fo_w1b = (bf16*)take((size_t)64 * 512 * 2);
  bf16* h0_0 = (bf16*)take((size_t)6 * 256 * 512 * 2);   // initial h per dir
  bf16* hf_0 = (bf16*)take((size_t)6 * 256 * 512 * 2);   // final h
  float* c_0 = (float*)take((size_t)6 * 256 * 512 * 4);  // persistent c per dir
  int* flags = (int*)take(4096 * 4);
  bf16* h0_[6]; bf16* hf_[6]; float* c_[6];
  for (int i = 0; i < 6; ++i) {
    h0_[i] = h0_0 + (size_t)i * 256 * 512;
    hf_[i] = hf_0 + (size_t)i * 256 * 512;
    c_[i] = c_0 + (size_t)i * 256 * 512;
  }
  char* RA = take((size_t)64 << 20);  // x1_hc -> proj_enc/inp/qb/kb/vb/attnb/dec_in/fc1out
  char* RB = take((size_t)64 << 20);  // enc_hc -> hc0/hc1
  char* XG = take((size_t)64 << 20);  // 4 parity xg chunk buffers -> xg_dec
  bf16* embed = (bf16*)take((size_t)32768 * 128 * 2);
  size_t required = o;
  if (required > ws_size) {
    fprintf(stderr, "[kernel_launch] ws_size=%zu < required=%zu — aborting launch\n",
            ws_size, required);
    return;
  }

  bf16* x1_hc    = (bf16*)RA;                        // layer-0 out, hc layout (64MB)
  bf16* proj_enc = (bf16*)RA;                        // (128,256,128) time-major
  bf16* inp      = (bf16*)(RA + ((size_t)8 << 20));  // (64,256,128) time-major
  bf16* qb       = (bf16*)(RA + ((size_t)12 << 20));
  bf16* kb       = (bf16*)(RA + ((size_t)16 << 20));
  bf16* vb       = (bf16*)(RA + ((size_t)24 << 20));
  bf16* attnb    = (bf16*)(RA + ((size_t)32 << 20));
  bf16* dec_in   = (bf16*)(RA + ((size_t)36 << 20)); // (64,256,128) time-major
  bf16* fc1out   = (bf16*)(RA + ((size_t)40 << 20));
  bf16* enc_hc   = (bf16*)RB;                        // layer-1 out, hc layout (64MB)
  bf16* hc0      = (bf16*)RB;                        // decoder d0 hcomm (16MB)
  bf16* hc1      = (bf16*)(RB + ((size_t)20 << 20)); // decoder d1 hcomm (16MB)
  bf16* bufF[2]  = {(bf16*)XG, (bf16*)(XG + ((size_t)32 << 20))};             // fwd chunk xg (16MB each)
  bf16* bufB[2]  = {(bf16*)(XG + ((size_t)16 << 20)), (bf16*)(XG + ((size_t)48 << 20))};
  bf16* xg_dec   = (bf16*)XG;                        // (64,256,2048) decoder d0 (64MB)

  // ---- prep ----
  for (int i = 0; i < 6; ++i) {
    reorder_gate_rows<<<dim3((2048 * kin[i] + 255) / 256), 256, 0, stream>>>(wih_in[i], wr_wih[i], kin[i]);
    reorder_gate_rows<<<dim3(4096), 256, 0, stream>>>(whh_in[i], wr_whh[i], 512);
    combine_bias<<<dim3(8), 256, 0, stream>>>(bih_in[i], bhh_in[i], bias_l[i]);
  }
  f2b<<<dim3(512), 256, 0, stream>>>(attnfc_w, attnfc_wb, 128 * 1024);
  f2b<<<dim3(192), 256, 0, stream>>>(inproj_w, inproj_wb, 384 * 128);
  f2b<<<dim3(64), 256, 0, stream>>>(outproj_w, outproj_wb, 128 * 128);
  f2b<<<dim3(128), 256, 0, stream>>>(fo_w1, fo_w1b, 64 * 512);
  zero_u32<<<dim3(1024), 256, 0, stream>>>((uint32_t*)h0_0, 4 * 256 * 512 / 2);  // enc h0 = 0
  zero_u32<<<dim3(2048), 256, 0, stream>>>((uint32_t*)c_0, 4 * 256 * 512);       // enc c = 0
  zero_u32<<<dim3(16), 256, 0, stream>>>((uint32_t*)flags, 4096);

  // ---- fc_in on src (time-major) ----
  fc_in_mlp<<<dim3(128), 256, 0, stream>>>(src, embed, 32768, 128, fi_w1, fi_b1, fi_w2, fi_b2, fi_w3, fi_b3);

  constexpr int TCC = 16, NCH = 8;
  // ---- encoder layer 0: chunk-0 GEMM serial, then fused rec+next-GEMM ----
  gemm_bt<2, 2, 0, false><<<dim3(32, 16), 256, 0, stream>>>(
      embed, wr_wih[0], bias_l[0], nullptr, bufF[0], 4096, 2048, 128);
  gemm_bt<2, 2, 0, false><<<dim3(32, 16), 256, 0, stream>>>(
      embed + (size_t)(128 - TCC) * 256 * 128, wr_wih[1], bias_l[1], nullptr, bufB[0], 4096, 2048, 128);
  for (int c = 0; c < NCH; ++c) {
    GJob job{};
    if (c < NCH - 1) {
      int n = c + 1;
      job.mode = 1;
      job.Af = embed + (size_t)(TCC * n) * 256 * 128;
      job.Ab = embed + (size_t)(128 - TCC * n - TCC) * 256 * 128;
      job.Wf = wr_wih[0]; job.Wb = wr_wih[1];
      job.bsF = bias_l[0]; job.bsB = bias_l[1];
      job.outF = bufF[n & 1]; job.outB = bufB[n & 1];
    }
    RDir f{wr_whh[0], bufF[c & 1], x1_hc, 0, 0, h0_[0], c_[0], hf_[0]};
    RDir bk{wr_whh[1], bufB[c & 1], x1_hc, 64, 1, h0_[1], c_[1], hf_[1]};
    lstm_rec_g<<<dim3(256), 512, 0, stream>>>(f, bk, c * TCC, TCC, 128, flags + c * 128, job);
  }
  // ---- encoder layer 1: chunk-0 GEMM serial (needs full x1_hc), then fused ----
  gemm_hcA<2, 2, 0><<<dim3(32, 16), 256, 0, stream>>>(
      x1_hc, 0, wr_wih[2], bias_l[2], bufF[0], 4096, 2048, 1024);
  gemm_hcA<2, 2, 0><<<dim3(32, 16), 256, 0, stream>>>(
      x1_hc, 128 - TCC, wr_wih[3], bias_l[3], bufB[0], 4096, 2048, 1024);
  for (int c = 0; c < NCH; ++c) {
    GJob job{};
    if (c < NCH - 1) {
      int n = c + 1;
      job.mode = 2;
      job.Af = x1_hc; job.Ab = x1_hc;
      job.tbF = TCC * n; job.tbB = 128 - TCC * n - TCC;
      job.Wf = wr_wih[2]; job.Wb = wr_wih[3];
      job.bsF = bias_l[2]; job.bsB = bias_l[3];
      job.outF = bufF[n & 1]; job.outB = bufB[n & 1];
    }
    RDir f{wr_whh[2], bufF[c & 1], enc_hc, 0, 0, h0_[2], c_[2], hf_[2]};
    RDir bk{wr_whh[3], bufB[c & 1], enc_hc, 64, 1, h0_[3], c_[3], hf_[3]};
    lstm_rec_g<<<dim3(256), 512, 0, stream>>>(f, bk, c * TCC, TCC, 128, flags + 1024 + c * 128, job);
  }

  // ---- attnfc (tanh), reads enc_hc directly ----
  gemm_hcA<2, 2, 1><<<dim3(256, 1), 256, 0, stream>>>(
      enc_hc, 0, attnfc_wb, attnfc_b, proj_enc, 32768, 128, 1024);

  // ---- fc_in on trg (time-major) ----
  fc_in_mlp<<<dim3(64), 256, 0, stream>>>(trg, inp, 16384, 64, fi_w1, fi_b1, fi_w2, fi_b2, fi_w3, fi_b3);

  // ---- MHA (all time-major) ----
  gemm_bt<2, 2, 0, false><<<dim3(128, 1), 256, 0, stream>>>(inp, inproj_wb, inproj_b, nullptr, qb, 16384, 128, 128);
  gemm_bt<2, 2, 0, false><<<dim3(256, 1), 256, 0, stream>>>(proj_enc, inproj_wb + (size_t)128 * 128, inproj_b + 128, nullptr, kb, 32768, 128, 128);
  gemm_bt<2, 2, 0, false><<<dim3(256, 1), 256, 0, stream>>>(proj_enc, inproj_wb + (size_t)256 * 128, inproj_b + 256, nullptr, vb, 32768, 128, 128);
  attention_kernel<<<dim3(256, 4), 128, 0, stream>>>(qb, kb, vb, attnb);
  gemm_bt<2, 2, 0, true><<<dim3(128, 1), 256, 0, stream>>>(attnb, outproj_wb, outproj_b, inp, dec_in, 16384, 128, 128);

  // ---- decoder initial states (enc c_ hold final c after last chunk) ----
  dec_state_init<<<dim3(512), 256, 0, stream>>>(hf_[0], hf_[1], c_[0], c_[1], h0_[4], c_[4]);
  dec_state_init<<<dim3(512), 256, 0, stream>>>(hf_[2], hf_[3], c_[2], c_[3], h0_[5], c_[5]);

  // ---- decoder: d0 xg GEMM + fused batch-split d0/d1 recurrence ----
  gemm_bt<2, 2, 0, false><<<dim3(128, 16), 256, 0, stream>>>(dec_in, wr_wih[4], bias_l[4], nullptr, xg_dec, 16384, 2048, 128);
  lstm_dec_fused<<<dim3(256), 512, 0, stream>>>(
      wr_whh[4], xg_dec, hc0, h0_[4], c_[4],
      wr_whh[5], wr_wih[5], bias_l[5], hc1, h0_[5], c_[5],
      flags + 2048);

  // ---- fc_out (stage 1 reads hc1 hcomm layout directly) ----
  gemm_hc_fcout<<<dim3(128, 1), 128, 0, stream>>>(hc1, fo_w1b, fo_b1, fc1out, 16384, 64, 512);
  fc_out_tail<<<dim3(64), 256, 0, stream>>>(fc1out, trg, out, 16384, fo_w2, fo_b2, fo_w3, fo_b3);
}

// Round 13
// 2916.848 us; speedup vs baseline: 1.4437x; 1.0475x over previous
//
#include <hip/hip_runtime.h>
#include <cstdint>
#include <cstddef>
#include <cstdio>

typedef __bf16 bf16;
typedef __bf16 bf16x8 __attribute__((ext_vector_type(8)));
typedef __bf16 bf16x4 __attribute__((ext_vector_type(4)));
typedef float f32x4 __attribute__((ext_vector_type(4)));

#define DEVFN __device__ __forceinline__

DEVFN float geluf(float x) { return 0.5f * x * (1.0f + erff(x * 0.70710678118654752f)); }
DEVFN float sigmoidf(float x) { return 1.0f / (1.0f + expf(-x)); }

// ---------------------------------------------------------------------------
// Generic MFMA GEMM: C(M,N) = act(A(M,K) @ W(N,K)^T + bias) [+ residual]
// ---------------------------------------------------------------------------
template <int WGM, int WGN, int ACT, bool RES>
__launch_bounds__(WGM * WGN * 64)
__global__ void gemm_bt(const bf16* __restrict__ A, const bf16* __restrict__ W,
                        const float* __restrict__ bias, const bf16* __restrict__ Rsd,
                        bf16* __restrict__ C, int M, int N, int K) {
  constexpr int BM = WGM * 64, BN = WGN * 64, T = WGM * WGN * 64;
  constexpr int NA = BM * 4 / T, NB = BN * 4 / T;
  __shared__ __align__(16) char ldsA[BM * 64];
  __shared__ __align__(16) char ldsB[BN * 64];
  const int tid = threadIdx.x;
  const int lane = tid & 63, wave = tid >> 6;
  const int wm = wave % WGM, wn = wave / WGM;
  const int l16 = lane & 15, quad = lane >> 4;
  const int bm0 = blockIdx.x * BM, bn0 = blockIdx.y * BN;

  f32x4 acc[4][4] = {};
  for (int k0 = 0; k0 < K; k0 += 32) {
    bf16x8 ta[NA], tb[NB];
#pragma unroll
    for (int i = 0; i < NA; ++i) {
      int lin = i * T + tid;
      int row = lin >> 2, seg = lin & 3;
      ta[i] = *(const bf16x8*)(A + (size_t)(bm0 + row) * K + k0 + seg * 8);
    }
#pragma unroll
    for (int i = 0; i < NB; ++i) {
      int lin = i * T + tid;
      int row = lin >> 2, seg = lin & 3;
      tb[i] = *(const bf16x8*)(W + (size_t)(bn0 + row) * K + k0 + seg * 8);
    }
#pragma unroll
    for (int i = 0; i < NA; ++i) *(bf16x8*)(ldsA + (i * T + tid) * 16) = ta[i];
#pragma unroll
    for (int i = 0; i < NB; ++i) *(bf16x8*)(ldsB + (i * T + tid) * 16) = tb[i];
    __syncthreads();
    bf16x8 af[4], bfrag[4];
#pragma unroll
    for (int mi = 0; mi < 4; ++mi)
      af[mi] = *(const bf16x8*)(ldsA + (wm * 64 + mi * 16 + l16) * 64 + quad * 16);
#pragma unroll
    for (int ni = 0; ni < 4; ++ni)
      bfrag[ni] = *(const bf16x8*)(ldsB + (wn * 64 + ni * 16 + l16) * 64 + quad * 16);
#pragma unroll
    for (int mi = 0; mi < 4; ++mi)
#pragma unroll
      for (int ni = 0; ni < 4; ++ni)
        acc[mi][ni] = __builtin_amdgcn_mfma_f32_16x16x32_bf16(af[mi], bfrag[ni], acc[mi][ni], 0, 0, 0);
    __syncthreads();
  }
#pragma unroll
  for (int mi = 0; mi < 4; ++mi) {
#pragma unroll
    for (int ni = 0; ni < 4; ++ni) {
      int col = bn0 + wn * 64 + ni * 16 + l16;
      float bv = bias[col];
#pragma unroll
      for (int r = 0; r < 4; ++r) {
        int row = bm0 + wm * 64 + mi * 16 + quad * 4 + r;
        float x = acc[mi][ni][r] + bv;
        if (ACT == 1) x = tanhf(x);
        if (ACT == 2) x = geluf(x);
        size_t idx = (size_t)row * N + col;
        if (RES) x += (float)Rsd[idx];
        C[idx] = (bf16)x;
      }
    }
  }
}

// ---------------------------------------------------------------------------
// GEMM with A in LAYER-HC layout [t][128 slices][256 b][8 u] (stride 262144/t):
// A row r=(t*256+b) col u -> HC + t*262144 + (u>>3)*2048 + b*8 + (u&7).
// ---------------------------------------------------------------------------
template <int WGM, int WGN, int ACT>
__launch_bounds__(WGM * WGN * 64)
__global__ void gemm_hcA(const bf16* __restrict__ HC, int tbase, const bf16* __restrict__ W,
                         const float* __restrict__ bias, bf16* __restrict__ C,
                         int M, int N, int K) {
  constexpr int BM = WGM * 64, BN = WGN * 64, T = WGM * WGN * 64;
  constexpr int NA = BM * 4 / T, NB = BN * 4 / T;
  __shared__ __align__(16) char ldsA[BM * 64];
  __shared__ __align__(16) char ldsB[BN * 64];
  const int tid = threadIdx.x;
  const int lane = tid & 63, wave = tid >> 6;
  const int wm = wave % WGM, wn = wave / WGM;
  const int l16 = lane & 15, quad = lane >> 4;
  const int bm0 = blockIdx.x * BM, bn0 = blockIdx.y * BN;

  f32x4 acc[4][4] = {};
  for (int k0 = 0; k0 < K; k0 += 32) {
    bf16x8 ta[NA], tb[NB];
#pragma unroll
    for (int i = 0; i < NA; ++i) {
      int lin = i * T + tid;
      int row = bm0 + (lin >> 2), seg = lin & 3;
      int t = tbase + (row >> 8), b = row & 255;
      ta[i] = *(const bf16x8*)(HC + (size_t)t * 262144 + (size_t)((k0 >> 3) + seg) * 2048 + b * 8);
    }
#pragma unroll
    for (int i = 0; i < NB; ++i) {
      int lin = i * T + tid;
      int row = lin >> 2, seg = lin & 3;
      tb[i] = *(const bf16x8*)(W + (size_t)(bn0 + row) * K + k0 + seg * 8);
    }
#pragma unroll
    for (int i = 0; i < NA; ++i) *(bf16x8*)(ldsA + (i * T + tid) * 16) = ta[i];
#pragma unroll
    for (int i = 0; i < NB; ++i) *(bf16x8*)(ldsB + (i * T + tid) * 16) = tb[i];
    __syncthreads();
    bf16x8 af[4], bfrag[4];
#pragma unroll
    for (int mi = 0; mi < 4; ++mi)
      af[mi] = *(const bf16x8*)(ldsA + (wm * 64 + mi * 16 + l16) * 64 + quad * 16);
#pragma unroll
    for (int ni = 0; ni < 4; ++ni)
      bfrag[ni] = *(const bf16x8*)(ldsB + (wn * 64 + ni * 16 + l16) * 64 + quad * 16);
#pragma unroll
    for (int mi = 0; mi < 4; ++mi)
#pragma unroll
      for (int ni = 0; ni < 4; ++ni)
        acc[mi][ni] = __builtin_amdgcn_mfma_f32_16x16x32_bf16(af[mi], bfrag[ni], acc[mi][ni], 0, 0, 0);
    __syncthreads();
  }
#pragma unroll
  for (int mi = 0; mi < 4; ++mi) {
#pragma unroll
    for (int ni = 0; ni < 4; ++ni) {
      int col = bn0 + wn * 64 + ni * 16 + l16;
      float bv = bias[col];
#pragma unroll
      for (int r = 0; r < 4; ++r) {
        int row = bm0 + wm * 64 + mi * 16 + quad * 4 + r;
        float x = acc[mi][ni][r] + bv;
        if (ACT == 1) x = tanhf(x);
        if (ACT == 2) x = geluf(x);
        C[(size_t)row * N + col] = (bf16)x;
      }
    }
  }
}

// ---------------------------------------------------------------------------
// fc_out stage-1 GEMM reading A from decoder hc layout [t][64 u8][256 b][8]
// (stride 131072/t). C(M,64) = gelu(A @ W(64,512)^T + bias).
// ---------------------------------------------------------------------------
__launch_bounds__(128)
__global__ void gemm_hc_fcout(const bf16* __restrict__ HC, const bf16* __restrict__ W,
                              const float* __restrict__ bias, bf16* __restrict__ C,
                              int M, int N, int K) {
  constexpr int WGM = 2, WGN = 1;
  constexpr int BM = WGM * 64, BN = WGN * 64, T = WGM * WGN * 64;
  constexpr int NA = BM * 4 / T, NB = BN * 4 / T;
  __shared__ __align__(16) char ldsA[BM * 64];
  __shared__ __align__(16) char ldsB[BN * 64];
  const int tid = threadIdx.x;
  const int lane = tid & 63, wave = tid >> 6;
  const int wm = wave % WGM, wn = wave / WGM;
  const int l16 = lane & 15, quad = lane >> 4;
  const int bm0 = blockIdx.x * BM, bn0 = blockIdx.y * BN;

  f32x4 acc[4][4] = {};
  for (int k0 = 0; k0 < K; k0 += 32) {
    bf16x8 ta[NA], tb[NB];
#pragma unroll
    for (int i = 0; i < NA; ++i) {
      int lin = i * T + tid;
      int row = bm0 + (lin >> 2), seg = lin & 3;
      int t = row >> 8, b = row & 255;
      ta[i] = *(const bf16x8*)(HC + (size_t)t * 131072 + (size_t)((k0 >> 3) + seg) * 2048 + b * 8);
    }
#pragma unroll
    for (int i = 0; i < NB; ++i) {
      int lin = i * T + tid;
      int row = lin >> 2, seg = lin & 3;
      tb[i] = *(const bf16x8*)(W + (size_t)(bn0 + row) * K + k0 + seg * 8);
    }
#pragma unroll
    for (int i = 0; i < NA; ++i) *(bf16x8*)(ldsA + (i * T + tid) * 16) = ta[i];
#pragma unroll
    for (int i = 0; i < NB; ++i) *(bf16x8*)(ldsB + (i * T + tid) * 16) = tb[i];
    __syncthreads();
    bf16x8 af[4], bfrag[4];
#pragma unroll
    for (int mi = 0; mi < 4; ++mi)
      af[mi] = *(const bf16x8*)(ldsA + (wm * 64 + mi * 16 + l16) * 64 + quad * 16);
#pragma unroll
    for (int ni = 0; ni < 4; ++ni)
      bfrag[ni] = *(const bf16x8*)(ldsB + (wn * 64 + ni * 16 + l16) * 64 + quad * 16);
#pragma unroll
    for (int mi = 0; mi < 4; ++mi)
#pragma unroll
      for (int ni = 0; ni < 4; ++ni)
        acc[mi][ni] = __builtin_amdgcn_mfma_f32_16x16x32_bf16(af[mi], bfrag[ni], acc[mi][ni], 0, 0, 0);
    __syncthreads();
  }
#pragma unroll
  for (int mi = 0; mi < 4; ++mi) {
#pragma unroll
    for (int ni = 0; ni < 4; ++ni) {
      int col = bn0 + wn * 64 + ni * 16 + l16;
      float bv = bias[col];
#pragma unroll
      for (int r = 0; r < 4; ++r) {
        int row = bm0 + wm * 64 + mi * 16 + quad * 4 + r;
        float x = geluf(acc[mi][ni][r] + bv);
        C[(size_t)row * N + col] = (bf16)x;
      }
    }
  }
}

// ---------------------------------------------------------------------------
// Device tile-GEMM for the fused rec+gemm kernel (512 threads, BM=128,
// BN=256). A row-major (HCMODE=0) or layer-hc (HCMODE=1). N fixed = 2048.
// ---------------------------------------------------------------------------
template <int HCMODE>
DEVFN void xg_tile(const bf16* __restrict__ A, int tbase, const bf16* __restrict__ W,
                   const float* __restrict__ bias, bf16* __restrict__ C,
                   int K, int bm0, int bn0, int tid, bf16* ldsA, bf16* ldsB) {
  const int lane = tid & 63, wave = tid >> 6;
  const int wm = wave & 1, wn = wave >> 1;  // WGM=2, WGN=4
  const int l16 = lane & 15, quad = lane >> 4;
  f32x4 acc[4][4] = {};
  for (int k0 = 0; k0 < K; k0 += 32) {
    bf16x8 ta, tb0, tb1;
    {
      int row = bm0 + (tid >> 2), seg = tid & 3;
      if (HCMODE) {
        int t = tbase + (row >> 8), b = row & 255;
        ta = *(const bf16x8*)(A + (size_t)t * 262144 + (size_t)((k0 >> 3) + seg) * 2048 + b * 8);
      } else {
        ta = *(const bf16x8*)(A + (size_t)row * K + k0 + seg * 8);
      }
    }
    { int row = tid >> 2, seg = tid & 3;
      tb0 = *(const bf16x8*)(W + (size_t)(bn0 + row) * K + k0 + seg * 8); }
    { int lin = 512 + tid; int row = lin >> 2, seg = lin & 3;
      tb1 = *(const bf16x8*)(W + (size_t)(bn0 + row) * K + k0 + seg * 8); }
    *(bf16x8*)(ldsA + tid * 8) = ta;
    *(bf16x8*)(ldsB + tid * 8) = tb0;
    *(bf16x8*)(ldsB + (512 + tid) * 8) = tb1;
    __syncthreads();
    bf16x8 af[4], bfr[4];
#pragma unroll
    for (int mi = 0; mi < 4; ++mi)
      af[mi] = *(const bf16x8*)(ldsA + (wm * 64 + mi * 16 + l16) * 32 + quad * 8);
#pragma unroll
    for (int ni = 0; ni < 4; ++ni)
      bfr[ni] = *(const bf16x8*)(ldsB + (wn * 64 + ni * 16 + l16) * 32 + quad * 8);
#pragma unroll
    for (int mi = 0; mi < 4; ++mi)
#pragma unroll
      for (int ni = 0; ni < 4; ++ni)
        acc[mi][ni] = __builtin_amdgcn_mfma_f32_16x16x32_bf16(af[mi], bfr[ni], acc[mi][ni], 0, 0, 0);
    __syncthreads();
  }
#pragma unroll
  for (int mi = 0; mi < 4; ++mi) {
#pragma unroll
    for (int ni = 0; ni < 4; ++ni) {
      int col = bn0 + wn * 64 + ni * 16 + l16;
      float bv = bias[col];
#pragma unroll
      for (int r = 0; r < 4; ++r) {
        int row = bm0 + wm * 64 + mi * 16 + quad * 4 + r;
        C[(size_t)row * 2048 + col] = (bf16)(acc[mi][ni][r] + bv);
      }
    }
  }
}

// ---------------------------------------------------------------------------
// Fused encoder dispatch. REC role now BATCH-SPLIT (mirrors the verified
// decoder win): 2 dirs x 32 slices x 2 batch-halves = 128 blocks, each
// 64 gate-cols x 128 batch rows. Per-thread h burst drops 32 -> 16 loads
// (64 VGPRs -- fits, unlike round 9's 128), per-step h-broadcast volume
// halves (32 -> 16 MB). 64-col whh in LDS (64KB). Publish: 2 contiguous
// single-writer 1KB regions per block. Counters: 64 signals/dir/step
// (unchanged). GEMM role (blocks 128-255) unchanged.
// ---------------------------------------------------------------------------
struct RDir {
  const bf16* whh_r;   // (2048,512) bf16, rows reordered 4j+g
  const bf16* xg;      // chunk: row lt*256+b, 2048 cols (bias included)
  bf16* hc;            // layer hc buffer [Tfull][128][256][8]
  int slcOff, rev;     // slice offset (0 fwd, 64 bwd), direction
  const bf16* h0;      // initial h (256x512 row-major) for global step 0
  float* cbuf;         // persistent c (256x512 fp32)
  bf16* hfin;          // final h (row-major) or nullptr
};

struct GJob {
  int mode;            // 0 none, 1 layer0 row-major A (K=128), 2 layer1 hcA (K=1024)
  const bf16* Af; const bf16* Ab;
  int tbF, tbB;        // hcA tbases (mode 2)
  const bf16* Wf; const bf16* Wb;
  const float* bsF; const float* bsB;
  bf16* outF; bf16* outB;   // next-chunk xg buffers (4096 rows x 2048)
};

__launch_bounds__(512, 1)
__global__ void lstm_rec_g(RDir da, RDir db, int t0, int tc, int Tfull,
                           int* __restrict__ cnts, GJob job) {
  __shared__ __align__(16) char smem[69632];  // rec: 64KB whh + 4KB hstg | gemm: 8KB A + 16KB B
  const int blk = blockIdx.x;
  const int tid = threadIdx.x;

  if (blk >= 128) {
    // ----------------- GEMM role: next-chunk xg (both dirs) -----------------
    if (job.mode == 0) return;
    bf16* ldsA = (bf16*)smem;
    bf16* ldsB = (bf16*)(smem + 8192);
    const int gb = blk - 128;
    const int K = (job.mode == 2) ? 1024 : 128;
    for (int tile = gb; tile < 512; tile += 128) {
      int dir = tile >> 8;
      int rem = tile & 255;
      int mi = rem >> 3, ni = rem & 7;
      const bf16* A = dir ? job.Ab : job.Af;
      int tb = dir ? job.tbB : job.tbF;
      const bf16* W = dir ? job.Wb : job.Wf;
      const float* bs = dir ? job.bsB : job.bsF;
      bf16* C = dir ? job.outB : job.outF;
      if (job.mode == 2)
        xg_tile<1>(A, tb, W, bs, C, K, mi * 128, ni * 256, tid, ldsA, ldsB);
      else
        xg_tile<0>(A, tb, W, bs, C, K, mi * 128, ni * 256, tid, ldsA, ldsB);
    }
    return;
  }

  // ---- REC role: 2 dirs x 32 slices x 2 batch-halves, 64 cols/block ----
  bf16* whh_lds = (bf16*)smem;             // 64 cols x 512 k (64KB), permuted
  bf16* hstg = (bf16*)(smem + 65536);      // 128 b x 16 u (4KB)
  const int isB = (blk >= 64);
  const RDir d = isB ? db : da;
  const int idx = blk & 63;
  const int bslice = idx >> 1, bh = idx & 1;
  const int colBase = bslice * 64, unitBase = bslice * 16;
  const int w = tid >> 6, lane = tid & 63;
  const int l16 = lane & 15, quad = lane >> 4;
  const int b0 = bh * 128 + w * 16 + l16;  // global batch row (one frag/wave)

  // prologue: whh slice -> LDS, permuted ((k>>3)*512 + c*8 + (k&7))
  for (int e = tid * 8; e < 64 * 512; e += 512 * 8) {
    int c = e >> 9, k0 = e & 511;
    bf16x8 v = *(const bf16x8*)(d.whh_r + (size_t)(colBase + c) * 512 + k0);
    *(bf16x8*)(whh_lds + ((k0 >> 3) << 9) + (c << 3)) = v;
  }
  float cst[4];
#pragma unroll
  for (int m = 0; m < 4; ++m)
    cst[m] = d.cbuf[(size_t)b0 * 512 + unitBase + m * 4 + quad];
  __syncthreads();

  int* cnt = cnts + (isB ? 64 : 0);

  for (int s = 0; s < tc; ++s) {
    const int sg = t0 + s;
    const int t = d.rev ? (Tfull - 1 - sg) : sg;
    const int lt = d.rev ? (tc - 1 - s) : s;

    bf16x4 gxr[4];
#pragma unroll
    for (int m = 0; m < 4; ++m)
      gxr[m] = *(const bf16x4*)(d.xg + ((size_t)lt * 256 + b0) * 2048 + colBase + m * 16 + quad * 4);
    bf16x8 hr[16];
    if (sg == 0) {
      const bf16* hp = d.h0 + (size_t)b0 * 512 + quad * 8;
#pragma unroll
      for (int kk = 0; kk < 16; ++kk) hr[kk] = *(const bf16x8*)(hp + kk * 32);
    } else {
      const int tp = d.rev ? (t + 1) : (t - 1);
      const bf16* hc = d.hc + (size_t)tp * 262144 + (size_t)d.slcOff * 2048;
#pragma unroll
      for (int kk = 0; kk < 16; ++kk) {
        int u8 = kk * 4 + quad;
        hr[kk] = *(const bf16x8*)(hc + u8 * 2048 + (size_t)b0 * 8);
      }
    }
    __builtin_amdgcn_sched_barrier(0);

    f32x4 acc[4] = {};
#pragma unroll
    for (int kk = 0; kk < 16; ++kk) {
      bf16x8 a0 = *(const bf16x8*)(whh_lds + kk * 2048 + quad * 512 + l16 * 8);
      bf16x8 a1 = *(const bf16x8*)(whh_lds + kk * 2048 + quad * 512 + 128 + l16 * 8);
      bf16x8 a2 = *(const bf16x8*)(whh_lds + kk * 2048 + quad * 512 + 256 + l16 * 8);
      bf16x8 a3 = *(const bf16x8*)(whh_lds + kk * 2048 + quad * 512 + 384 + l16 * 8);
      acc[0] = __builtin_amdgcn_mfma_f32_16x16x32_bf16(a0, hr[kk], acc[0], 0, 0, 0);
      acc[1] = __builtin_amdgcn_mfma_f32_16x16x32_bf16(a1, hr[kk], acc[1], 0, 0, 0);
      acc[2] = __builtin_amdgcn_mfma_f32_16x16x32_bf16(a2, hr[kk], acc[2], 0, 0, 0);
      acc[3] = __builtin_amdgcn_mfma_f32_16x16x32_bf16(a3, hr[kk], acc[3], 0, 0, 0);
    }
#pragma unroll
    for (int m = 0; m < 4; ++m) {
      float gi = acc[m][0] + (float)gxr[m][0];
      float gf = acc[m][1] + (float)gxr[m][1];
      float gg = acc[m][2] + (float)gxr[m][2];
      float go = acc[m][3] + (float)gxr[m][3];
      float cn = sigmoidf(gf) * cst[m] + sigmoidf(gi) * tanhf(gg);
      float hv = sigmoidf(go) * tanhf(cn);
      cst[m] = cn;
      int lb = w * 16 + l16;
      hstg[lb * 16 + m * 4 + quad] = (bf16)hv;
    }
    __syncthreads();
    // publish: 2 contiguous single-writer 1KB half-slice regions
    {
      int hi = tid >> 8, r = tid & 255, lb = r >> 1, uh = r & 1;
      unsigned long long v = *(const unsigned long long*)(hstg + lb * 16 + hi * 8 + uh * 4);
      __hip_atomic_store((unsigned long long*)(d.hc + (size_t)t * 262144 +
                                               (size_t)(d.slcOff + 2 * bslice + hi) * 2048 +
                                               bh * 1024 + lb * 8 + uh * 4),
                         v, __ATOMIC_RELAXED, __HIP_MEMORY_SCOPE_AGENT);
    }
    __syncthreads();  // drains vmcnt -> hc visible before signal
    if (s < tc - 1 && tid == 0)
      __hip_atomic_fetch_add(cnt, 1, __ATOMIC_RELAXED, __HIP_MEMORY_SCOPE_AGENT);
    if (sg == Tfull - 1 && d.hfin) {  // final h (row-major 512 stride)
      int hi = tid >> 8, r = tid & 255, lb = r >> 1, uh = r & 1;
      const unsigned long long* p = (const unsigned long long*)(hstg + lb * 16 + hi * 8 + uh * 4);
      *(unsigned long long*)(d.hfin + (size_t)(bh * 128 + lb) * 512 + unitBase + hi * 8 + uh * 4) = p[0];
    }
    if (s < tc - 1) {
      if (w == 0) {
        int target = 64 * (s + 1), guard = 0;
        while (__hip_atomic_load(cnt, __ATOMIC_RELAXED, __HIP_MEMORY_SCOPE_AGENT) < target) {
          __builtin_amdgcn_s_sleep(2);
          if (++guard > (1 << 22)) break;  // bail (wrong answer) instead of hang
        }
      }
      __syncthreads();
    }
  }
#pragma unroll
  for (int m = 0; m < 4; ++m)
    d.cbuf[(size_t)b0 * 512 + unitBase + m * 4 + quad] = cst[m];
}

// ---------------------------------------------------------------------------
// Fused decoder, batch-split (round-12, verified): d0 = 128 blocks, d1 = 128.
// ---------------------------------------------------------------------------
__launch_bounds__(512, 1)
__global__ void lstm_dec_fused(
    const bf16* __restrict__ whh0, const bf16* __restrict__ xg0,
    bf16* __restrict__ hc0, const bf16* __restrict__ h0d0, float* __restrict__ c0buf,
    const bf16* __restrict__ whh1, const bf16* __restrict__ wih1, const float* __restrict__ bias1,
    bf16* __restrict__ hc1, const bf16* __restrict__ h0d1,
    float* __restrict__ c1buf, int* __restrict__ cnts) {
  const int blk = blockIdx.x;
  const int tid = threadIdx.x;
  const int w = tid >> 6, lane = tid & 63;
  const int l16 = lane & 15, quad = lane >> 4;
  constexpr int TC = 64;

  __shared__ __align__(16) bf16 wldsA[32 * 512];
  __shared__ __align__(16) bf16 wldsB[32 * 512];
  __shared__ __align__(16) bf16 hstg[128 * 8];

  int* cnt0 = cnts;
  int* cnt1 = cnts + 64;

  if (blk < 128) {
    // ---------------- d0: slice x half-batch ----------------
    const int slice = blk >> 1, bh = blk & 1;
    const int colBase = slice * 32;
    const int b0 = bh * 128 + w * 16 + l16;
    for (int e = tid * 8; e < 32 * 512; e += 512 * 8) {
      int c = e >> 9, k0 = e & 511;
      bf16x8 v = *(const bf16x8*)(whh0 + (size_t)(colBase + c) * 512 + k0);
      *(bf16x8*)(wldsA + ((k0 >> 3) << 8) + (c << 3)) = v;
    }
    float cst[2];
#pragma unroll
    for (int m = 0; m < 2; ++m)
      cst[m] = c0buf[(size_t)b0 * 512 + slice * 8 + m * 4 + quad];
    __syncthreads();

    for (int s = 0; s < TC; ++s) {
      bf16x4 gxr[2];
#pragma unroll
      for (int m = 0; m < 2; ++m)
        gxr[m] = *(const bf16x4*)(xg0 + ((size_t)s * 256 + b0) * 2048 + colBase + m * 16 + quad * 4);
      bf16x8 hr[16];
      if (s == 0) {
        const bf16* hp = h0d0 + (size_t)b0 * 512 + quad * 8;
#pragma unroll
        for (int kk = 0; kk < 16; ++kk) hr[kk] = *(const bf16x8*)(hp + kk * 32);
      } else {
        const bf16* hc = hc0 + (size_t)(s - 1) * 131072;
#pragma unroll
        for (int kk = 0; kk < 16; ++kk) {
          int u8 = kk * 4 + quad;
          hr[kk] = *(const bf16x8*)(hc + u8 * 2048 + (size_t)b0 * 8);
        }
      }
      __builtin_amdgcn_sched_barrier(0);
      f32x4 acc[2] = {};
#pragma unroll
      for (int kk = 0; kk < 16; ++kk) {
        bf16x8 a0 = *(const bf16x8*)(wldsA + kk * 1024 + quad * 256 + l16 * 8);
        bf16x8 a1 = *(const bf16x8*)(wldsA + kk * 1024 + quad * 256 + 128 + l16 * 8);
        acc[0] = __builtin_amdgcn_mfma_f32_16x16x32_bf16(a0, hr[kk], acc[0], 0, 0, 0);
        acc[1] = __builtin_amdgcn_mfma_f32_16x16x32_bf16(a1, hr[kk], acc[1], 0, 0, 0);
      }
#pragma unroll
      for (int m = 0; m < 2; ++m) {
        float gi = acc[m][0] + (float)gxr[m][0];
        float gf = acc[m][1] + (float)gxr[m][1];
        float gg = acc[m][2] + (float)gxr[m][2];
        float go = acc[m][3] + (float)gxr[m][3];
        float cn = sigmoidf(gf) * cst[m] + sigmoidf(gi) * tanhf(gg);
        float hv = sigmoidf(go) * tanhf(cn);
        cst[m] = cn;
        int lb = w * 16 + l16;
        hstg[lb * 8 + m * 4 + quad] = (bf16)hv;
      }
      __syncthreads();
      if (tid < 256) {  // contiguous single-writer 2KB half-slice
        unsigned long long v = *(const unsigned long long*)(hstg + tid * 4);
        __hip_atomic_store((unsigned long long*)(hc0 + (size_t)s * 131072 +
                                                 slice * 2048 + bh * 1024 + tid * 4),
                           v, __ATOMIC_RELAXED, __HIP_MEMORY_SCOPE_AGENT);
      }
      __syncthreads();  // hcomm visible
      if (tid == 0)     // every step incl. last (d1 consumes all 64)
        __hip_atomic_fetch_add(cnt0, 1, __ATOMIC_RELAXED, __HIP_MEMORY_SCOPE_AGENT);
      if (s < TC - 1) {
        if (w == 0) {
          int target = 128 * (s + 1), guard = 0;
          while (__hip_atomic_load(cnt0, __ATOMIC_RELAXED, __HIP_MEMORY_SCOPE_AGENT) < target) {
            __builtin_amdgcn_s_sleep(2);
            if (++guard > (1 << 22)) break;
          }
        }
        __syncthreads();
      }
    }
#pragma unroll
    for (int m = 0; m < 2; ++m)
      c0buf[(size_t)b0 * 512 + slice * 8 + m * 4 + quad] = cst[m];
  } else {
    // ---------------- d1: slice x half-batch, single dual burst ------------
    const int idx = blk - 128, slice = idx >> 1, bh = idx & 1;
    const int colBase = slice * 32;
    const int b0 = bh * 128 + w * 16 + l16;
    for (int e = tid * 8; e < 32 * 512; e += 512 * 8) {
      int c = e >> 9, k0 = e & 511;
      bf16x8 v = *(const bf16x8*)(whh1 + (size_t)(colBase + c) * 512 + k0);
      *(bf16x8*)(wldsA + ((k0 >> 3) << 8) + (c << 3)) = v;
      bf16x8 u = *(const bf16x8*)(wih1 + (size_t)(colBase + c) * 512 + k0);
      *(bf16x8*)(wldsB + ((k0 >> 3) << 8) + (c << 3)) = u;
    }
    float gbv[2][4];
#pragma unroll
    for (int m = 0; m < 2; ++m)
#pragma unroll
      for (int r = 0; r < 4; ++r) gbv[m][r] = bias1[colBase + m * 16 + quad * 4 + r];
    float cst[2];
#pragma unroll
    for (int m = 0; m < 2; ++m)
      cst[m] = c1buf[(size_t)b0 * 512 + slice * 8 + m * 4 + quad];
    __syncthreads();
    if (w == 0) {  // wait for hc0[0]
      int guard = 0;
      while (__hip_atomic_load(cnt0, __ATOMIC_RELAXED, __HIP_MEMORY_SCOPE_AGENT) < 128) {
        __builtin_amdgcn_s_sleep(2);
        if (++guard > (1 << 22)) break;
      }
    }
    __syncthreads();

    for (int s = 0; s < TC; ++s) {
      bf16x8 hr[16], xr[16];
      if (s == 0) {
        const bf16* hp = h0d1 + (size_t)b0 * 512 + quad * 8;
#pragma unroll
        for (int kk = 0; kk < 16; ++kk) hr[kk] = *(const bf16x8*)(hp + kk * 32);
      } else {
        const bf16* hc = hc1 + (size_t)(s - 1) * 131072;
#pragma unroll
        for (int kk = 0; kk < 16; ++kk) {
          int u8 = kk * 4 + quad;
          hr[kk] = *(const bf16x8*)(hc + u8 * 2048 + (size_t)b0 * 8);
        }
      }
      {
        const bf16* xc = hc0 + (size_t)s * 131072;
#pragma unroll
        for (int kk = 0; kk < 16; ++kk) {
          int u8 = kk * 4 + quad;
          xr[kk] = *(const bf16x8*)(xc + u8 * 2048 + (size_t)b0 * 8);
        }
      }
      __builtin_amdgcn_sched_barrier(0);
      f32x4 acc[2] = {};
#pragma unroll
      for (int kk = 0; kk < 16; ++kk) {
        bf16x8 a0 = *(const bf16x8*)(wldsA + kk * 1024 + quad * 256 + l16 * 8);
        bf16x8 a1 = *(const bf16x8*)(wldsA + kk * 1024 + quad * 256 + 128 + l16 * 8);
        acc[0] = __builtin_amdgcn_mfma_f32_16x16x32_bf16(a0, hr[kk], acc[0], 0, 0, 0);
        acc[1] = __builtin_amdgcn_mfma_f32_16x16x32_bf16(a1, hr[kk], acc[1], 0, 0, 0);
      }
#pragma unroll
      for (int kk = 0; kk < 16; ++kk) {
        bf16x8 aw0 = *(const bf16x8*)(wldsB + kk * 1024 + quad * 256 + l16 * 8);
        bf16x8 aw1 = *(const bf16x8*)(wldsB + kk * 1024 + quad * 256 + 128 + l16 * 8);
        acc[0] = __builtin_amdgcn_mfma_f32_16x16x32_bf16(aw0, xr[kk], acc[0], 0, 0, 0);
        acc[1] = __builtin_amdgcn_mfma_f32_16x16x32_bf16(aw1, xr[kk], acc[1], 0, 0, 0);
      }
#pragma unroll
      for (int m = 0; m < 2; ++m) {
        float gi = acc[m][0] + gbv[m][0];
        float gf = acc[m][1] + gbv[m][1];
        float gg = acc[m][2] + gbv[m][2];
        float go = acc[m][3] + gbv[m][3];
        float cn = sigmoidf(gf) * cst[m] + sigmoidf(gi) * tanhf(gg);
        float hv = sigmoidf(go) * tanhf(cn);
        cst[m] = cn;
        int lb = w * 16 + l16;
        hstg[lb * 8 + m * 4 + quad] = (bf16)hv;
      }
      __syncthreads();
      if (tid < 256) {
        unsigned long long v = *(const unsigned long long*)(hstg + tid * 4);
        __hip_atomic_store((unsigned long long*)(hc1 + (size_t)s * 131072 +
                                                 slice * 2048 + bh * 1024 + tid * 4),
                           v, __ATOMIC_RELAXED, __HIP_MEMORY_SCOPE_AGENT);
      }
      __syncthreads();  // hcomm visible
      if (s < TC - 1) {
        if (tid == 0)
          __hip_atomic_fetch_add(cnt1, 1, __ATOMIC_RELAXED, __HIP_MEMORY_SCOPE_AGENT);
        if (w == 0) {
          int t1 = 128 * (s + 1), t0n = 128 * (s + 2), guard = 0;
          while (true) {
            int v1 = __hip_atomic_load(cnt1, __ATOMIC_RELAXED, __HIP_MEMORY_SCOPE_AGENT);
            int v0 = __hip_atomic_load(cnt0, __ATOMIC_RELAXED, __HIP_MEMORY_SCOPE_AGENT);
            if (v1 >= t1 && v0 >= t0n) break;
            __builtin_amdgcn_s_sleep(2);
            if (++guard > (1 << 22)) break;
          }
        }
        __syncthreads();
      }
    }
#pragma unroll
    for (int m = 0; m < 2; ++m)
      c1buf[(size_t)b0 * 512 + slice * 8 + m * 4 + quad] = cst[m];
  }
}

// ---------------------------------------------------------------------------
// fc_in MLP: 4 -> 32 -> 64 -> 128, exact GELU. One row per thread. fp32 in.
// ---------------------------------------------------------------------------
__launch_bounds__(256)
__global__ void fc_in_mlp(const float* __restrict__ x, bf16* __restrict__ y, int rows, int tmod,
                          const float* __restrict__ w1, const float* __restrict__ b1,
                          const float* __restrict__ w2, const float* __restrict__ b2,
                          const float* __restrict__ w3, const float* __restrict__ b3) {
  __shared__ float sm[10592];
  const int tid = threadIdx.x;
  for (int i = tid; i < 10592; i += 256) {
    float v;
    if (i < 128) v = w1[i];
    else if (i < 160) v = b1[i - 128];
    else if (i < 2208) v = w2[i - 160];
    else if (i < 2272) v = b2[i - 2208];
    else if (i < 10464) v = w3[i - 2272];
    else v = b3[i - 10464];
    sm[i] = v;
  }
  __syncthreads();
  int row = blockIdx.x * 256 + tid;
  if (row >= rows) return;
  int orow = tmod ? ((row % tmod) * 256 + row / tmod) : row;
  float xin[4];
#pragma unroll
  for (int k = 0; k < 4; ++k) xin[k] = x[(size_t)row * 4 + k];
  float h1[32];
#pragma unroll
  for (int j = 0; j < 32; ++j) {
    float a = sm[128 + j];
#pragma unroll
    for (int k = 0; k < 4; ++k) a += sm[j * 4 + k] * xin[k];
    h1[j] = geluf(a);
  }
  float h2[64];
#pragma unroll
  for (int j = 0; j < 64; ++j) {
    float a = sm[2208 + j];
#pragma unroll
    for (int k = 0; k < 32; ++k) a += sm[160 + j * 32 + k] * h1[k];
    h2[j] = geluf(a);
  }
  for (int c = 0; c < 8; ++c) {
    float accv[16];
#pragma unroll
    for (int j = 0; j < 16; ++j) accv[j] = sm[10464 + c * 16 + j];
#pragma unroll
    for (int j = 0; j < 16; ++j) {
#pragma unroll
      for (int k = 0; k < 64; ++k) accv[j] += sm[2272 + (c * 16 + j) * 64 + k] * h2[k];
    }
#pragma unroll
    for (int j = 0; j < 16; ++j) y[(size_t)orow * 128 + c * 16 + j] = (bf16)accv[j];
  }
}

// ---------------------------------------------------------------------------
// fc_out tail: h1in rows time-major (t*256+b); trg/out rows (b*64+t), fp32.
// ---------------------------------------------------------------------------
__launch_bounds__(256)
__global__ void fc_out_tail(const bf16* __restrict__ h1in, const float* __restrict__ trg,
                            float* __restrict__ out, int rows,
                            const float* __restrict__ w2, const float* __restrict__ b2,
                            const float* __restrict__ w3, const float* __restrict__ b3) {
  __shared__ float sm[2212];
  const int tid = threadIdx.x;
  for (int i = tid; i < 2212; i += 256) {
    float v;
    if (i < 2048) v = w2[i];
    else if (i < 2080) v = b2[i - 2048];
    else if (i < 2208) v = w3[i - 2080];
    else v = b3[i - 2208];
    sm[i] = v;
  }
  __syncthreads();
  int row = blockIdx.x * 256 + tid;
  if (row >= rows) return;
  int b = row >> 6, t = row & 63;
  const bf16* h1p = h1in + ((size_t)t * 256 + b) * 64;
  float h1[64];
#pragma unroll
  for (int k = 0; k < 64; ++k) h1[k] = (float)h1p[k];
  float h2[32];
#pragma unroll
  for (int j = 0; j < 32; ++j) {
    float a = sm[2048 + j];
#pragma unroll
    for (int k = 0; k < 64; ++k) a += sm[j * 64 + k] * h1[k];
    h2[j] = geluf(a);
  }
#pragma unroll
  for (int dd = 0; dd < 4; ++dd) {
    float a = sm[2208 + dd];
#pragma unroll
    for (int k = 0; k < 32; ++k) a += sm[2080 + dd * 32 + k] * h2[k];
    out[(size_t)row * 4 + dd] = trg[(size_t)row * 4 + dd] + a;
  }
}

// ---------------------------------------------------------------------------
// MHA core: one block per (batch, head). All tensors time-major (row s*256+b).
// ---------------------------------------------------------------------------
__launch_bounds__(128)
__global__ void attention_kernel(const bf16* __restrict__ Q, const bf16* __restrict__ K,
                                 const bf16* __restrict__ V, bf16* __restrict__ O) {
  __shared__ bf16 qs[64 * 32];
  __shared__ float ks[128 * 33];
  __shared__ bf16 vs[128 * 32];
  __shared__ float sc[64 * 132];
  const int b = blockIdx.x, h = blockIdx.y, tid = threadIdx.x;
  for (int i = tid; i < 64 * 32; i += 128) {
    int t = i >> 5, dd = i & 31;
    qs[i] = Q[((size_t)t * 256 + b) * 128 + h * 32 + dd];
  }
  for (int i = tid; i < 128 * 32; i += 128) {
    int s = i >> 5, dd = i & 31;
    size_t ridx = ((size_t)s * 256 + b) * 128 + h * 32 + dd;
    ks[s * 33 + dd] = (float)K[ridx];
    vs[i] = V[ridx];
  }
  __syncthreads();
  const float scale = 0.17677669529663687f;
  for (int i = tid; i < 64 * 128; i += 128) {
    int t = i >> 7, s = i & 127;
    float a = 0.f;
#pragma unroll
    for (int dd = 0; dd < 32; ++dd) a += (float)qs[t * 32 + dd] * ks[s * 33 + dd];
    sc[t * 132 + s] = a * scale;
  }
  __syncthreads();
  if (tid < 64) {
    float m = -1e30f;
    for (int s = 0; s < 128; ++s) m = fmaxf(m, sc[tid * 132 + s]);
    float sum = 0.f;
    for (int s = 0; s < 128; ++s) { float e = expf(sc[tid * 132 + s] - m); sc[tid * 132 + s] = e; sum += e; }
    float r = 1.0f / sum;
    for (int s = 0; s < 128; ++s) sc[tid * 132 + s] *= r;
  }
  __syncthreads();
  for (int i = tid; i < 64 * 32; i += 128) {
    int t = i >> 5, dd = i & 31;
    float a = 0.f;
    for (int s = 0; s < 128; ++s) a += sc[t * 132 + s] * (float)vs[s * 32 + dd];
    O[((size_t)t * 256 + b) * 128 + h * 32 + dd] = (bf16)a;
  }
}

// ---------------------------------------------------------------------------
// Prep kernels
// ---------------------------------------------------------------------------
__global__ void reorder_gate_rows(const float* __restrict__ in, bf16* __restrict__ out, int K) {
  int i = blockIdx.x * 256 + threadIdx.x;
  if (i >= 2048 * K) return;
  int r = i / K, k = i - r * K;
  int nr = 4 * (r & 511) + (r >> 9);
  out[(size_t)nr * K + k] = (bf16)in[i];
}

__global__ void combine_bias(const float* __restrict__ a, const float* __restrict__ b,
                             float* __restrict__ out) {
  int i = blockIdx.x * 256 + threadIdx.x;
  if (i >= 2048) return;
  out[4 * (i & 511) + (i >> 9)] = a[i] + b[i];
}

__global__ void f2b(const float* __restrict__ in, bf16* __restrict__ out, int n) {
  int i = blockIdx.x * 256 + threadIdx.x;
  if (i < n) out[i] = (bf16)in[i];
}

__global__ void zero_u32(uint32_t* __restrict__ p, int n) {
  int i = blockIdx.x * 256 + threadIdx.x;
  if (i < n) p[i] = 0u;
}

__global__ void dec_state_init(const bf16* __restrict__ hf, const bf16* __restrict__ hb,
                               const float* __restrict__ cf, const float* __restrict__ cb,
                               bf16* __restrict__ hout, float* __restrict__ cout) {
  int i = blockIdx.x * 256 + threadIdx.x;
  if (i >= 256 * 512) return;
  hout[i] = (bf16)((float)hf[i] + (float)hb[i]);
  cout[i] = cf[i] + cb[i];
}

// ---------------------------------------------------------------------------
// Host
// ---------------------------------------------------------------------------
extern "C" void kernel_launch(void* const* d_in, const int* in_sizes, int n_in,
                              void* d_out, int out_size, void* d_ws, size_t ws_size,
                              hipStream_t stream) {
  (void)in_sizes; (void)n_in; (void)out_size;
  const float* src = (const float*)d_in[0];
  const float* trg = (const float*)d_in[1];
  const float* fi_w1 = (const float*)d_in[2];
  const float* fi_b1 = (const float*)d_in[3];
  const float* fi_w2 = (const float*)d_in[4];
  const float* fi_b2 = (const float*)d_in[5];
  const float* fi_w3 = (const float*)d_in[6];
  const float* fi_b3 = (const float*)d_in[7];
  // LSTM param order: e0f, e0b, e1f, e1b, d0, d1
  const float* wih_in[6] = {(const float*)d_in[8],  (const float*)d_in[12], (const float*)d_in[16],
                            (const float*)d_in[20], (const float*)d_in[30], (const float*)d_in[34]};
  const float* whh_in[6] = {(const float*)d_in[9],  (const float*)d_in[13], (const float*)d_in[17],
                            (const float*)d_in[21], (const float*)d_in[31], (const float*)d_in[35]};
  const float* bih_in[6] = {(const float*)d_in[10], (const float*)d_in[14], (const float*)d_in[18],
                            (const float*)d_in[22], (const float*)d_in[32], (const float*)d_in[36]};
  const float* bhh_in[6] = {(const float*)d_in[11], (const float*)d_in[15], (const float*)d_in[19],
                            (const float*)d_in[23], (const float*)d_in[33], (const float*)d_in[37]};
  const int kin[6] = {128, 128, 1024, 1024, 128, 512};
  const float* attnfc_w = (const float*)d_in[24];
  const float* attnfc_b = (const float*)d_in[25];
  const float* inproj_w = (const float*)d_in[26];
  const float* inproj_b = (const float*)d_in[27];
  const float* outproj_w = (const float*)d_in[28];
  const float* outproj_b = (const float*)d_in[29];
  const float* fo_w1 = (const float*)d_in[38];
  const float* fo_b1 = (const float*)d_in[39];
  const float* fo_w2 = (const float*)d_in[40];
  const float* fo_b2 = (const float*)d_in[41];
  const float* fo_w3 = (const float*)d_in[42];
  const float* fo_b3 = (const float*)d_in[43];
  float* out = (float*)d_out;

  // ---- workspace carve ----
  char* base = (char*)d_ws;
  size_t o = 0;
  auto take = [&](size_t bytes) -> char* {
    char* p = base + o;
    o = (o + bytes + 255) & ~(size_t)255;
    return p;
  };
  bf16* wr_wih[6]; for (int i = 0; i < 6; ++i) wr_wih[i] = (bf16*)take((size_t)2048 * kin[i] * 2);
  bf16* wr_whh[6]; for (int i = 0; i < 6; ++i) wr_whh[i] = (bf16*)take((size_t)2048 * 512 * 2);
  float* bias_l[6]; for (int i = 0; i < 6; ++i) bias_l[i] = (float*)take(2048 * 4);
  bf16* attnfc_wb = (bf16*)take((size_t)128 * 1024 * 2);
  bf16* inproj_wb = (bf16*)take((size_t)384 * 128 * 2);
  bf16* outproj_wb = (bf16*)take((size_t)128 * 128 * 2);
  bf16* fo_w1b = (bf16*)take((size_t)64 * 512 * 2);
  bf16* h0_0 = (bf16*)take((size_t)6 * 256 * 512 * 2);   // initial h per dir
  bf16* hf_0 = (bf16*)take((size_t)6 * 256 * 512 * 2);   // final h
  float* c_0 = (float*)take((size_t)6 * 256 * 512 * 4);  // persistent c per dir
  int* flags = (int*)take(4096 * 4);
  bf16* h0_[6]; bf16* hf_[6]; float* c_[6];
  for (int i = 0; i < 6; ++i) {
    h0_[i] = h0_0 + (size_t)i * 256 * 512;
    hf_[i] = hf_0 + (size_t)i * 256 * 512;
    c_[i] = c_0 + (size_t)i * 256 * 512;
  }
  char* RA = take((size_t)64 << 20);  // x1_hc -> proj_enc/inp/qb/kb/vb/attnb/dec_in/fc1out
  char* RB = take((size_t)64 << 20);  // enc_hc -> hc0/hc1
  char* XG = take((size_t)64 << 20);  // 4 parity xg chunk buffers -> xg_dec
  bf16* embed = (bf16*)take((size_t)32768 * 128 * 2);
  size_t required = o;
  if (required > ws_size) {
    fprintf(stderr, "[kernel_launch] ws_size=%zu < required=%zu — aborting launch\n",
            ws_size, required);
    return;
  }

  bf16* x1_hc    = (bf16*)RA;                        // layer-0 out, hc layout (64MB)
  bf16* proj_enc = (bf16*)RA;                        // (128,256,128) time-major
  bf16* inp      = (bf16*)(RA + ((size_t)8 << 20));  // (64,256,128) time-major
  bf16* qb       = (bf16*)(RA + ((size_t)12 << 20));
  bf16* kb       = (bf16*)(RA + ((size_t)16 << 20));
  bf16* vb       = (bf16*)(RA + ((size_t)24 << 20));
  bf16* attnb    = (bf16*)(RA + ((size_t)32 << 20));
  bf16* dec_in   = (bf16*)(RA + ((size_t)36 << 20)); // (64,256,128) time-major
  bf16* fc1out   = (bf16*)(RA + ((size_t)40 << 20));
  bf16* enc_hc   = (bf16*)RB;                        // layer-1 out, hc layout (64MB)
  bf16* hc0      = (bf16*)RB;                        // decoder d0 hcomm (16MB)
  bf16* hc1      = (bf16*)(RB + ((size_t)20 << 20)); // decoder d1 hcomm (16MB)
  bf16* bufF[2]  = {(bf16*)XG, (bf16*)(XG + ((size_t)32 << 20))};             // fwd chunk xg (16MB each)
  bf16* bufB[2]  = {(bf16*)(XG + ((size_t)16 << 20)), (bf16*)(XG + ((size_t)48 << 20))};
  bf16* xg_dec   = (bf16*)XG;                        // (64,256,2048) decoder d0 (64MB)

  // ---- prep ----
  for (int i = 0; i < 6; ++i) {
    reorder_gate_rows<<<dim3((2048 * kin[i] + 255) / 256), 256, 0, stream>>>(wih_in[i], wr_wih[i], kin[i]);
    reorder_gate_rows<<<dim3(4096), 256, 0, stream>>>(whh_in[i], wr_whh[i], 512);
    combine_bias<<<dim3(8), 256, 0, stream>>>(bih_in[i], bhh_in[i], bias_l[i]);
  }
  f2b<<<dim3(512), 256, 0, stream>>>(attnfc_w, attnfc_wb, 128 * 1024);
  f2b<<<dim3(192), 256, 0, stream>>>(inproj_w, inproj_wb, 384 * 128);
  f2b<<<dim3(64), 256, 0, stream>>>(outproj_w, outproj_wb, 128 * 128);
  f2b<<<dim3(128), 256, 0, stream>>>(fo_w1, fo_w1b, 64 * 512);
  zero_u32<<<dim3(1024), 256, 0, stream>>>((uint32_t*)h0_0, 4 * 256 * 512 / 2);  // enc h0 = 0
  zero_u32<<<dim3(2048), 256, 0, stream>>>((uint32_t*)c_0, 4 * 256 * 512);       // enc c = 0
  zero_u32<<<dim3(16), 256, 0, stream>>>((uint32_t*)flags, 4096);

  // ---- fc_in on src (time-major) ----
  fc_in_mlp<<<dim3(128), 256, 0, stream>>>(src, embed, 32768, 128, fi_w1, fi_b1, fi_w2, fi_b2, fi_w3, fi_b3);

  constexpr int TCC = 16, NCH = 8;
  // ---- encoder layer 0: chunk-0 GEMM serial, then fused rec+next-GEMM ----
  gemm_bt<2, 2, 0, false><<<dim3(32, 16), 256, 0, stream>>>(
      embed, wr_wih[0], bias_l[0], nullptr, bufF[0], 4096, 2048, 128);
  gemm_bt<2, 2, 0, false><<<dim3(32, 16), 256, 0, stream>>>(
      embed + (size_t)(128 - TCC) * 256 * 128, wr_wih[1], bias_l[1], nullptr, bufB[0], 4096, 2048, 128);
  for (int c = 0; c < NCH; ++c) {
    GJob job{};
    if (c < NCH - 1) {
      int n = c + 1;
      job.mode = 1;
      job.Af = embed + (size_t)(TCC * n) * 256 * 128;
      job.Ab = embed + (size_t)(128 - TCC * n - TCC) * 256 * 128;
      job.Wf = wr_wih[0]; job.Wb = wr_wih[1];
      job.bsF = bias_l[0]; job.bsB = bias_l[1];
      job.outF = bufF[n & 1]; job.outB = bufB[n & 1];
    }
    RDir f{wr_whh[0], bufF[c & 1], x1_hc, 0, 0, h0_[0], c_[0], hf_[0]};
    RDir bk{wr_whh[1], bufB[c & 1], x1_hc, 64, 1, h0_[1], c_[1], hf_[1]};
    lstm_rec_g<<<dim3(256), 512, 0, stream>>>(f, bk, c * TCC, TCC, 128, flags + c * 128, job);
  }
  // ---- encoder layer 1: chunk-0 GEMM serial (needs full x1_hc), then fused ----
  gemm_hcA<2, 2, 0><<<dim3(32, 16), 256, 0, stream>>>(
      x1_hc, 0, wr_wih[2], bias_l[2], bufF[0], 4096, 2048, 1024);
  gemm_hcA<2, 2, 0><<<dim3(32, 16), 256, 0, stream>>>(
      x1_hc, 128 - TCC, wr_wih[3], bias_l[3], bufB[0], 4096, 2048, 1024);
  for (int c = 0; c < NCH; ++c) {
    GJob job{};
    if (c < NCH - 1) {
      int n = c + 1;
      job.mode = 2;
      job.Af = x1_hc; job.Ab = x1_hc;
      job.tbF = TCC * n; job.tbB = 128 - TCC * n - TCC;
      job.Wf = wr_wih[2]; job.Wb = wr_wih[3];
      job.bsF = bias_l[2]; job.bsB = bias_l[3];
      job.outF = bufF[n & 1]; job.outB = bufB[n & 1];
    }
    RDir f{wr_whh[2], bufF[c & 1], enc_hc, 0, 0, h0_[2], c_[2], hf_[2]};
    RDir bk{wr_whh[3], bufB[c & 1], enc_hc, 64, 1, h0_[3], c_[3], hf_[3]};
    lstm_rec_g<<<dim3(256), 512, 0, stream>>>(f, bk, c * TCC, TCC, 128, flags + 1024 + c * 128, job);
  }

  // ---- attnfc (tanh), reads enc_hc directly ----
  gemm_hcA<2, 2, 1><<<dim3(256, 1), 256, 0, stream>>>(
      enc_hc, 0, attnfc_wb, attnfc_b, proj_enc, 32768, 128, 1024);

  // ---- fc_in on trg (time-major) ----
  fc_in_mlp<<<dim3(64), 256, 0, stream>>>(trg, inp, 16384, 64, fi_w1, fi_b1, fi_w2, fi_b2, fi_w3, fi_b3);

  // ---- MHA (all time-major) ----
  gemm_bt<2, 2, 0, false><<<dim3(128, 1), 256, 0, stream>>>(inp, inproj_wb, inproj_b, nullptr, qb, 16384, 128, 128);
  gemm_bt<2, 2, 0, false><<<dim3(256, 1), 256, 0, stream>>>(proj_enc, inproj_wb + (size_t)128 * 128, inproj_b + 128, nullptr, kb, 32768, 128, 128);
  gemm_bt<2, 2, 0, false><<<dim3(256, 1), 256, 0, stream>>>(proj_enc, inproj_wb + (size_t)256 * 128, inproj_b + 256, nullptr, vb, 32768, 128, 128);
  attention_kernel<<<dim3(256, 4), 128, 0, stream>>>(qb, kb, vb, attnb);
  gemm_bt<2, 2, 0, true><<<dim3(128, 1), 256, 0, stream>>>(attnb, outproj_wb, outproj_b, inp, dec_in, 16384, 128, 128);

  // ---- decoder initial states (enc c_ hold final c after last chunk) ----
  dec_state_init<<<dim3(512), 256, 0, stream>>>(hf_[0], hf_[1], c_[0], c_[1], h0_[4], c_[4]);
  dec_state_init<<<dim3(512), 256, 0, stream>>>(hf_[2], hf_[3], c_[2], c_[3], h0_[5], c_[5]);

  // ---- decoder: d0 xg GEMM + fused batch-split d0/d1 recurrence ----
  gemm_bt<2, 2, 0, false><<<dim3(128, 16), 256, 0, stream>>>(dec_in, wr_wih[4], bias_l[4], nullptr, xg_dec, 16384, 2048, 128);
  lstm_dec_fused<<<dim3(256), 512, 0, stream>>>(
      wr_whh[4], xg_dec, hc0, h0_[4], c_[4],
      wr_whh[5], wr_wih[5], bias_l[5], hc1, h0_[5], c_[5],
      flags + 2048);

  // ---- fc_out (stage 1 reads hc1 hcomm layout directly) ----
  gemm_hc_fcout<<<dim3(128, 1), 128, 0, stream>>>(hc1, fo_w1b, fo_b1, fc1out, 16384, 64, 512);
  fc_out_tail<<<dim3(64), 256, 0, stream>>>(fc1out, trg, out, 16384, fo_w2, fo_b2, fo_w3, fo_b3);
}